// Round 6
// baseline (2642.312 us; speedup 1.0000x reference)
//
#include <hip/hip_runtime.h>

typedef unsigned int u32;

#define N_NODES 32768
#define N_EDGES 262144
#define PF 65   // LDS pitch (floats): 64 edges + 1 pad

// ---------- fp32 weight buffer layout (float offsets in d_ws) ----------
enum : int {
  OFF_RT_W   = 0,       // [64,128]
  OFF_RT_B   = 8192,    // [128]
  OFF_RIN_W  = 8320,    // [128,192]  (stored PERMUTED for 8-wave ownership:
                        //  scalar col c<128 -> (c>>4)*24 + (c&15)
                        //  vec u=c-128     -> (u>>3)*24 + 16 + (u&7))
  OFF_RIN_B  = 32896,   // [192] (unpermuted)
  OFF_ROUT_W = 33088,   // [128,192]
  OFF_ROUT_B = 57664,   // [192]
  OFF_TP00   = 57856,   // [128,128]
  OFF_TP01   = 74240,   // [128,64]
  OFF_TP10   = 82432,   // [64,64]
  OFF_TP11   = 86528,   // [64,128]
  OFF_ACT_W1 = 94720,   // [64,64]
  OFF_ACT_B1 = 98816,   // [64]
  OFF_ACT_W2 = 98880,   // [64,64]
  OFF_ACT_B2 = 102976,  // [64]
  OFF_GATE_W1= 103040,  // [64,64]
  OFF_GATE_B1= 107136,  // [64]
  OFF_GATE_W2= 107200,  // [64,65]
  OFF_GATE_B2= 111360,  // [65]
  OFF_LSIG   = 111428,  // [10]
  OFF_VR_W   = 111440,  // [64,64]
  OFF_VR_B   = 115536,  // [64]
  OFF_SELF_WS= 115600,  // [128,128]
  OFF_SELF_BS= 131984,  // [128]
  OFF_SELF_WV= 132112,  // [64,64]
  NWF        = 136208
};
enum : int {
  ACC_S_OFF  = NWF,
  ACC_SG_OFF = ACC_S_OFF + N_NODES*128,
  ACC_VG_OFF = ACC_SG_OFF + N_NODES,
  ACC_V_OFF  = ACC_VG_OFF + N_NODES*64,
  ACC_END    = ACC_V_OFF + N_NODES*192
};

__device__ __forceinline__ float fsilu(float x){ return x/(1.f+__expf(-x)); }
__device__ __forceinline__ float fsig (float x){ return 1.f/(1.f+__expf(-x)); }

#define SQ3f     1.7320508075688772f
#define INV_SQ3f 0.5773502691896258f

__global__ void k_zero(float* __restrict__ p, int n){
  int t = blockIdx.x*256 + threadIdx.x;
  if (t < n) p[t] = 0.f;
}

// weight copy; tensor index 2 (rin_w) permuted so wave wv (of 8) owns a
// contiguous 24-slot slice [24wv,24wv+24):
//   scalar cols [16wv,16wv+16) -> slots [24wv, 24wv+16)
//   vec u's    [ 8wv, 8wv+ 8)  -> slots [24wv+16, 24wv+24)
struct WCopy { const float* src[24]; int n[24]; int off[24]; };

__global__ void k_copy(WCopy w, float* __restrict__ dst){
  int t = blockIdx.x*256 + threadIdx.x;
  for (int a=0;a<24;++a){
    int n = w.n[a];
    if (t < n){
      if (a == 2){
        int k = t/192, c = t%192;
        int dc = (c < 128) ? ((c>>4)*24 + (c&15))
                           : ((((c-128)>>3)*24) + 16 + ((c-128)&7));
        dst[w.off[a] + k*192 + dc] = w.src[a][t];
      } else {
        dst[w.off[a]+t] = w.src[a][t];
      }
      return;
    }
    t -= n;
  }
}

// ---------------- edge kernel ----------------
// R6: 512 threads (8 waves) per 64-edge tile; per-wave output slice HALVED
// (24 rin / 16 tp00 / 8 u) -> peak live floats ~85 (fits 6 waves/SIMD cap).
// LDS arena 128 channels x 65 (33.3 KB) -> 3 blocks/CU = 24 waves/CU.
// Arena schedule:
//   [0,64)=ES  (P0..P11) | [64,128)=trunk-half (P1a/P2a/P1b/P2b) then GE
//   then XS [0,128) | XB [0,96)+DOT [96,128) | VN [0,64)+T1 [64,128)
//   scatter: A 128ch, B 2x96ch, C 64ch
__launch_bounds__(512,6)
__global__ void k_edge(const float* __restrict__ h, const float* __restrict__ evec,
                       const float* __restrict__ es_g, const float* __restrict__ edist,
                       const int* __restrict__ src_idx, const int* __restrict__ dst_idx,
                       const int* __restrict__ etype, const float* __restrict__ wf,
                       float* __restrict__ acc_s, float* __restrict__ acc_sg,
                       float* __restrict__ acc_vg, float* __restrict__ acc_v)
{
  __shared__ float smf[128*PF];
  __shared__ float s_sgate[64];
  __shared__ int   s_dst[64];

  const int tid  = threadIdx.x;
  const int lane = tid & 63;
  const int wv   = __builtin_amdgcn_readfirstlane(tid >> 6);   // 0..7
  const int e0   = blockIdx.x * 64;
  const int e    = e0 + lane;

  if (tid >= 64 && tid < 128) s_dst[tid-64] = dst_idx[e0 + tid-64];

  const int srcn = src_idx[e];
  const float* hrow = h + (size_t)srcn*320;
  const float4* hrow4 = reinterpret_cast<const float4*>(hrow);

  float y0,y1,y2;
  { float vx=evec[e*3], vy=evec[e*3+1], vz=evec[e*3+2];
    float rn = SQ3f * rsqrtf(vx*vx+vy*vy+vz*vz+1e-12f);
    y0=vx*rn; y1=vy*rn; y2=vz*rn; }

  // P0: stage edge_scalars -> ES [0,64)
  for (int lin=tid; lin<1024; lin+=512){
    int row = lin>>4, c4 = lin&15;
    float4 v = reinterpret_cast<const float4*>(es_g)[(e0+row)*16 + c4];
    smf[(c4*4+0)*PF + row] = v.x;
    smf[(c4*4+1)*PF + row] = v.y;
    smf[(c4*4+2)*PF + row] = v.z;
    smf[(c4*4+3)*PF + row] = v.w;
  }
  __syncthreads();                                        // B1

  // P1a: trunk cols [0,64), 8 cols/wave -> T [64,128)
  { float acc[8];
    #pragma unroll
    for (int j=0;j<8;++j) acc[j] = wf[OFF_RT_B + 8*wv + j];
    for (int k=0;k<64;++k){
      float a = smf[k*PF + lane];
      const float* wr = wf + OFF_RT_W + k*128 + 8*wv;
      #pragma unroll
      for (int j=0;j<8;++j) acc[j] += a*wr[j];
    }
    #pragma unroll
    for (int j=0;j<8;++j) smf[(64 + 8*wv + j)*PF + lane] = fsilu(acc[j]);
  }
  __syncthreads();                                        // B2

  float sregS[16], sregV[8], souts[16], soutv[8];
  #pragma unroll
  for (int i=0;i<16;++i) sregS[i] = 1.f + wf[OFF_RIN_B + 16*wv + i];
  #pragma unroll
  for (int t=0;t<8;++t)  sregV[t] = 1.f + wf[OFF_RIN_B + 128 + 8*wv + t];
  #pragma unroll
  for (int j=0;j<16;++j) souts[j] = 1.f + wf[OFF_ROUT_B + 16*wv + j];
  #pragma unroll
  for (int t=0;t<8;++t)  soutv[t] = 1.f + wf[OFF_ROUT_B + 128 + 8*wv + t];

  // P2a: trunk k in [0,64)
  for (int k=0;k<64;++k){
    float a = smf[(64+k)*PF + lane];
    const float* wi = wf + OFF_RIN_W + k*192 + 24*wv;
    #pragma unroll
    for (int i=0;i<16;++i) sregS[i] += a*wi[i];
    #pragma unroll
    for (int t=0;t<8;++t)  sregV[t] += a*wi[16+t];
    const float* wo = wf + OFF_ROUT_W + k*192;
    #pragma unroll
    for (int j=0;j<16;++j) souts[j] += a*wo[16*wv + j];
    #pragma unroll
    for (int t=0;t<8;++t)  soutv[t] += a*wo[128 + 8*wv + t];
  }
  __syncthreads();                                        // B3 (T reads done)

  // P1b: trunk cols [64,128) -> overwrite T [64,128)
  { float acc[8];
    #pragma unroll
    for (int j=0;j<8;++j) acc[j] = wf[OFF_RT_B + 64 + 8*wv + j];
    for (int k=0;k<64;++k){
      float a = smf[k*PF + lane];
      const float* wr = wf + OFF_RT_W + k*128 + 64 + 8*wv;
      #pragma unroll
      for (int j=0;j<8;++j) acc[j] += a*wr[j];
    }
    #pragma unroll
    for (int j=0;j<8;++j) smf[(64 + 8*wv + j)*PF + lane] = fsilu(acc[j]);
  }
  __syncthreads();                                        // B4

  // P2b: trunk k in [64,128)
  for (int k=0;k<64;++k){
    float a = smf[(64+k)*PF + lane];
    const float* wi = wf + OFF_RIN_W + (64+k)*192 + 24*wv;
    #pragma unroll
    for (int i=0;i<16;++i) sregS[i] += a*wi[i];
    #pragma unroll
    for (int t=0;t<8;++t)  sregV[t] += a*wi[16+t];
    const float* wo = wf + OFF_ROUT_W + (64+k)*192;
    #pragma unroll
    for (int j=0;j<16;++j) souts[j] += a*wo[16*wv + j];
    #pragma unroll
    for (int t=0;t<8;++t)  soutv[t] += a*wo[128 + 8*wv + t];
  }
  __syncthreads();                                        // B5 (T dead)

  // P10: ge = silu(es@gate_w1+b1) -> GE [64,128)  (ES still resident)
  { float ge[8];
    #pragma unroll
    for (int t=0;t<8;++t) ge[t] = wf[OFF_GATE_B1 + 8*wv + t];
    for (int k=0;k<64;++k){
      float a = smf[k*PF + lane];
      const float* wr = wf + OFF_GATE_W1 + k*64 + 8*wv;
      #pragma unroll
      for (int t=0;t<8;++t) ge[t] += a*wr[t];
    }
    #pragma unroll
    for (int t=0;t<8;++t) smf[(64 + 8*wv + t)*PF + lane] = fsilu(ge[t]);
  }
  __syncthreads();                                        // B6

  // P11: go = ge@gate_w2 + b2 -> vg (regs), sgate (LDS, wv0)
  float vg[8];
  { float g0 = wf[OFF_GATE_B2];
    #pragma unroll
    for (int t=0;t<8;++t) vg[t] = wf[OFF_GATE_B2 + 1 + 8*wv + t];
    for (int k=0;k<64;++k){
      float a = smf[(64+k)*PF + lane];
      const float* wr = wf + OFF_GATE_W2 + k*65;
      g0 += a*wr[0];
      #pragma unroll
      for (int t=0;t<8;++t) vg[t] += a*wr[1 + 8*wv + t];
    }
    #pragma unroll
    for (int t=0;t<8;++t) vg[t] = fsig(vg[t]);
    if (wv == 0){
      float sigma = __expf(wf[OFF_LSIG + etype[e]]);
      s_sgate[lane] = fsig(g0) * __expf(-edist[e]/sigma);
    }
  }
  __syncthreads();                                        // B7 (ES+GE dead)

  // XS stage: wave owns scalar cols [16wv,16wv+16) via 4 float4
  #pragma unroll
  for (int q=0;q<4;++q){
    float4 v = hrow4[4*wv + q];
    int s = 16*wv + 4*q;
    smf[(s+0)*PF + lane] = v.x*sregS[4*q+0];
    smf[(s+1)*PF + lane] = v.y*sregS[4*q+1];
    smf[(s+2)*PF + lane] = v.z*sregS[4*q+2];
    smf[(s+3)*PF + lane] = v.w*sregS[4*q+3];
  }
  __syncthreads();                                        // B8

  // scalar loop k=0..127 (24 FMA/iter/wave)
  float msg_s[16], svv[8];
  #pragma unroll
  for (int j=0;j<16;++j) msg_s[j]=0.f;
  #pragma unroll
  for (int t=0;t<8;++t) svv[t]=0.f;
  for (int k=0;k<128;++k){
    float a = smf[k*PF + lane];
    const float* w0p = wf + OFF_TP00 + k*128 + 16*wv;
    const float* w1p = wf + OFF_TP01 + k*64  + 8*wv;
    #pragma unroll
    for (int j=0;j<16;++j) msg_s[j] += a*w0p[j];
    #pragma unroll
    for (int t=0;t<8;++t)  svv[t]  += a*w1p[t];
  }
  __syncthreads();                                        // B9 (XS dead)

  // rank-1 init: mv = svv*y  (svv dies here)
  float mv[8][3];
  #pragma unroll
  for (int t=0;t<8;++t){ mv[t][0]=svv[t]*y0; mv[t][1]=svv[t]*y1; mv[t][2]=svv[t]*y2; }

  // vec chunk A stage: u in [0,32) by waves 0..3; dot at staging
  if (wv < 4){
    float f[24];
    #pragma unroll
    for (int q=0;q<6;++q){
      float4 v = hrow4[32 + 6*wv + q];
      f[4*q+0]=v.x; f[4*q+1]=v.y; f[4*q+2]=v.z; f[4*q+3]=v.w;
    }
    #pragma unroll
    for (int t=0;t<8;++t){
      int u = 8*wv + t;
      float sc = sregV[t];
      float x0=f[3*t+0]*sc, x1=f[3*t+1]*sc, x2=f[3*t+2]*sc;
      smf[(3*u+0)*PF + lane] = x0;
      smf[(3*u+1)*PF + lane] = x1;
      smf[(3*u+2)*PF + lane] = x2;
      smf[(96+u)*PF + lane] = (x0*y0 + x1*y1 + x2*y2)*INV_SQ3f;
    }
  }
  __syncthreads();                                        // B10

  { for (int ul=0; ul<32; ++ul){
      float x0 = smf[(3*ul+0)*PF + lane];
      float x1 = smf[(3*ul+1)*PF + lane];
      float x2 = smf[(3*ul+2)*PF + lane];
      const float* wr = wf + OFF_TP10 + ul*64 + 8*wv;
      #pragma unroll
      for (int t=0;t<8;++t){ float wt=wr[t]; mv[t][0]+=x0*wt; mv[t][1]+=x1*wt; mv[t][2]+=x2*wt; }
    }
    for (int k=0;k<32;++k){
      float a = smf[(96+k)*PF + lane];
      const float* wr = wf + OFF_TP11 + k*128 + 16*wv;
      #pragma unroll
      for (int j=0;j<16;++j) msg_s[j] += a*wr[j];
    } }
  __syncthreads();                                        // B11

  // vec chunk B stage: u in [32,64) by waves 4..7
  if (wv >= 4){
    float f[24];
    #pragma unroll
    for (int q=0;q<6;++q){
      float4 v = hrow4[32 + 6*wv + q];
      f[4*q+0]=v.x; f[4*q+1]=v.y; f[4*q+2]=v.z; f[4*q+3]=v.w;
    }
    #pragma unroll
    for (int t=0;t<8;++t){
      int um = 8*(wv-4) + t;
      float sc = sregV[t];
      float x0=f[3*t+0]*sc, x1=f[3*t+1]*sc, x2=f[3*t+2]*sc;
      smf[(3*um+0)*PF + lane] = x0;
      smf[(3*um+1)*PF + lane] = x1;
      smf[(3*um+2)*PF + lane] = x2;
      smf[(96+um)*PF + lane] = (x0*y0 + x1*y1 + x2*y2)*INV_SQ3f;
    }
  }
  __syncthreads();                                        // B12

  { for (int ul=0; ul<32; ++ul){
      float x0 = smf[(3*ul+0)*PF + lane];
      float x1 = smf[(3*ul+1)*PF + lane];
      float x2 = smf[(3*ul+2)*PF + lane];
      const float* wr = wf + OFF_TP10 + (32+ul)*64 + 8*wv;
      #pragma unroll
      for (int t=0;t<8;++t){ float wt=wr[t]; mv[t][0]+=x0*wt; mv[t][1]+=x1*wt; mv[t][2]+=x2*wt; }
    }
    for (int k=0;k<32;++k){
      float a = smf[(96+k)*PF + lane];
      const float* wr = wf + OFF_TP11 + (32+k)*128 + 16*wv;
      #pragma unroll
      for (int j=0;j<16;++j) msg_s[j] += a*wr[j];
    } }
  __syncthreads();                                        // B13 (XB/DOT dead)

  // P6: scale_out + silu + vn -> VN [0,64)
  #pragma unroll
  for (int j=0;j<16;++j) msg_s[j] = fsilu(msg_s[j]*souts[j]);
  #pragma unroll
  for (int t=0;t<8;++t){
    mv[t][0]*=soutv[t]; mv[t][1]*=soutv[t]; mv[t][2]*=soutv[t];
    float vn = sqrtf(mv[t][0]*mv[t][0]+mv[t][1]*mv[t][1]+mv[t][2]*mv[t][2]+1e-12f);
    smf[(8*wv + t)*PF + lane] = vn;
  }
  __syncthreads();                                        // B14

  // P7: t1 = silu(vn@act_w1+b1) -> T1 [64,128)
  { float a1[8];
    #pragma unroll
    for (int t=0;t<8;++t) a1[t] = wf[OFF_ACT_B1 + 8*wv + t];
    for (int k=0;k<64;++k){
      float a = smf[k*PF + lane];
      const float* wr = wf + OFF_ACT_W1 + k*64 + 8*wv;
      #pragma unroll
      for (int t=0;t<8;++t) a1[t] += a*wr[t];
    }
    #pragma unroll
    for (int t=0;t<8;++t) smf[(64 + 8*wv + t)*PF + lane] = fsilu(a1[t]);
  }
  __syncthreads();                                        // B15

  // P8: g = sigmoid(t1@act_w2+b2); mv *= g
  { float gq[8];
    #pragma unroll
    for (int t=0;t<8;++t) gq[t] = wf[OFF_ACT_B2 + 8*wv + t];
    for (int k=0;k<64;++k){
      float a = smf[(64+k)*PF + lane];
      const float* wr = wf + OFF_ACT_W2 + k*64 + 8*wv;
      #pragma unroll
      for (int t=0;t<8;++t) gq[t] += a*wr[t];
    }
    #pragma unroll
    for (int t=0;t<8;++t){ float g=fsig(gq[t]); mv[t][0]*=g; mv[t][1]*=g; mv[t][2]*=g; }
  }
  __syncthreads();                                        // B16

  // ===== COALESCED scatter via LDS transpose =====
  // Phase A: sg*msg_s (128 ch)
  { float sg = s_sgate[lane];
    #pragma unroll
    for (int j=0;j<16;++j) smf[(16*wv + j)*PF + lane] = sg*msg_s[j];
  }
  __syncthreads();                                        // B17
  for (int lin=tid; lin<8192; lin+=512){
    int row = lin >> 7, ch = lin & 127;
    atomicAdd(acc_s + (size_t)s_dst[row]*128 + ch, smf[ch*PF + row]);
  }
  __syncthreads();                                        // B18
  // Phase B half 1: u in [0,32) (waves 0..3), 96 ch
  if (wv < 4){
    #pragma unroll
    for (int t=0;t<8;++t){
      int u = 8*wv + t;
      smf[(3*u+0)*PF + lane] = vg[t]*mv[t][0];
      smf[(3*u+1)*PF + lane] = vg[t]*mv[t][1];
      smf[(3*u+2)*PF + lane] = vg[t]*mv[t][2];
    }
  }
  __syncthreads();                                        // B19
  for (int lin=tid; lin<6144; lin+=512){
    int row = lin / 96, ch = lin % 96;
    atomicAdd(acc_v + (size_t)s_dst[row]*192 + ch, smf[ch*PF + row]);
  }
  __syncthreads();                                        // B20
  // Phase B half 2: u in [32,64) (waves 4..7), 96 ch
  if (wv >= 4){
    #pragma unroll
    for (int t=0;t<8;++t){
      int um = 8*(wv-4) + t;
      smf[(3*um+0)*PF + lane] = vg[t]*mv[t][0];
      smf[(3*um+1)*PF + lane] = vg[t]*mv[t][1];
      smf[(3*um+2)*PF + lane] = vg[t]*mv[t][2];
    }
  }
  __syncthreads();                                        // B21
  for (int lin=tid; lin<6144; lin+=512){
    int row = lin / 96, ch = lin % 96;
    atomicAdd(acc_v + (size_t)s_dst[row]*192 + 96 + ch, smf[ch*PF + row]);
  }
  __syncthreads();                                        // B22
  // Phase C: vg (64 ch) + sg
  #pragma unroll
  for (int t=0;t<8;++t) smf[(8*wv + t)*PF + lane] = vg[t];
  __syncthreads();                                        // B23
  for (int lin=tid; lin<4096; lin+=512){
    int row = lin >> 6, ch = lin & 63;
    atomicAdd(acc_vg + (size_t)s_dst[row]*64 + ch, smf[ch*PF + row]);
  }
  if (tid < 64) atomicAdd(acc_sg + s_dst[tid], s_sgate[tid]);
}

// ---------------- node kernel ----------------
__launch_bounds__(256,2)
__global__ void k_node(const float* __restrict__ h, const float* __restrict__ wf,
                       const float* __restrict__ acc_s, const float* __restrict__ acc_sg,
                       const float* __restrict__ acc_vg, const float* __restrict__ acc_v,
                       float* __restrict__ out)
{
  __shared__ float smf[160*PF];
  const int tid  = threadIdx.x;
  const int lane = tid & 63;
  const int wv   = __builtin_amdgcn_readfirstlane(tid >> 6);
  const int n0   = blockIdx.x * 64;
  const int n    = n0 + lane;
  const int w0   = 16*wv;

  float agg[16][3], vnr[16], sva[16][3];
  #pragma unroll
  for (int t=0;t<16;++t){
    float inv = 1.f/(acc_vg[n*64 + w0 + t] + 1e-6f);
    agg[t][0] = acc_v[n*192 + (w0+t)*3 + 0]*inv;
    agg[t][1] = acc_v[n*192 + (w0+t)*3 + 1]*inv;
    agg[t][2] = acc_v[n*192 + (w0+t)*3 + 2]*inv;
    vnr[t] = sqrtf(agg[t][0]*agg[t][0]+agg[t][1]*agg[t][1]+agg[t][2]*agg[t][2]+1e-12f);
    smf[(96 + w0 + t)*PF + lane] = vnr[t];
    sva[t][0]=0.f; sva[t][1]=0.f; sva[t][2]=0.f;
  }

  float outs[32];
  #pragma unroll
  for (int j=0;j<32;++j) outs[j] = wf[OFF_SELF_BS + 32*wv + j];

  for (int cc=0; cc<2; ++cc){
    for (int lin=tid; lin<1024; lin+=256){
      int row = lin>>4, c4 = lin&15;
      float4 v = reinterpret_cast<const float4*>(h)[(n0+row)*80 + cc*16 + c4];
      smf[(c4*4+0)*PF + row] = v.x;
      smf[(c4*4+1)*PF + row] = v.y;
      smf[(c4*4+2)*PF + row] = v.z;
      smf[(c4*4+3)*PF + row] = v.w;
    }
    __syncthreads();
    for (int k=0;k<64;++k){
      float a = smf[k*PF + lane];
      const float* wr = wf + OFF_SELF_WS + (cc*64+k)*128 + 32*wv;
      #pragma unroll
      for (int j=0;j<32;++j) outs[j] += a*wr[j];
    }
    __syncthreads();
  }
  for (int cc=0; cc<2; ++cc){
    for (int lin=tid; lin<1536; lin+=256){
      int row = lin/24, c6 = lin%24;
      float4 v = reinterpret_cast<const float4*>(h)[(n0+row)*80 + 32 + cc*24 + c6];
      smf[(c6*4+0)*PF + row] = v.x;
      smf[(c6*4+1)*PF + row] = v.y;
      smf[(c6*4+2)*PF + row] = v.z;
      smf[(c6*4+3)*PF + row] = v.w;
    }
    __syncthreads();
    for (int ul=0; ul<32; ++ul){
      float x0 = smf[(3*ul+0)*PF + lane];
      float x1 = smf[(3*ul+1)*PF + lane];
      float x2 = smf[(3*ul+2)*PF + lane];
      const float* wr = wf + OFF_SELF_WV + (cc*32+ul)*64 + w0;
      #pragma unroll
      for (int t=0;t<16;++t){ float wt=wr[t]; sva[t][0]+=x0*wt; sva[t][1]+=x1*wt; sva[t][2]+=x2*wt; }
    }
    __syncthreads();
  }

  float rv[16];
  #pragma unroll
  for (int t=0;t<16;++t) rv[t] = wf[OFF_VR_B + w0 + t];
  for (int k=0;k<64;++k){
    float a = smf[(96+k)*PF + lane];
    const float* wr = wf + OFF_VR_W + k*64 + w0;
    #pragma unroll
    for (int t=0;t<16;++t) rv[t] += a*wr[t];
  }

  { float inv = 1.f/(acc_sg[n] + 1e-6f);
    #pragma unroll
    for (int j=0;j<32;++j) outs[j] += acc_s[n*128 + 32*wv + j]*inv;
  }

  float* orow = out + (size_t)n*320;
  { float4* o4 = reinterpret_cast<float4*>(orow + 32*wv);
    #pragma unroll
    for (int j=0;j<8;++j){
      float4 v; v.x=outs[4*j]; v.y=outs[4*j+1]; v.z=outs[4*j+2]; v.w=outs[4*j+3];
      o4[j] = v;
    }
  }
  { float vbuf[48];
    #pragma unroll
    for (int t=0;t<16;++t){
      float sc = rv[t]/(vnr[t]+1e-6f);
      vbuf[t*3+0] = agg[t][0]*sc + sva[t][0];
      vbuf[t*3+1] = agg[t][1]*sc + sva[t][1];
      vbuf[t*3+2] = agg[t][2]*sc + sva[t][2];
    }
    float4* o4 = reinterpret_cast<float4*>(orow + 128 + 48*wv);
    #pragma unroll
    for (int j=0;j<12;++j){
      float4 v; v.x=vbuf[4*j]; v.y=vbuf[4*j+1]; v.z=vbuf[4*j+2]; v.w=vbuf[4*j+3];
      o4[j] = v;
    }
  }
}

// ---------------- launch ----------------
extern "C" void kernel_launch(void* const* d_in, const int* in_sizes, int n_in,
                              void* d_out, int out_size, void* d_ws, size_t ws_size,
                              hipStream_t stream) {
  const float* h     = (const float*)d_in[0];
  const float* evec  = (const float*)d_in[1];
  const float* es    = (const float*)d_in[2];
  const float* edist = (const float*)d_in[3];
  const int* srcI    = (const int*)d_in[4];
  const int* dstI    = (const int*)d_in[5];
  const int* etyp    = (const int*)d_in[6];

  float* wsf    = (float*)d_ws;
  float* acc_s  = wsf + ACC_S_OFF;
  float* acc_sg = wsf + ACC_SG_OFF;
  float* acc_vg = wsf + ACC_VG_OFF;
  float* acc_v  = wsf + ACC_V_OFF;

  WCopy wc;
  const int ns[24]  = {8192,128,24576,192,24576,192,16384,8192,4096,8192,4096,64,4096,64,
                       4096,64,4160,65,10,4096,64,16384,128,4096};
  const int offs[24]= {OFF_RT_W,OFF_RT_B,OFF_RIN_W,OFF_RIN_B,OFF_ROUT_W,OFF_ROUT_B,
                       OFF_TP00,OFF_TP01,OFF_TP10,OFF_TP11,OFF_ACT_W1,OFF_ACT_B1,
                       OFF_ACT_W2,OFF_ACT_B2,OFF_GATE_W1,OFF_GATE_B1,OFF_GATE_W2,OFF_GATE_B2,
                       OFF_LSIG,OFF_VR_W,OFF_VR_B,OFF_SELF_WS,OFF_SELF_BS,OFF_SELF_WV};
  for (int a=0;a<24;++a){ wc.src[a] = (const float*)d_in[8+a]; wc.n[a]=ns[a]; wc.off[a]=offs[a]; }
  hipLaunchKernelGGL(k_copy, dim3(533), dim3(256), 0, stream, wc, wsf);

  { int nz = ACC_END - ACC_S_OFF;
    hipLaunchKernelGGL(k_zero, dim3((nz+255)/256), dim3(256), 0, stream, acc_s, nz); }

  hipLaunchKernelGGL(k_edge, dim3(N_EDGES/64), dim3(512), 0, stream,
                     h, evec, es, edist, srcI, dstI, etyp, wsf,
                     acc_s, acc_sg, acc_vg, acc_v);
  hipLaunchKernelGGL(k_node, dim3(N_NODES/64), dim3(256), 0, stream,
                     h, wsf, acc_s, acc_sg, acc_vg, acc_v, (float*)d_out);
}

// Round 7
// 1876.633 us; speedup vs baseline: 1.4080x; 1.4080x over previous
//
#include <hip/hip_runtime.h>

typedef unsigned int u32;

#define N_NODES 32768
#define N_EDGES 262144
#define PF 65   // LDS pitch (floats): 64 edges + 1 pad

// ---------- fp32 weight buffer layout (float offsets in d_ws) ----------
enum : int {
  OFF_RT_W   = 0,       // [64,128]
  OFF_RT_B   = 8192,    // [128]
  OFF_RIN_W  = 8320,    // [128,192]  (stored PERMUTED for 8-wave ownership:
                        //  scalar col c<128 -> (c>>4)*24 + (c&15)
                        //  vec u=c-128     -> (u>>3)*24 + 16 + (u&7))
  OFF_RIN_B  = 32896,   // [192] (unpermuted)
  OFF_ROUT_W = 33088,   // [128,192]
  OFF_ROUT_B = 57664,   // [192]
  OFF_TP00   = 57856,   // [128,128]
  OFF_TP01   = 74240,   // [128,64]
  OFF_TP10   = 82432,   // [64,64]
  OFF_TP11   = 86528,   // [64,128]
  OFF_ACT_W1 = 94720,   // [64,64]
  OFF_ACT_B1 = 98816,   // [64]
  OFF_ACT_W2 = 98880,   // [64,64]
  OFF_ACT_B2 = 102976,  // [64]
  OFF_GATE_W1= 103040,  // [64,64]
  OFF_GATE_B1= 107136,  // [64]
  OFF_GATE_W2= 107200,  // [64,65]
  OFF_GATE_B2= 111360,  // [65]
  OFF_LSIG   = 111428,  // [10]
  OFF_VR_W   = 111440,  // [64,64]
  OFF_VR_B   = 115536,  // [64]
  OFF_SELF_WS= 115600,  // [128,128]
  OFF_SELF_BS= 131984,  // [128]
  OFF_SELF_WV= 132112,  // [64,64]
  NWF        = 136208
};
enum : int {
  ACC_S_OFF  = NWF,
  ACC_SG_OFF = ACC_S_OFF + N_NODES*128,
  ACC_VG_OFF = ACC_SG_OFF + N_NODES,
  ACC_V_OFF  = ACC_VG_OFF + N_NODES*64,
  ACC_END    = ACC_V_OFF + N_NODES*192
};

__device__ __forceinline__ float fsilu(float x){ return x/(1.f+__expf(-x)); }
__device__ __forceinline__ float fsig (float x){ return 1.f/(1.f+__expf(-x)); }

#define SQ3f     1.7320508075688772f
#define INV_SQ3f 0.5773502691896258f

__global__ void k_zero(float* __restrict__ p, int n){
  int t = blockIdx.x*256 + threadIdx.x;
  if (t < n) p[t] = 0.f;
}

// weight copy; tensor index 2 (rin_w) permuted so wave wv (of 8) owns a
// contiguous 24-slot slice [24wv,24wv+24):
//   scalar cols [16wv,16wv+16) -> slots [24wv, 24wv+16)
//   vec u's    [ 8wv, 8wv+ 8)  -> slots [24wv+16, 24wv+24)
struct WCopy { const float* src[24]; int n[24]; int off[24]; };

__global__ void k_copy(WCopy w, float* __restrict__ dst){
  int t = blockIdx.x*256 + threadIdx.x;
  for (int a=0;a<24;++a){
    int n = w.n[a];
    if (t < n){
      if (a == 2){
        int k = t/192, c = t%192;
        int dc = (c < 128) ? ((c>>4)*24 + (c&15))
                           : ((((c-128)>>3)*24) + 16 + ((c-128)&7));
        dst[w.off[a] + k*192 + dc] = w.src[a][t];
      } else {
        dst[w.off[a]+t] = w.src[a][t];
      }
      return;
    }
    t -= n;
  }
}

// ---------------- edge kernel ----------------
// R7: R6's 8-wave structure at the REGISTER-FEASIBLE occupancy.
// R6 lesson: (512,6) caps unified regs at ~85/wave but live set ~120 ->
// massive scratch spill (FETCH 0.26->1.24 GB, WRITE 0.53->2.34 GB), all
// occupancy gain eaten by spill traffic. (512,4) = 128-reg budget,
// 2 blocks/CU = 16 waves/CU (vs R1's 12), no spill. vg[8] stashed to LDS
// (same-thread write/read, conflict-free) frees 8 regs across the fat region.
__launch_bounds__(512,4)
__global__ void k_edge(const float* __restrict__ h, const float* __restrict__ evec,
                       const float* __restrict__ es_g, const float* __restrict__ edist,
                       const int* __restrict__ src_idx, const int* __restrict__ dst_idx,
                       const int* __restrict__ etype, const float* __restrict__ wf,
                       float* __restrict__ acc_s, float* __restrict__ acc_sg,
                       float* __restrict__ acc_vg, float* __restrict__ acc_v)
{
  __shared__ float smf[128*PF];
  __shared__ float s_vg[8*512];     // vg stash: [t][tid], stride-1 across lanes
  __shared__ float s_sgate[64];
  __shared__ int   s_dst[64];

  const int tid  = threadIdx.x;
  const int lane = tid & 63;
  const int wv   = __builtin_amdgcn_readfirstlane(tid >> 6);   // 0..7
  const int e0   = blockIdx.x * 64;
  const int e    = e0 + lane;

  if (tid >= 64 && tid < 128) s_dst[tid-64] = dst_idx[e0 + tid-64];

  const int srcn = src_idx[e];
  const float* hrow = h + (size_t)srcn*320;
  const float4* hrow4 = reinterpret_cast<const float4*>(hrow);

  float y0,y1,y2;
  { float vx=evec[e*3], vy=evec[e*3+1], vz=evec[e*3+2];
    float rn = SQ3f * rsqrtf(vx*vx+vy*vy+vz*vz+1e-12f);
    y0=vx*rn; y1=vy*rn; y2=vz*rn; }

  // P0: stage edge_scalars -> ES [0,64)
  for (int lin=tid; lin<1024; lin+=512){
    int row = lin>>4, c4 = lin&15;
    float4 v = reinterpret_cast<const float4*>(es_g)[(e0+row)*16 + c4];
    smf[(c4*4+0)*PF + row] = v.x;
    smf[(c4*4+1)*PF + row] = v.y;
    smf[(c4*4+2)*PF + row] = v.z;
    smf[(c4*4+3)*PF + row] = v.w;
  }
  __syncthreads();                                        // B1

  // P1a: trunk cols [0,64), 8 cols/wave -> T [64,128)
  { float acc[8];
    #pragma unroll
    for (int j=0;j<8;++j) acc[j] = wf[OFF_RT_B + 8*wv + j];
    for (int k=0;k<64;++k){
      float a = smf[k*PF + lane];
      const float* wr = wf + OFF_RT_W + k*128 + 8*wv;
      #pragma unroll
      for (int j=0;j<8;++j) acc[j] += a*wr[j];
    }
    #pragma unroll
    for (int j=0;j<8;++j) smf[(64 + 8*wv + j)*PF + lane] = fsilu(acc[j]);
  }
  __syncthreads();                                        // B2

  float sregS[16], sregV[8], souts[16], soutv[8];
  #pragma unroll
  for (int i=0;i<16;++i) sregS[i] = 1.f + wf[OFF_RIN_B + 16*wv + i];
  #pragma unroll
  for (int t=0;t<8;++t)  sregV[t] = 1.f + wf[OFF_RIN_B + 128 + 8*wv + t];
  #pragma unroll
  for (int j=0;j<16;++j) souts[j] = 1.f + wf[OFF_ROUT_B + 16*wv + j];
  #pragma unroll
  for (int t=0;t<8;++t)  soutv[t] = 1.f + wf[OFF_ROUT_B + 128 + 8*wv + t];

  // P2a: trunk k in [0,64)
  for (int k=0;k<64;++k){
    float a = smf[(64+k)*PF + lane];
    const float* wi = wf + OFF_RIN_W + k*192 + 24*wv;
    #pragma unroll
    for (int i=0;i<16;++i) sregS[i] += a*wi[i];
    #pragma unroll
    for (int t=0;t<8;++t)  sregV[t] += a*wi[16+t];
    const float* wo = wf + OFF_ROUT_W + k*192;
    #pragma unroll
    for (int j=0;j<16;++j) souts[j] += a*wo[16*wv + j];
    #pragma unroll
    for (int t=0;t<8;++t)  soutv[t] += a*wo[128 + 8*wv + t];
  }
  __syncthreads();                                        // B3 (T reads done)

  // P1b: trunk cols [64,128) -> overwrite T [64,128)
  { float acc[8];
    #pragma unroll
    for (int j=0;j<8;++j) acc[j] = wf[OFF_RT_B + 64 + 8*wv + j];
    for (int k=0;k<64;++k){
      float a = smf[k*PF + lane];
      const float* wr = wf + OFF_RT_W + k*128 + 64 + 8*wv;
      #pragma unroll
      for (int j=0;j<8;++j) acc[j] += a*wr[j];
    }
    #pragma unroll
    for (int j=0;j<8;++j) smf[(64 + 8*wv + j)*PF + lane] = fsilu(acc[j]);
  }
  __syncthreads();                                        // B4

  // P2b: trunk k in [64,128)
  for (int k=0;k<64;++k){
    float a = smf[(64+k)*PF + lane];
    const float* wi = wf + OFF_RIN_W + (64+k)*192 + 24*wv;
    #pragma unroll
    for (int i=0;i<16;++i) sregS[i] += a*wi[i];
    #pragma unroll
    for (int t=0;t<8;++t)  sregV[t] += a*wi[16+t];
    const float* wo = wf + OFF_ROUT_W + (64+k)*192;
    #pragma unroll
    for (int j=0;j<16;++j) souts[j] += a*wo[16*wv + j];
    #pragma unroll
    for (int t=0;t<8;++t)  soutv[t] += a*wo[128 + 8*wv + t];
  }
  __syncthreads();                                        // B5 (T dead)

  // P10: ge = silu(es@gate_w1+b1) -> GE [64,128)  (ES still resident)
  { float ge[8];
    #pragma unroll
    for (int t=0;t<8;++t) ge[t] = wf[OFF_GATE_B1 + 8*wv + t];
    for (int k=0;k<64;++k){
      float a = smf[k*PF + lane];
      const float* wr = wf + OFF_GATE_W1 + k*64 + 8*wv;
      #pragma unroll
      for (int t=0;t<8;++t) ge[t] += a*wr[t];
    }
    #pragma unroll
    for (int t=0;t<8;++t) smf[(64 + 8*wv + t)*PF + lane] = fsilu(ge[t]);
  }
  __syncthreads();                                        // B6

  // P11: go = ge@gate_w2 + b2 -> vg (LDS stash), sgate (LDS, wv0)
  { float vga[8];
    float g0 = wf[OFF_GATE_B2];
    #pragma unroll
    for (int t=0;t<8;++t) vga[t] = wf[OFF_GATE_B2 + 1 + 8*wv + t];
    for (int k=0;k<64;++k){
      float a = smf[(64+k)*PF + lane];
      const float* wr = wf + OFF_GATE_W2 + k*65;
      g0 += a*wr[0];
      #pragma unroll
      for (int t=0;t<8;++t) vga[t] += a*wr[1 + 8*wv + t];
    }
    #pragma unroll
    for (int t=0;t<8;++t) s_vg[t*512 + tid] = fsig(vga[t]);  // same-thread stash
    if (wv == 0){
      float sigma = __expf(wf[OFF_LSIG + etype[e]]);
      s_sgate[lane] = fsig(g0) * __expf(-edist[e]/sigma);
    }
  }
  __syncthreads();                                        // B7 (ES+GE dead)

  // XS stage: wave owns scalar cols [16wv,16wv+16) via 4 float4
  #pragma unroll
  for (int q=0;q<4;++q){
    float4 v = hrow4[4*wv + q];
    int s = 16*wv + 4*q;
    smf[(s+0)*PF + lane] = v.x*sregS[4*q+0];
    smf[(s+1)*PF + lane] = v.y*sregS[4*q+1];
    smf[(s+2)*PF + lane] = v.z*sregS[4*q+2];
    smf[(s+3)*PF + lane] = v.w*sregS[4*q+3];
  }
  __syncthreads();                                        // B8

  // scalar loop k=0..127 (24 FMA/iter/wave)
  float msg_s[16], svv[8];
  #pragma unroll
  for (int j=0;j<16;++j) msg_s[j]=0.f;
  #pragma unroll
  for (int t=0;t<8;++t) svv[t]=0.f;
  for (int k=0;k<128;++k){
    float a = smf[k*PF + lane];
    const float* w0p = wf + OFF_TP00 + k*128 + 16*wv;
    const float* w1p = wf + OFF_TP01 + k*64  + 8*wv;
    #pragma unroll
    for (int j=0;j<16;++j) msg_s[j] += a*w0p[j];
    #pragma unroll
    for (int t=0;t<8;++t)  svv[t]  += a*w1p[t];
  }
  __syncthreads();                                        // B9 (XS dead)

  // rank-1 init: mv = svv*y  (svv dies here)
  float mv[8][3];
  #pragma unroll
  for (int t=0;t<8;++t){ mv[t][0]=svv[t]*y0; mv[t][1]=svv[t]*y1; mv[t][2]=svv[t]*y2; }

  // vec chunk A stage: u in [0,32) by waves 0..3; dot at staging
  if (wv < 4){
    float f[24];
    #pragma unroll
    for (int q=0;q<6;++q){
      float4 v = hrow4[32 + 6*wv + q];
      f[4*q+0]=v.x; f[4*q+1]=v.y; f[4*q+2]=v.z; f[4*q+3]=v.w;
    }
    #pragma unroll
    for (int t=0;t<8;++t){
      int u = 8*wv + t;
      float sc = sregV[t];
      float x0=f[3*t+0]*sc, x1=f[3*t+1]*sc, x2=f[3*t+2]*sc;
      smf[(3*u+0)*PF + lane] = x0;
      smf[(3*u+1)*PF + lane] = x1;
      smf[(3*u+2)*PF + lane] = x2;
      smf[(96+u)*PF + lane] = (x0*y0 + x1*y1 + x2*y2)*INV_SQ3f;
    }
  }
  __syncthreads();                                        // B10

  { for (int ul=0; ul<32; ++ul){
      float x0 = smf[(3*ul+0)*PF + lane];
      float x1 = smf[(3*ul+1)*PF + lane];
      float x2 = smf[(3*ul+2)*PF + lane];
      const float* wr = wf + OFF_TP10 + ul*64 + 8*wv;
      #pragma unroll
      for (int t=0;t<8;++t){ float wt=wr[t]; mv[t][0]+=x0*wt; mv[t][1]+=x1*wt; mv[t][2]+=x2*wt; }
    }
    for (int k=0;k<32;++k){
      float a = smf[(96+k)*PF + lane];
      const float* wr = wf + OFF_TP11 + k*128 + 16*wv;
      #pragma unroll
      for (int j=0;j<16;++j) msg_s[j] += a*wr[j];
    } }
  __syncthreads();                                        // B11

  // vec chunk B stage: u in [32,64) by waves 4..7
  if (wv >= 4){
    float f[24];
    #pragma unroll
    for (int q=0;q<6;++q){
      float4 v = hrow4[32 + 6*wv + q];
      f[4*q+0]=v.x; f[4*q+1]=v.y; f[4*q+2]=v.z; f[4*q+3]=v.w;
    }
    #pragma unroll
    for (int t=0;t<8;++t){
      int um = 8*(wv-4) + t;
      float sc = sregV[t];
      float x0=f[3*t+0]*sc, x1=f[3*t+1]*sc, x2=f[3*t+2]*sc;
      smf[(3*um+0)*PF + lane] = x0;
      smf[(3*um+1)*PF + lane] = x1;
      smf[(3*um+2)*PF + lane] = x2;
      smf[(96+um)*PF + lane] = (x0*y0 + x1*y1 + x2*y2)*INV_SQ3f;
    }
  }
  __syncthreads();                                        // B12

  { for (int ul=0; ul<32; ++ul){
      float x0 = smf[(3*ul+0)*PF + lane];
      float x1 = smf[(3*ul+1)*PF + lane];
      float x2 = smf[(3*ul+2)*PF + lane];
      const float* wr = wf + OFF_TP10 + (32+ul)*64 + 8*wv;
      #pragma unroll
      for (int t=0;t<8;++t){ float wt=wr[t]; mv[t][0]+=x0*wt; mv[t][1]+=x1*wt; mv[t][2]+=x2*wt; }
    }
    for (int k=0;k<32;++k){
      float a = smf[(96+k)*PF + lane];
      const float* wr = wf + OFF_TP11 + (32+k)*128 + 16*wv;
      #pragma unroll
      for (int j=0;j<16;++j) msg_s[j] += a*wr[j];
    } }
  __syncthreads();                                        // B13 (XB/DOT dead)

  // P6: scale_out + silu + vn -> VN [0,64)
  #pragma unroll
  for (int j=0;j<16;++j) msg_s[j] = fsilu(msg_s[j]*souts[j]);
  #pragma unroll
  for (int t=0;t<8;++t){
    mv[t][0]*=soutv[t]; mv[t][1]*=soutv[t]; mv[t][2]*=soutv[t];
    float vn = sqrtf(mv[t][0]*mv[t][0]+mv[t][1]*mv[t][1]+mv[t][2]*mv[t][2]+1e-12f);
    smf[(8*wv + t)*PF + lane] = vn;
  }
  __syncthreads();                                        // B14

  // P7: t1 = silu(vn@act_w1+b1) -> T1 [64,128)
  { float a1[8];
    #pragma unroll
    for (int t=0;t<8;++t) a1[t] = wf[OFF_ACT_B1 + 8*wv + t];
    for (int k=0;k<64;++k){
      float a = smf[k*PF + lane];
      const float* wr = wf + OFF_ACT_W1 + k*64 + 8*wv;
      #pragma unroll
      for (int t=0;t<8;++t) a1[t] += a*wr[t];
    }
    #pragma unroll
    for (int t=0;t<8;++t) smf[(64 + 8*wv + t)*PF + lane] = fsilu(a1[t]);
  }
  __syncthreads();                                        // B15

  // P8: g = sigmoid(t1@act_w2+b2); mv *= g
  { float gq[8];
    #pragma unroll
    for (int t=0;t<8;++t) gq[t] = wf[OFF_ACT_B2 + 8*wv + t];
    for (int k=0;k<64;++k){
      float a = smf[(64+k)*PF + lane];
      const float* wr = wf + OFF_ACT_W2 + k*64 + 8*wv;
      #pragma unroll
      for (int t=0;t<8;++t) gq[t] += a*wr[t];
    }
    #pragma unroll
    for (int t=0;t<8;++t){ float g=fsig(gq[t]); mv[t][0]*=g; mv[t][1]*=g; mv[t][2]*=g; }
  }
  __syncthreads();                                        // B16

  // ===== COALESCED scatter via LDS transpose =====
  // Phase A: sg*msg_s (128 ch)
  { float sg = s_sgate[lane];
    #pragma unroll
    for (int j=0;j<16;++j) smf[(16*wv + j)*PF + lane] = sg*msg_s[j];
  }
  __syncthreads();                                        // B17
  for (int lin=tid; lin<8192; lin+=512){
    int row = lin >> 7, ch = lin & 127;
    atomicAdd(acc_s + (size_t)s_dst[row]*128 + ch, smf[ch*PF + row]);
  }
  __syncthreads();                                        // B18
  // Phase B half 1: u in [0,32) (waves 0..3), 96 ch
  if (wv < 4){
    #pragma unroll
    for (int t=0;t<8;++t){
      int u = 8*wv + t;
      float vgt = s_vg[t*512 + tid];
      smf[(3*u+0)*PF + lane] = vgt*mv[t][0];
      smf[(3*u+1)*PF + lane] = vgt*mv[t][1];
      smf[(3*u+2)*PF + lane] = vgt*mv[t][2];
    }
  }
  __syncthreads();                                        // B19
  for (int lin=tid; lin<6144; lin+=512){
    int row = lin / 96, ch = lin % 96;
    atomicAdd(acc_v + (size_t)s_dst[row]*192 + ch, smf[ch*PF + row]);
  }
  __syncthreads();                                        // B20
  // Phase B half 2: u in [32,64) (waves 4..7), 96 ch
  if (wv >= 4){
    #pragma unroll
    for (int t=0;t<8;++t){
      int um = 8*(wv-4) + t;
      float vgt = s_vg[t*512 + tid];
      smf[(3*um+0)*PF + lane] = vgt*mv[t][0];
      smf[(3*um+1)*PF + lane] = vgt*mv[t][1];
      smf[(3*um+2)*PF + lane] = vgt*mv[t][2];
    }
  }
  __syncthreads();                                        // B21
  for (int lin=tid; lin<6144; lin+=512){
    int row = lin / 96, ch = lin % 96;
    atomicAdd(acc_v + (size_t)s_dst[row]*192 + 96 + ch, smf[ch*PF + row]);
  }
  __syncthreads();                                        // B22
  // Phase C: vg (64 ch) + sg
  #pragma unroll
  for (int t=0;t<8;++t) smf[(8*wv + t)*PF + lane] = s_vg[t*512 + tid];
  __syncthreads();                                        // B23
  for (int lin=tid; lin<4096; lin+=512){
    int row = lin >> 6, ch = lin & 63;
    atomicAdd(acc_vg + (size_t)s_dst[row]*64 + ch, smf[ch*PF + row]);
  }
  if (tid < 64) atomicAdd(acc_sg + s_dst[tid], s_sgate[tid]);
}

// ---------------- node kernel ----------------
__launch_bounds__(256,2)
__global__ void k_node(const float* __restrict__ h, const float* __restrict__ wf,
                       const float* __restrict__ acc_s, const float* __restrict__ acc_sg,
                       const float* __restrict__ acc_vg, const float* __restrict__ acc_v,
                       float* __restrict__ out)
{
  __shared__ float smf[160*PF];
  const int tid  = threadIdx.x;
  const int lane = tid & 63;
  const int wv   = __builtin_amdgcn_readfirstlane(tid >> 6);
  const int n0   = blockIdx.x * 64;
  const int n    = n0 + lane;
  const int w0   = 16*wv;

  float agg[16][3], vnr[16], sva[16][3];
  #pragma unroll
  for (int t=0;t<16;++t){
    float inv = 1.f/(acc_vg[n*64 + w0 + t] + 1e-6f);
    agg[t][0] = acc_v[n*192 + (w0+t)*3 + 0]*inv;
    agg[t][1] = acc_v[n*192 + (w0+t)*3 + 1]*inv;
    agg[t][2] = acc_v[n*192 + (w0+t)*3 + 2]*inv;
    vnr[t] = sqrtf(agg[t][0]*agg[t][0]+agg[t][1]*agg[t][1]+agg[t][2]*agg[t][2]+1e-12f);
    smf[(96 + w0 + t)*PF + lane] = vnr[t];
    sva[t][0]=0.f; sva[t][1]=0.f; sva[t][2]=0.f;
  }

  float outs[32];
  #pragma unroll
  for (int j=0;j<32;++j) outs[j] = wf[OFF_SELF_BS + 32*wv + j];

  for (int cc=0; cc<2; ++cc){
    for (int lin=tid; lin<1024; lin+=256){
      int row = lin>>4, c4 = lin&15;
      float4 v = reinterpret_cast<const float4*>(h)[(n0+row)*80 + cc*16 + c4];
      smf[(c4*4+0)*PF + row] = v.x;
      smf[(c4*4+1)*PF + row] = v.y;
      smf[(c4*4+2)*PF + row] = v.z;
      smf[(c4*4+3)*PF + row] = v.w;
    }
    __syncthreads();
    for (int k=0;k<64;++k){
      float a = smf[k*PF + lane];
      const float* wr = wf + OFF_SELF_WS + (cc*64+k)*128 + 32*wv;
      #pragma unroll
      for (int j=0;j<32;++j) outs[j] += a*wr[j];
    }
    __syncthreads();
  }
  for (int cc=0; cc<2; ++cc){
    for (int lin=tid; lin<1536; lin+=256){
      int row = lin/24, c6 = lin%24;
      float4 v = reinterpret_cast<const float4*>(h)[(n0+row)*80 + 32 + cc*24 + c6];
      smf[(c6*4+0)*PF + row] = v.x;
      smf[(c6*4+1)*PF + row] = v.y;
      smf[(c6*4+2)*PF + row] = v.z;
      smf[(c6*4+3)*PF + row] = v.w;
    }
    __syncthreads();
    for (int ul=0; ul<32; ++ul){
      float x0 = smf[(3*ul+0)*PF + lane];
      float x1 = smf[(3*ul+1)*PF + lane];
      float x2 = smf[(3*ul+2)*PF + lane];
      const float* wr = wf + OFF_SELF_WV + (cc*32+ul)*64 + w0;
      #pragma unroll
      for (int t=0;t<16;++t){ float wt=wr[t]; sva[t][0]+=x0*wt; sva[t][1]+=x1*wt; sva[t][2]+=x2*wt; }
    }
    __syncthreads();
  }

  float rv[16];
  #pragma unroll
  for (int t=0;t<16;++t) rv[t] = wf[OFF_VR_B + w0 + t];
  for (int k=0;k<64;++k){
    float a = smf[(96+k)*PF + lane];
    const float* wr = wf + OFF_VR_W + k*64 + w0;
    #pragma unroll
    for (int t=0;t<16;++t) rv[t] += a*wr[t];
  }

  { float inv = 1.f/(acc_sg[n] + 1e-6f);
    #pragma unroll
    for (int j=0;j<32;++j) outs[j] += acc_s[n*128 + 32*wv + j]*inv;
  }

  float* orow = out + (size_t)n*320;
  { float4* o4 = reinterpret_cast<float4*>(orow + 32*wv);
    #pragma unroll
    for (int j=0;j<8;++j){
      float4 v; v.x=outs[4*j]; v.y=outs[4*j+1]; v.z=outs[4*j+2]; v.w=outs[4*j+3];
      o4[j] = v;
    }
  }
  { float vbuf[48];
    #pragma unroll
    for (int t=0;t<16;++t){
      float sc = rv[t]/(vnr[t]+1e-6f);
      vbuf[t*3+0] = agg[t][0]*sc + sva[t][0];
      vbuf[t*3+1] = agg[t][1]*sc + sva[t][1];
      vbuf[t*3+2] = agg[t][2]*sc + sva[t][2];
    }
    float4* o4 = reinterpret_cast<float4*>(orow + 128 + 48*wv);
    #pragma unroll
    for (int j=0;j<12;++j){
      float4 v; v.x=vbuf[4*j]; v.y=vbuf[4*j+1]; v.z=vbuf[4*j+2]; v.w=vbuf[4*j+3];
      o4[j] = v;
    }
  }
}

// ---------------- launch ----------------
extern "C" void kernel_launch(void* const* d_in, const int* in_sizes, int n_in,
                              void* d_out, int out_size, void* d_ws, size_t ws_size,
                              hipStream_t stream) {
  const float* h     = (const float*)d_in[0];
  const float* evec  = (const float*)d_in[1];
  const float* es    = (const float*)d_in[2];
  const float* edist = (const float*)d_in[3];
  const int* srcI    = (const int*)d_in[4];
  const int* dstI    = (const int*)d_in[5];
  const int* etyp    = (const int*)d_in[6];

  float* wsf    = (float*)d_ws;
  float* acc_s  = wsf + ACC_S_OFF;
  float* acc_sg = wsf + ACC_SG_OFF;
  float* acc_vg = wsf + ACC_VG_OFF;
  float* acc_v  = wsf + ACC_V_OFF;

  WCopy wc;
  const int ns[24]  = {8192,128,24576,192,24576,192,16384,8192,4096,8192,4096,64,4096,64,
                       4096,64,4160,65,10,4096,64,16384,128,4096};
  const int offs[24]= {OFF_RT_W,OFF_RT_B,OFF_RIN_W,OFF_RIN_B,OFF_ROUT_W,OFF_ROUT_B,
                       OFF_TP00,OFF_TP01,OFF_TP10,OFF_TP11,OFF_ACT_W1,OFF_ACT_B1,
                       OFF_ACT_W2,OFF_ACT_B2,OFF_GATE_W1,OFF_GATE_B1,OFF_GATE_W2,OFF_GATE_B2,
                       OFF_LSIG,OFF_VR_W,OFF_VR_B,OFF_SELF_WS,OFF_SELF_BS,OFF_SELF_WV};
  for (int a=0;a<24;++a){ wc.src[a] = (const float*)d_in[8+a]; wc.n[a]=ns[a]; wc.off[a]=offs[a]; }
  hipLaunchKernelGGL(k_copy, dim3(533), dim3(256), 0, stream, wc, wsf);

  { int nz = ACC_END - ACC_S_OFF;
    hipLaunchKernelGGL(k_zero, dim3((nz+255)/256), dim3(256), 0, stream, acc_s, nz); }

  hipLaunchKernelGGL(k_edge, dim3(N_EDGES/64), dim3(512), 0, stream,
                     h, evec, es, edist, srcI, dstI, etyp, wsf,
                     acc_s, acc_sg, acc_vg, acc_v);
  hipLaunchKernelGGL(k_node, dim3(N_NODES/64), dim3(256), 0, stream,
                     h, wsf, acc_s, acc_sg, acc_vg, acc_v, (float*)d_out);
}

// Round 8
// 1605.092 us; speedup vs baseline: 1.6462x; 1.1692x over previous
//
#include <hip/hip_runtime.h>

typedef unsigned int u32;

#define N_NODES 32768
#define N_EDGES 262144
#define PF 65   // LDS pitch (floats): 64 edges + 1 pad

// ---------- fp32 weight buffer layout (float offsets in d_ws) ----------
enum : int {
  OFF_RT_W   = 0,       // [64,128]
  OFF_RT_B   = 8192,    // [128]
  OFF_RIN_W  = 8320,    // [128,192]  (stored PERMUTED for 8-wave ownership:
                        //  scalar col c<128 -> (c>>4)*24 + (c&15)
                        //  vec u=c-128     -> (u>>3)*24 + 16 + (u&7))
  OFF_RIN_B  = 32896,   // [192] (unpermuted)
  OFF_ROUT_W = 33088,   // [128,192]
  OFF_ROUT_B = 57664,   // [192]
  OFF_TP00   = 57856,   // [128,128]
  OFF_TP01   = 74240,   // [128,64]
  OFF_TP10   = 82432,   // [64,64]
  OFF_TP11   = 86528,   // [64,128]
  OFF_ACT_W1 = 94720,   // [64,64]
  OFF_ACT_B1 = 98816,   // [64]
  OFF_ACT_W2 = 98880,   // [64,64]
  OFF_ACT_B2 = 102976,  // [64]
  OFF_GATE_W1= 103040,  // [64,64]
  OFF_GATE_B1= 107136,  // [64]
  OFF_GATE_W2= 107200,  // [64,65]
  OFF_GATE_B2= 111360,  // [65]
  OFF_LSIG   = 111428,  // [10]
  OFF_VR_W   = 111440,  // [64,64]
  OFF_VR_B   = 115536,  // [64]
  OFF_SELF_WS= 115600,  // [128,128]
  OFF_SELF_BS= 131984,  // [128]
  OFF_SELF_WV= 132112,  // [64,64]
  NWF        = 136208
};
enum : int {
  ACC_S_OFF  = NWF,
  ACC_SG_OFF = ACC_S_OFF + N_NODES*128,
  ACC_VG_OFF = ACC_SG_OFF + N_NODES,
  ACC_V_OFF  = ACC_VG_OFF + N_NODES*64,
  ACC_END    = ACC_V_OFF + N_NODES*192
};

__device__ __forceinline__ float fsilu(float x){ return x/(1.f+__expf(-x)); }
__device__ __forceinline__ float fsig (float x){ return 1.f/(1.f+__expf(-x)); }

#define SQ3f     1.7320508075688772f
#define INV_SQ3f 0.5773502691896258f

__global__ void k_zero(float* __restrict__ p, int n){
  int t = blockIdx.x*256 + threadIdx.x;
  if (t < n) p[t] = 0.f;
}

// weight copy; tensor index 2 (rin_w) permuted so wave wv (of 8) owns a
// contiguous 24-slot slice [24wv,24wv+24):
//   scalar cols [16wv,16wv+16) -> slots [24wv, 24wv+16)
//   vec u's    [ 8wv, 8wv+ 8)  -> slots [24wv+16, 24wv+24)
struct WCopy { const float* src[24]; int n[24]; int off[24]; };

__global__ void k_copy(WCopy w, float* __restrict__ dst){
  int t = blockIdx.x*256 + threadIdx.x;
  for (int a=0;a<24;++a){
    int n = w.n[a];
    if (t < n){
      if (a == 2){
        int k = t/192, c = t%192;
        int dc = (c < 128) ? ((c>>4)*24 + (c&15))
                           : ((((c-128)>>3)*24) + 16 + ((c-128)&7));
        dst[w.off[a] + k*192 + dc] = w.src[a][t];
      } else {
        dst[w.off[a]+t] = w.src[a][t];
      }
      return;
    }
    t -= n;
  }
}

// ---------------- edge kernel ----------------
// R8: 8-wave structure, spill-free schedule.
// R7 lesson: LDS 50KB allowed 3 blocks -> compiler targeted 6 waves/SIMD ->
// 64-reg granule -> spilled ~25 floats (souts/soutv/sregV) to scratch
// (FETCH 667MB / WRITE 1.28GB) while runtime ran 2 blocks anyway.
// Fixes: (1) arena 192 ch (66.8KB total) -> LDS forces 2 blocks -> compiler
// targets 4 waves/SIMD -> 128-reg budget. (2) trunk stays RESIDENT in
// [64,192) through TP (staging confined to [0,64)); rout GEMM moved AFTER
// TP so souts/soutv live only briefly. Gate path runs first (vg -> s_vg).
// Peak live floats ~76 -> no spill.
__launch_bounds__(512,4)
__global__ void k_edge(const float* __restrict__ h, const float* __restrict__ evec,
                       const float* __restrict__ es_g, const float* __restrict__ edist,
                       const int* __restrict__ src_idx, const int* __restrict__ dst_idx,
                       const int* __restrict__ etype, const float* __restrict__ wf,
                       float* __restrict__ acc_s, float* __restrict__ acc_sg,
                       float* __restrict__ acc_vg, float* __restrict__ acc_v)
{
  __shared__ float smf[192*PF];     // [0,64) staging/VN ; [64,192) trunk (resident)
  __shared__ float s_vg[8*512];     // vg stash: [t][tid]
  __shared__ float s_sgate[64];
  __shared__ int   s_dst[64];

  const int tid  = threadIdx.x;
  const int lane = tid & 63;
  const int wv   = __builtin_amdgcn_readfirstlane(tid >> 6);   // 0..7
  const int e0   = blockIdx.x * 64;
  const int e    = e0 + lane;

  if (tid >= 64 && tid < 128) s_dst[tid-64] = dst_idx[e0 + tid-64];

  const int srcn = src_idx[e];
  const float* hrow = h + (size_t)srcn*320;
  const float4* hrow4 = reinterpret_cast<const float4*>(hrow);

  float y0,y1,y2;
  { float vx=evec[e*3], vy=evec[e*3+1], vz=evec[e*3+2];
    float rn = SQ3f * rsqrtf(vx*vx+vy*vy+vz*vz+1e-12f);
    y0=vx*rn; y1=vy*rn; y2=vz*rn; }

  // P0: stage edge_scalars -> ES [0,64)
  for (int lin=tid; lin<1024; lin+=512){
    int row = lin>>4, c4 = lin&15;
    float4 v = reinterpret_cast<const float4*>(es_g)[(e0+row)*16 + c4];
    smf[(c4*4+0)*PF + row] = v.x;
    smf[(c4*4+1)*PF + row] = v.y;
    smf[(c4*4+2)*PF + row] = v.z;
    smf[(c4*4+3)*PF + row] = v.w;
  }
  __syncthreads();                                        // B1

  // GATE 1: ge = silu(es@gate_w1+b1) -> [64,128)
  { float ge[8];
    #pragma unroll
    for (int t=0;t<8;++t) ge[t] = wf[OFF_GATE_B1 + 8*wv + t];
    for (int k=0;k<64;++k){
      float a = smf[k*PF + lane];
      const float* wr = wf + OFF_GATE_W1 + k*64 + 8*wv;
      #pragma unroll
      for (int t=0;t<8;++t) ge[t] += a*wr[t];
    }
    #pragma unroll
    for (int t=0;t<8;++t) smf[(64 + 8*wv + t)*PF + lane] = fsilu(ge[t]);
  }
  __syncthreads();                                        // B2

  // GATE 2: go = ge@gate_w2 + b2 -> vg stash (s_vg), sgate
  { float vga[8];
    float g0 = wf[OFF_GATE_B2];
    #pragma unroll
    for (int t=0;t<8;++t) vga[t] = wf[OFF_GATE_B2 + 1 + 8*wv + t];
    for (int k=0;k<64;++k){
      float a = smf[(64+k)*PF + lane];
      const float* wr = wf + OFF_GATE_W2 + k*65;
      g0 += a*wr[0];
      #pragma unroll
      for (int t=0;t<8;++t) vga[t] += a*wr[1 + 8*wv + t];
    }
    #pragma unroll
    for (int t=0;t<8;++t) s_vg[t*512 + tid] = fsig(vga[t]);
    if (wv == 0){
      float sigma = __expf(wf[OFF_LSIG + etype[e]]);
      s_sgate[lane] = fsig(g0) * __expf(-edist[e]/sigma);
    }
  }
  __syncthreads();                                        // B3 (GE dead)

  // P1: trunk = silu(es@rt_w+b), 16 cols/wave -> [64,192)  (RESIDENT)
  { float acc[16];
    #pragma unroll
    for (int j=0;j<16;++j) acc[j] = wf[OFF_RT_B + 16*wv + j];
    for (int k=0;k<64;++k){
      float a = smf[k*PF + lane];
      const float* wr = wf + OFF_RT_W + k*128 + 16*wv;
      #pragma unroll
      for (int j=0;j<16;++j) acc[j] += a*wr[j];
    }
    #pragma unroll
    for (int j=0;j<16;++j) smf[(64 + 16*wv + j)*PF + lane] = fsilu(acc[j]);
  }
  __syncthreads();                                        // B4 (ES dead)

  // P2: scale_in only (sregS[16], sregV[8]) over full trunk
  float sregS[16], sregV[8];
  #pragma unroll
  for (int i=0;i<16;++i) sregS[i] = 1.f + wf[OFF_RIN_B + 16*wv + i];
  #pragma unroll
  for (int t=0;t<8;++t)  sregV[t] = 1.f + wf[OFF_RIN_B + 128 + 8*wv + t];
  for (int k=0;k<128;++k){
    float a = smf[(64+k)*PF + lane];
    const float* wi = wf + OFF_RIN_W + k*192 + 24*wv;
    #pragma unroll
    for (int i=0;i<16;++i) sregS[i] += a*wi[i];
    #pragma unroll
    for (int t=0;t<8;++t)  sregV[t] += a*wi[16+t];
  }
  // (no barrier: next writes [0,64); all es readers passed B4)

  float msg_s[16], svv[8];
  #pragma unroll
  for (int j=0;j<16;++j) msg_s[j]=0.f;
  #pragma unroll
  for (int t=0;t<8;++t) svv[t]=0.f;

  // ---- TP scalar, chunk 0: cols [0,64) staged by waves 0..3 into [0,64) ----
  if (wv < 4){
    #pragma unroll
    for (int q=0;q<4;++q){
      float4 v = hrow4[4*wv + q];
      int s = 16*wv + 4*q;
      smf[(s+0)*PF + lane] = v.x*sregS[4*q+0];
      smf[(s+1)*PF + lane] = v.y*sregS[4*q+1];
      smf[(s+2)*PF + lane] = v.z*sregS[4*q+2];
      smf[(s+3)*PF + lane] = v.w*sregS[4*q+3];
    }
  }
  __syncthreads();                                        // B5
  for (int k=0;k<64;++k){
    float a = smf[k*PF + lane];
    const float* w0p = wf + OFF_TP00 + k*128 + 16*wv;
    const float* w1p = wf + OFF_TP01 + k*64  + 8*wv;
    #pragma unroll
    for (int j=0;j<16;++j) msg_s[j] += a*w0p[j];
    #pragma unroll
    for (int t=0;t<8;++t)  svv[t]  += a*w1p[t];
  }
  __syncthreads();                                        // B6
  // ---- TP scalar, chunk 1: cols [64,128) staged by waves 4..7 ----
  if (wv >= 4){
    #pragma unroll
    for (int q=0;q<4;++q){
      float4 v = hrow4[4*wv + q];
      int s = 16*(wv-4) + 4*q;
      smf[(s+0)*PF + lane] = v.x*sregS[4*q+0];
      smf[(s+1)*PF + lane] = v.y*sregS[4*q+1];
      smf[(s+2)*PF + lane] = v.z*sregS[4*q+2];
      smf[(s+3)*PF + lane] = v.w*sregS[4*q+3];
    }
  }
  __syncthreads();                                        // B7
  for (int k=0;k<64;++k){
    float a = smf[k*PF + lane];
    const float* w0p = wf + OFF_TP00 + (64+k)*128 + 16*wv;
    const float* w1p = wf + OFF_TP01 + (64+k)*64  + 8*wv;
    #pragma unroll
    for (int j=0;j<16;++j) msg_s[j] += a*w0p[j];
    #pragma unroll
    for (int t=0;t<8;++t)  svv[t]  += a*w1p[t];
  }
  __syncthreads();                                        // B8

  // rank-1 init: mv = svv*y (svv dies)
  float mv[8][3];
  #pragma unroll
  for (int t=0;t<8;++t){ mv[t][0]=svv[t]*y0; mv[t][1]=svv[t]*y1; mv[t][2]=svv[t]*y2; }

  // ---- TP vector: 4 chunks of 16 u's; XB [0,48) + DOT [48,64) ----
  for (int vc=0; vc<4; ++vc){
    if ((wv>>1) == vc){
      const int half = wv & 1;
      float dreg[8];
      #pragma unroll
      for (int t=0;t<8;++t) dreg[t]=0.f;
      #pragma unroll
      for (int q=0;q<6;++q){
        float4 v = hrow4[32 + 6*wv + q];
        float vv[4] = {v.x, v.y, v.z, v.w};
        #pragma unroll
        for (int c=0;c<4;++c){
          int l = 4*q + c;             // 0..23
          int t = l/3, d = l - 3*t;    // compile-time
          float x = vv[c]*sregV[t];
          smf[(3*(8*half + t) + d)*PF + lane] = x;
          dreg[t] += x * (d==0 ? y0 : (d==1 ? y1 : y2));
        }
      }
      #pragma unroll
      for (int t=0;t<8;++t)
        smf[(48 + 8*half + t)*PF + lane] = dreg[t]*INV_SQ3f;
    }
    __syncthreads();                                      // stage done
    for (int ul=0; ul<16; ++ul){
      float x0 = smf[(3*ul+0)*PF + lane];
      float x1 = smf[(3*ul+1)*PF + lane];
      float x2 = smf[(3*ul+2)*PF + lane];
      const float* wr = wf + OFF_TP10 + (16*vc + ul)*64 + 8*wv;
      #pragma unroll
      for (int t=0;t<8;++t){ float wt=wr[t]; mv[t][0]+=x0*wt; mv[t][1]+=x1*wt; mv[t][2]+=x2*wt; }
    }
    for (int k=0;k<16;++k){
      float a = smf[(48+k)*PF + lane];
      const float* wr = wf + OFF_TP11 + (16*vc + k)*128 + 16*wv;
      #pragma unroll
      for (int j=0;j<16;++j) msg_s[j] += a*wr[j];
    }
    __syncthreads();                                      // compute done
  }

  // ---- rout pass (LATE): souts/soutv from resident trunk ----
  float souts[16], soutv[8];
  #pragma unroll
  for (int j=0;j<16;++j) souts[j] = 1.f + wf[OFF_ROUT_B + 16*wv + j];
  #pragma unroll
  for (int t=0;t<8;++t)  soutv[t] = 1.f + wf[OFF_ROUT_B + 128 + 8*wv + t];
  for (int k=0;k<128;++k){
    float a = smf[(64+k)*PF + lane];
    const float* wo = wf + OFF_ROUT_W + k*192;
    #pragma unroll
    for (int j=0;j<16;++j) souts[j] += a*wo[16*wv + j];
    #pragma unroll
    for (int t=0;t<8;++t)  soutv[t] += a*wo[128 + 8*wv + t];
  }

  // P6: apply scale_out + silu + vn -> VN [0,64)
  #pragma unroll
  for (int j=0;j<16;++j) msg_s[j] = fsilu(msg_s[j]*souts[j]);
  #pragma unroll
  for (int t=0;t<8;++t){
    mv[t][0]*=soutv[t]; mv[t][1]*=soutv[t]; mv[t][2]*=soutv[t];
    float vn = sqrtf(mv[t][0]*mv[t][0]+mv[t][1]*mv[t][1]+mv[t][2]*mv[t][2]+1e-12f);
    smf[(8*wv + t)*PF + lane] = vn;
  }
  __syncthreads();                                        // B17 (trunk reads done)

  // P7: t1 = silu(vn@act_w1+b1) -> T1 [64,128) (overwrites trunk lo-half)
  { float a1[8];
    #pragma unroll
    for (int t=0;t<8;++t) a1[t] = wf[OFF_ACT_B1 + 8*wv + t];
    for (int k=0;k<64;++k){
      float a = smf[k*PF + lane];
      const float* wr = wf + OFF_ACT_W1 + k*64 + 8*wv;
      #pragma unroll
      for (int t=0;t<8;++t) a1[t] += a*wr[t];
    }
    #pragma unroll
    for (int t=0;t<8;++t) smf[(64 + 8*wv + t)*PF + lane] = fsilu(a1[t]);
  }
  __syncthreads();                                        // B18

  // P8: g = sigmoid(t1@act_w2+b2); mv *= g
  { float gq[8];
    #pragma unroll
    for (int t=0;t<8;++t) gq[t] = wf[OFF_ACT_B2 + 8*wv + t];
    for (int k=0;k<64;++k){
      float a = smf[(64+k)*PF + lane];
      const float* wr = wf + OFF_ACT_W2 + k*64 + 8*wv;
      #pragma unroll
      for (int t=0;t<8;++t) gq[t] += a*wr[t];
    }
    #pragma unroll
    for (int t=0;t<8;++t){ float g=fsig(gq[t]); mv[t][0]*=g; mv[t][1]*=g; mv[t][2]*=g; }
  }
  __syncthreads();                                        // B19

  // ===== COALESCED scatter via LDS transpose =====
  // Phase A: sg*msg_s (128 ch)
  { float sg = s_sgate[lane];
    #pragma unroll
    for (int j=0;j<16;++j) smf[(16*wv + j)*PF + lane] = sg*msg_s[j];
  }
  __syncthreads();
  for (int lin=tid; lin<8192; lin+=512){
    int row = lin >> 7, ch = lin & 127;
    atomicAdd(acc_s + (size_t)s_dst[row]*128 + ch, smf[ch*PF + row]);
  }
  __syncthreads();
  // Phase B half 1: u in [0,32) (waves 0..3), 96 ch
  if (wv < 4){
    #pragma unroll
    for (int t=0;t<8;++t){
      int u = 8*wv + t;
      float vgt = s_vg[t*512 + tid];
      smf[(3*u+0)*PF + lane] = vgt*mv[t][0];
      smf[(3*u+1)*PF + lane] = vgt*mv[t][1];
      smf[(3*u+2)*PF + lane] = vgt*mv[t][2];
    }
  }
  __syncthreads();
  for (int lin=tid; lin<6144; lin+=512){
    int row = lin / 96, ch = lin % 96;
    atomicAdd(acc_v + (size_t)s_dst[row]*192 + ch, smf[ch*PF + row]);
  }
  __syncthreads();
  // Phase B half 2: u in [32,64) (waves 4..7), 96 ch
  if (wv >= 4){
    #pragma unroll
    for (int t=0;t<8;++t){
      int um = 8*(wv-4) + t;
      float vgt = s_vg[t*512 + tid];
      smf[(3*um+0)*PF + lane] = vgt*mv[t][0];
      smf[(3*um+1)*PF + lane] = vgt*mv[t][1];
      smf[(3*um+2)*PF + lane] = vgt*mv[t][2];
    }
  }
  __syncthreads();
  for (int lin=tid; lin<6144; lin+=512){
    int row = lin / 96, ch = lin % 96;
    atomicAdd(acc_v + (size_t)s_dst[row]*192 + 96 + ch, smf[ch*PF + row]);
  }
  __syncthreads();
  // Phase C: vg (64 ch) + sg
  #pragma unroll
  for (int t=0;t<8;++t) smf[(8*wv + t)*PF + lane] = s_vg[t*512 + tid];
  __syncthreads();
  for (int lin=tid; lin<4096; lin+=512){
    int row = lin >> 6, ch = lin & 63;
    atomicAdd(acc_vg + (size_t)s_dst[row]*64 + ch, smf[ch*PF + row]);
  }
  if (tid < 64) atomicAdd(acc_sg + s_dst[tid], s_sgate[tid]);
}

// ---------------- node kernel ----------------
__launch_bounds__(256,2)
__global__ void k_node(const float* __restrict__ h, const float* __restrict__ wf,
                       const float* __restrict__ acc_s, const float* __restrict__ acc_sg,
                       const float* __restrict__ acc_vg, const float* __restrict__ acc_v,
                       float* __restrict__ out)
{
  __shared__ float smf[160*PF];
  const int tid  = threadIdx.x;
  const int lane = tid & 63;
  const int wv   = __builtin_amdgcn_readfirstlane(tid >> 6);
  const int n0   = blockIdx.x * 64;
  const int n    = n0 + lane;
  const int w0   = 16*wv;

  float agg[16][3], vnr[16], sva[16][3];
  #pragma unroll
  for (int t=0;t<16;++t){
    float inv = 1.f/(acc_vg[n*64 + w0 + t] + 1e-6f);
    agg[t][0] = acc_v[n*192 + (w0+t)*3 + 0]*inv;
    agg[t][1] = acc_v[n*192 + (w0+t)*3 + 1]*inv;
    agg[t][2] = acc_v[n*192 + (w0+t)*3 + 2]*inv;
    vnr[t] = sqrtf(agg[t][0]*agg[t][0]+agg[t][1]*agg[t][1]+agg[t][2]*agg[t][2]+1e-12f);
    smf[(96 + w0 + t)*PF + lane] = vnr[t];
    sva[t][0]=0.f; sva[t][1]=0.f; sva[t][2]=0.f;
  }

  float outs[32];
  #pragma unroll
  for (int j=0;j<32;++j) outs[j] = wf[OFF_SELF_BS + 32*wv + j];

  for (int cc=0; cc<2; ++cc){
    for (int lin=tid; lin<1024; lin+=256){
      int row = lin>>4, c4 = lin&15;
      float4 v = reinterpret_cast<const float4*>(h)[(n0+row)*80 + cc*16 + c4];
      smf[(c4*4+0)*PF + row] = v.x;
      smf[(c4*4+1)*PF + row] = v.y;
      smf[(c4*4+2)*PF + row] = v.z;
      smf[(c4*4+3)*PF + row] = v.w;
    }
    __syncthreads();
    for (int k=0;k<64;++k){
      float a = smf[k*PF + lane];
      const float* wr = wf + OFF_SELF_WS + (cc*64+k)*128 + 32*wv;
      #pragma unroll
      for (int j=0;j<32;++j) outs[j] += a*wr[j];
    }
    __syncthreads();
  }
  for (int cc=0; cc<2; ++cc){
    for (int lin=tid; lin<1536; lin+=256){
      int row = lin/24, c6 = lin%24;
      float4 v = reinterpret_cast<const float4*>(h)[(n0+row)*80 + 32 + cc*24 + c6];
      smf[(c6*4+0)*PF + row] = v.x;
      smf[(c6*4+1)*PF + row] = v.y;
      smf[(c6*4+2)*PF + row] = v.z;
      smf[(c6*4+3)*PF + row] = v.w;
    }
    __syncthreads();
    for (int ul=0; ul<32; ++ul){
      float x0 = smf[(3*ul+0)*PF + lane];
      float x1 = smf[(3*ul+1)*PF + lane];
      float x2 = smf[(3*ul+2)*PF + lane];
      const float* wr = wf + OFF_SELF_WV + (cc*32+ul)*64 + w0;
      #pragma unroll
      for (int t=0;t<16;++t){ float wt=wr[t]; sva[t][0]+=x0*wt; sva[t][1]+=x1*wt; sva[t][2]+=x2*wt; }
    }
    __syncthreads();
  }

  float rv[16];
  #pragma unroll
  for (int t=0;t<16;++t) rv[t] = wf[OFF_VR_B + w0 + t];
  for (int k=0;k<64;++k){
    float a = smf[(96+k)*PF + lane];
    const float* wr = wf + OFF_VR_W + k*64 + w0;
    #pragma unroll
    for (int t=0;t<16;++t) rv[t] += a*wr[t];
  }

  { float inv = 1.f/(acc_sg[n] + 1e-6f);
    #pragma unroll
    for (int j=0;j<32;++j) outs[j] += acc_s[n*128 + 32*wv + j]*inv;
  }

  float* orow = out + (size_t)n*320;
  { float4* o4 = reinterpret_cast<float4*>(orow + 32*wv);
    #pragma unroll
    for (int j=0;j<8;++j){
      float4 v; v.x=outs[4*j]; v.y=outs[4*j+1]; v.z=outs[4*j+2]; v.w=outs[4*j+3];
      o4[j] = v;
    }
  }
  { float vbuf[48];
    #pragma unroll
    for (int t=0;t<16;++t){
      float sc = rv[t]/(vnr[t]+1e-6f);
      vbuf[t*3+0] = agg[t][0]*sc + sva[t][0];
      vbuf[t*3+1] = agg[t][1]*sc + sva[t][1];
      vbuf[t*3+2] = agg[t][2]*sc + sva[t][2];
    }
    float4* o4 = reinterpret_cast<float4*>(orow + 128 + 48*wv);
    #pragma unroll
    for (int j=0;j<12;++j){
      float4 v; v.x=vbuf[4*j]; v.y=vbuf[4*j+1]; v.z=vbuf[4*j+2]; v.w=vbuf[4*j+3];
      o4[j] = v;
    }
  }
}

// ---------------- launch ----------------
extern "C" void kernel_launch(void* const* d_in, const int* in_sizes, int n_in,
                              void* d_out, int out_size, void* d_ws, size_t ws_size,
                              hipStream_t stream) {
  const float* h     = (const float*)d_in[0];
  const float* evec  = (const float*)d_in[1];
  const float* es    = (const float*)d_in[2];
  const float* edist = (const float*)d_in[3];
  const int* srcI    = (const int*)d_in[4];
  const int* dstI    = (const int*)d_in[5];
  const int* etyp    = (const int*)d_in[6];

  float* wsf    = (float*)d_ws;
  float* acc_s  = wsf + ACC_S_OFF;
  float* acc_sg = wsf + ACC_SG_OFF;
  float* acc_vg = wsf + ACC_VG_OFF;
  float* acc_v  = wsf + ACC_V_OFF;

  WCopy wc;
  const int ns[24]  = {8192,128,24576,192,24576,192,16384,8192,4096,8192,4096,64,4096,64,
                       4096,64,4160,65,10,4096,64,16384,128,4096};
  const int offs[24]= {OFF_RT_W,OFF_RT_B,OFF_RIN_W,OFF_RIN_B,OFF_ROUT_W,OFF_ROUT_B,
                       OFF_TP00,OFF_TP01,OFF_TP10,OFF_TP11,OFF_ACT_W1,OFF_ACT_B1,
                       OFF_ACT_W2,OFF_ACT_B2,OFF_GATE_W1,OFF_GATE_B1,OFF_GATE_W2,OFF_GATE_B2,
                       OFF_LSIG,OFF_VR_W,OFF_VR_B,OFF_SELF_WS,OFF_SELF_BS,OFF_SELF_WV};
  for (int a=0;a<24;++a){ wc.src[a] = (const float*)d_in[8+a]; wc.n[a]=ns[a]; wc.off[a]=offs[a]; }
  hipLaunchKernelGGL(k_copy, dim3(533), dim3(256), 0, stream, wc, wsf);

  { int nz = ACC_END - ACC_S_OFF;
    hipLaunchKernelGGL(k_zero, dim3((nz+255)/256), dim3(256), 0, stream, acc_s, nz); }

  hipLaunchKernelGGL(k_edge, dim3(N_EDGES/64), dim3(512), 0, stream,
                     h, evec, es, edist, srcI, dstI, etyp, wsf,
                     acc_s, acc_sg, acc_vg, acc_v);
  hipLaunchKernelGGL(k_node, dim3(N_NODES/64), dim3(256), 0, stream,
                     h, wsf, acc_s, acc_sg, acc_vg, acc_v, (float*)d_out);
}

// Round 9
// 1472.657 us; speedup vs baseline: 1.7942x; 1.0899x over previous
//
#include <hip/hip_runtime.h>

typedef unsigned int u32;

#define N_NODES 32768
#define N_EDGES 262144
#define PF 65   // LDS pitch (floats): 64 edges + 1 pad

// ---------- fp32 weight buffer layout (float offsets in d_ws) ----------
enum : int {
  OFF_RT_W   = 0,       // [64,128]
  OFF_RT_B   = 8192,    // [128]
  OFF_RIN_W  = 8320,    // [128,192]  (stored PERMUTED for 8-wave ownership:
                        //  scalar col c<128 -> (c>>4)*24 + (c&15)
                        //  vec u=c-128     -> (u>>3)*24 + 16 + (u&7))
  OFF_RIN_B  = 32896,   // [192] (unpermuted)
  OFF_ROUT_W = 33088,   // [128,192]
  OFF_ROUT_B = 57664,   // [192]
  OFF_TP00   = 57856,   // [128,128]
  OFF_TP01   = 74240,   // [128,64]
  OFF_TP10   = 82432,   // [64,64]
  OFF_TP11   = 86528,   // [64,128]
  OFF_ACT_W1 = 94720,   // [64,64]
  OFF_ACT_B1 = 98816,   // [64]
  OFF_ACT_W2 = 98880,   // [64,64]
  OFF_ACT_B2 = 102976,  // [64]
  OFF_GATE_W1= 103040,  // [64,64]
  OFF_GATE_B1= 107136,  // [64]
  OFF_GATE_W2= 107200,  // [64,65]
  OFF_GATE_B2= 111360,  // [65]
  OFF_LSIG   = 111428,  // [10]
  OFF_VR_W   = 111440,  // [64,64]
  OFF_VR_B   = 115536,  // [64]
  OFF_SELF_WS= 115600,  // [128,128]
  OFF_SELF_BS= 131984,  // [128]
  OFF_SELF_WV= 132112,  // [64,64]
  NWF        = 136208
};
enum : int {
  ACC_S_OFF  = NWF,
  ACC_SG_OFF = ACC_S_OFF + N_NODES*128,
  ACC_VG_OFF = ACC_SG_OFF + N_NODES,
  ACC_V_OFF  = ACC_VG_OFF + N_NODES*64,
  ACC_END    = ACC_V_OFF + N_NODES*192
};

__device__ __forceinline__ float fsilu(float x){ return x/(1.f+__expf(-x)); }
__device__ __forceinline__ float fsig (float x){ return 1.f/(1.f+__expf(-x)); }

#define SQ3f     1.7320508075688772f
#define INV_SQ3f 0.5773502691896258f

__global__ void k_zero(float* __restrict__ p, int n){
  int t = blockIdx.x*256 + threadIdx.x;
  if (t < n) p[t] = 0.f;
}

// weight copy; tensor index 2 (rin_w) permuted so wave wv (of 8) owns a
// contiguous 24-slot slice [24wv,24wv+24):
//   scalar cols [16wv,16wv+16) -> slots [24wv, 24wv+16)
//   vec u's    [ 8wv, 8wv+ 8)  -> slots [24wv+16, 24wv+24)
struct WCopy { const float* src[24]; int n[24]; int off[24]; };

__global__ void k_copy(WCopy w, float* __restrict__ dst){
  int t = blockIdx.x*256 + threadIdx.x;
  for (int a=0;a<24;++a){
    int n = w.n[a];
    if (t < n){
      if (a == 2){
        int k = t/192, c = t%192;
        int dc = (c < 128) ? ((c>>4)*24 + (c&15))
                           : ((((c-128)>>3)*24) + 16 + ((c-128)&7));
        dst[w.off[a] + k*192 + dc] = w.src[a][t];
      } else {
        dst[w.off[a]+t] = w.src[a][t];
      }
      return;
    }
    t -= n;
  }
}

// ---------------- edge kernel ----------------
// R9 = R8 + unroll-2 on all weight-streaming k-loops.
// R8 spill-free baseline: VGPR=64 of 128-budget (launch_bounds 512,4; LDS
// 67KB pins 2 blocks/CU) -> ~64 regs headroom. The k-loops mix ds_read
// (activation) with s_load (wave-uniform weights); SMEM+DS share lgkmcnt
// and complete out-of-order -> conservative per-iter waits. Unroll-2
// batches 2 iterations of loads behind one wait. (R3's unroll regression
// was at the 170-cap 3-block regime — different budget; watch FETCH/WRITE
// for spill: abort signal is FETCH >> 256MB.)
__launch_bounds__(512,4)
__global__ void k_edge(const float* __restrict__ h, const float* __restrict__ evec,
                       const float* __restrict__ es_g, const float* __restrict__ edist,
                       const int* __restrict__ src_idx, const int* __restrict__ dst_idx,
                       const int* __restrict__ etype, const float* __restrict__ wf,
                       float* __restrict__ acc_s, float* __restrict__ acc_sg,
                       float* __restrict__ acc_vg, float* __restrict__ acc_v)
{
  __shared__ float smf[192*PF];     // [0,64) staging/VN ; [64,192) trunk (resident)
  __shared__ float s_vg[8*512];     // vg stash: [t][tid]
  __shared__ float s_sgate[64];
  __shared__ int   s_dst[64];

  const int tid  = threadIdx.x;
  const int lane = tid & 63;
  const int wv   = __builtin_amdgcn_readfirstlane(tid >> 6);   // 0..7
  const int e0   = blockIdx.x * 64;
  const int e    = e0 + lane;

  if (tid >= 64 && tid < 128) s_dst[tid-64] = dst_idx[e0 + tid-64];

  const int srcn = src_idx[e];
  const float* hrow = h + (size_t)srcn*320;
  const float4* hrow4 = reinterpret_cast<const float4*>(hrow);

  float y0,y1,y2;
  { float vx=evec[e*3], vy=evec[e*3+1], vz=evec[e*3+2];
    float rn = SQ3f * rsqrtf(vx*vx+vy*vy+vz*vz+1e-12f);
    y0=vx*rn; y1=vy*rn; y2=vz*rn; }

  // P0: stage edge_scalars -> ES [0,64)
  for (int lin=tid; lin<1024; lin+=512){
    int row = lin>>4, c4 = lin&15;
    float4 v = reinterpret_cast<const float4*>(es_g)[(e0+row)*16 + c4];
    smf[(c4*4+0)*PF + row] = v.x;
    smf[(c4*4+1)*PF + row] = v.y;
    smf[(c4*4+2)*PF + row] = v.z;
    smf[(c4*4+3)*PF + row] = v.w;
  }
  __syncthreads();                                        // B1

  // GATE 1: ge = silu(es@gate_w1+b1) -> [64,128)
  { float ge[8];
    #pragma unroll
    for (int t=0;t<8;++t) ge[t] = wf[OFF_GATE_B1 + 8*wv + t];
    #pragma unroll 2
    for (int k=0;k<64;++k){
      float a = smf[k*PF + lane];
      const float* wr = wf + OFF_GATE_W1 + k*64 + 8*wv;
      #pragma unroll
      for (int t=0;t<8;++t) ge[t] += a*wr[t];
    }
    #pragma unroll
    for (int t=0;t<8;++t) smf[(64 + 8*wv + t)*PF + lane] = fsilu(ge[t]);
  }
  __syncthreads();                                        // B2

  // GATE 2: go = ge@gate_w2 + b2 -> vg stash (s_vg), sgate
  { float vga[8];
    float g0 = wf[OFF_GATE_B2];
    #pragma unroll
    for (int t=0;t<8;++t) vga[t] = wf[OFF_GATE_B2 + 1 + 8*wv + t];
    #pragma unroll 2
    for (int k=0;k<64;++k){
      float a = smf[(64+k)*PF + lane];
      const float* wr = wf + OFF_GATE_W2 + k*65;
      g0 += a*wr[0];
      #pragma unroll
      for (int t=0;t<8;++t) vga[t] += a*wr[1 + 8*wv + t];
    }
    #pragma unroll
    for (int t=0;t<8;++t) s_vg[t*512 + tid] = fsig(vga[t]);
    if (wv == 0){
      float sigma = __expf(wf[OFF_LSIG + etype[e]]);
      s_sgate[lane] = fsig(g0) * __expf(-edist[e]/sigma);
    }
  }
  __syncthreads();                                        // B3 (GE dead)

  // P1: trunk = silu(es@rt_w+b), 16 cols/wave -> [64,192)  (RESIDENT)
  { float acc[16];
    #pragma unroll
    for (int j=0;j<16;++j) acc[j] = wf[OFF_RT_B + 16*wv + j];
    #pragma unroll 2
    for (int k=0;k<64;++k){
      float a = smf[k*PF + lane];
      const float* wr = wf + OFF_RT_W + k*128 + 16*wv;
      #pragma unroll
      for (int j=0;j<16;++j) acc[j] += a*wr[j];
    }
    #pragma unroll
    for (int j=0;j<16;++j) smf[(64 + 16*wv + j)*PF + lane] = fsilu(acc[j]);
  }
  __syncthreads();                                        // B4 (ES dead)

  // P2: scale_in only (sregS[16], sregV[8]) over full trunk
  float sregS[16], sregV[8];
  #pragma unroll
  for (int i=0;i<16;++i) sregS[i] = 1.f + wf[OFF_RIN_B + 16*wv + i];
  #pragma unroll
  for (int t=0;t<8;++t)  sregV[t] = 1.f + wf[OFF_RIN_B + 128 + 8*wv + t];
  #pragma unroll 2
  for (int k=0;k<128;++k){
    float a = smf[(64+k)*PF + lane];
    const float* wi = wf + OFF_RIN_W + k*192 + 24*wv;
    #pragma unroll
    for (int i=0;i<16;++i) sregS[i] += a*wi[i];
    #pragma unroll
    for (int t=0;t<8;++t)  sregV[t] += a*wi[16+t];
  }
  // (no barrier: next writes [0,64); all es readers passed B4)

  float msg_s[16], svv[8];
  #pragma unroll
  for (int j=0;j<16;++j) msg_s[j]=0.f;
  #pragma unroll
  for (int t=0;t<8;++t) svv[t]=0.f;

  // ---- TP scalar, chunk 0: cols [0,64) staged by waves 0..3 into [0,64) ----
  if (wv < 4){
    #pragma unroll
    for (int q=0;q<4;++q){
      float4 v = hrow4[4*wv + q];
      int s = 16*wv + 4*q;
      smf[(s+0)*PF + lane] = v.x*sregS[4*q+0];
      smf[(s+1)*PF + lane] = v.y*sregS[4*q+1];
      smf[(s+2)*PF + lane] = v.z*sregS[4*q+2];
      smf[(s+3)*PF + lane] = v.w*sregS[4*q+3];
    }
  }
  __syncthreads();                                        // B5
  #pragma unroll 2
  for (int k=0;k<64;++k){
    float a = smf[k*PF + lane];
    const float* w0p = wf + OFF_TP00 + k*128 + 16*wv;
    const float* w1p = wf + OFF_TP01 + k*64  + 8*wv;
    #pragma unroll
    for (int j=0;j<16;++j) msg_s[j] += a*w0p[j];
    #pragma unroll
    for (int t=0;t<8;++t)  svv[t]  += a*w1p[t];
  }
  __syncthreads();                                        // B6
  // ---- TP scalar, chunk 1: cols [64,128) staged by waves 4..7 ----
  if (wv >= 4){
    #pragma unroll
    for (int q=0;q<4;++q){
      float4 v = hrow4[4*wv + q];
      int s = 16*(wv-4) + 4*q;
      smf[(s+0)*PF + lane] = v.x*sregS[4*q+0];
      smf[(s+1)*PF + lane] = v.y*sregS[4*q+1];
      smf[(s+2)*PF + lane] = v.z*sregS[4*q+2];
      smf[(s+3)*PF + lane] = v.w*sregS[4*q+3];
    }
  }
  __syncthreads();                                        // B7
  #pragma unroll 2
  for (int k=0;k<64;++k){
    float a = smf[k*PF + lane];
    const float* w0p = wf + OFF_TP00 + (64+k)*128 + 16*wv;
    const float* w1p = wf + OFF_TP01 + (64+k)*64  + 8*wv;
    #pragma unroll
    for (int j=0;j<16;++j) msg_s[j] += a*w0p[j];
    #pragma unroll
    for (int t=0;t<8;++t)  svv[t]  += a*w1p[t];
  }
  __syncthreads();                                        // B8

  // rank-1 init: mv = svv*y (svv dies)
  float mv[8][3];
  #pragma unroll
  for (int t=0;t<8;++t){ mv[t][0]=svv[t]*y0; mv[t][1]=svv[t]*y1; mv[t][2]=svv[t]*y2; }

  // ---- TP vector: 4 chunks of 16 u's; XB [0,48) + DOT [48,64) ----
  for (int vc=0; vc<4; ++vc){
    if ((wv>>1) == vc){
      const int half = wv & 1;
      float dreg[8];
      #pragma unroll
      for (int t=0;t<8;++t) dreg[t]=0.f;
      #pragma unroll
      for (int q=0;q<6;++q){
        float4 v = hrow4[32 + 6*wv + q];
        float vv[4] = {v.x, v.y, v.z, v.w};
        #pragma unroll
        for (int c=0;c<4;++c){
          int l = 4*q + c;             // 0..23
          int t = l/3, d = l - 3*t;    // compile-time
          float x = vv[c]*sregV[t];
          smf[(3*(8*half + t) + d)*PF + lane] = x;
          dreg[t] += x * (d==0 ? y0 : (d==1 ? y1 : y2));
        }
      }
      #pragma unroll
      for (int t=0;t<8;++t)
        smf[(48 + 8*half + t)*PF + lane] = dreg[t]*INV_SQ3f;
    }
    __syncthreads();                                      // stage done
    #pragma unroll 2
    for (int ul=0; ul<16; ++ul){
      float x0 = smf[(3*ul+0)*PF + lane];
      float x1 = smf[(3*ul+1)*PF + lane];
      float x2 = smf[(3*ul+2)*PF + lane];
      const float* wr = wf + OFF_TP10 + (16*vc + ul)*64 + 8*wv;
      #pragma unroll
      for (int t=0;t<8;++t){ float wt=wr[t]; mv[t][0]+=x0*wt; mv[t][1]+=x1*wt; mv[t][2]+=x2*wt; }
    }
    #pragma unroll 2
    for (int k=0;k<16;++k){
      float a = smf[(48+k)*PF + lane];
      const float* wr = wf + OFF_TP11 + (16*vc + k)*128 + 16*wv;
      #pragma unroll
      for (int j=0;j<16;++j) msg_s[j] += a*wr[j];
    }
    __syncthreads();                                      // compute done
  }

  // ---- rout pass (LATE): souts/soutv from resident trunk ----
  float souts[16], soutv[8];
  #pragma unroll
  for (int j=0;j<16;++j) souts[j] = 1.f + wf[OFF_ROUT_B + 16*wv + j];
  #pragma unroll
  for (int t=0;t<8;++t)  soutv[t] = 1.f + wf[OFF_ROUT_B + 128 + 8*wv + t];
  #pragma unroll 2
  for (int k=0;k<128;++k){
    float a = smf[(64+k)*PF + lane];
    const float* wo = wf + OFF_ROUT_W + k*192;
    #pragma unroll
    for (int j=0;j<16;++j) souts[j] += a*wo[16*wv + j];
    #pragma unroll
    for (int t=0;t<8;++t)  soutv[t] += a*wo[128 + 8*wv + t];
  }

  // P6: apply scale_out + silu + vn -> VN [0,64)
  #pragma unroll
  for (int j=0;j<16;++j) msg_s[j] = fsilu(msg_s[j]*souts[j]);
  #pragma unroll
  for (int t=0;t<8;++t){
    mv[t][0]*=soutv[t]; mv[t][1]*=soutv[t]; mv[t][2]*=soutv[t];
    float vn = sqrtf(mv[t][0]*mv[t][0]+mv[t][1]*mv[t][1]+mv[t][2]*mv[t][2]+1e-12f);
    smf[(8*wv + t)*PF + lane] = vn;
  }
  __syncthreads();                                        // B17 (trunk reads done)

  // P7: t1 = silu(vn@act_w1+b1) -> T1 [64,128) (overwrites trunk lo-half)
  { float a1[8];
    #pragma unroll
    for (int t=0;t<8;++t) a1[t] = wf[OFF_ACT_B1 + 8*wv + t];
    #pragma unroll 2
    for (int k=0;k<64;++k){
      float a = smf[k*PF + lane];
      const float* wr = wf + OFF_ACT_W1 + k*64 + 8*wv;
      #pragma unroll
      for (int t=0;t<8;++t) a1[t] += a*wr[t];
    }
    #pragma unroll
    for (int t=0;t<8;++t) smf[(64 + 8*wv + t)*PF + lane] = fsilu(a1[t]);
  }
  __syncthreads();                                        // B18

  // P8: g = sigmoid(t1@act_w2+b2); mv *= g
  { float gq[8];
    #pragma unroll
    for (int t=0;t<8;++t) gq[t] = wf[OFF_ACT_B2 + 8*wv + t];
    #pragma unroll 2
    for (int k=0;k<64;++k){
      float a = smf[(64+k)*PF + lane];
      const float* wr = wf + OFF_ACT_W2 + k*64 + 8*wv;
      #pragma unroll
      for (int t=0;t<8;++t) gq[t] += a*wr[t];
    }
    #pragma unroll
    for (int t=0;t<8;++t){ float g=fsig(gq[t]); mv[t][0]*=g; mv[t][1]*=g; mv[t][2]*=g; }
  }
  __syncthreads();                                        // B19

  // ===== COALESCED scatter via LDS transpose =====
  // Phase A: sg*msg_s (128 ch)
  { float sg = s_sgate[lane];
    #pragma unroll
    for (int j=0;j<16;++j) smf[(16*wv + j)*PF + lane] = sg*msg_s[j];
  }
  __syncthreads();
  for (int lin=tid; lin<8192; lin+=512){
    int row = lin >> 7, ch = lin & 127;
    atomicAdd(acc_s + (size_t)s_dst[row]*128 + ch, smf[ch*PF + row]);
  }
  __syncthreads();
  // Phase B half 1: u in [0,32) (waves 0..3), 96 ch
  if (wv < 4){
    #pragma unroll
    for (int t=0;t<8;++t){
      int u = 8*wv + t;
      float vgt = s_vg[t*512 + tid];
      smf[(3*u+0)*PF + lane] = vgt*mv[t][0];
      smf[(3*u+1)*PF + lane] = vgt*mv[t][1];
      smf[(3*u+2)*PF + lane] = vgt*mv[t][2];
    }
  }
  __syncthreads();
  for (int lin=tid; lin<6144; lin+=512){
    int row = lin / 96, ch = lin % 96;
    atomicAdd(acc_v + (size_t)s_dst[row]*192 + ch, smf[ch*PF + row]);
  }
  __syncthreads();
  // Phase B half 2: u in [32,64) (waves 4..7), 96 ch
  if (wv >= 4){
    #pragma unroll
    for (int t=0;t<8;++t){
      int um = 8*(wv-4) + t;
      float vgt = s_vg[t*512 + tid];
      smf[(3*um+0)*PF + lane] = vgt*mv[t][0];
      smf[(3*um+1)*PF + lane] = vgt*mv[t][1];
      smf[(3*um+2)*PF + lane] = vgt*mv[t][2];
    }
  }
  __syncthreads();
  for (int lin=tid; lin<6144; lin+=512){
    int row = lin / 96, ch = lin % 96;
    atomicAdd(acc_v + (size_t)s_dst[row]*192 + 96 + ch, smf[ch*PF + row]);
  }
  __syncthreads();
  // Phase C: vg (64 ch) + sg
  #pragma unroll
  for (int t=0;t<8;++t) smf[(8*wv + t)*PF + lane] = s_vg[t*512 + tid];
  __syncthreads();
  for (int lin=tid; lin<4096; lin+=512){
    int row = lin >> 6, ch = lin & 63;
    atomicAdd(acc_vg + (size_t)s_dst[row]*64 + ch, smf[ch*PF + row]);
  }
  if (tid < 64) atomicAdd(acc_sg + s_dst[tid], s_sgate[tid]);
}

// ---------------- node kernel ----------------
__launch_bounds__(256,2)
__global__ void k_node(const float* __restrict__ h, const float* __restrict__ wf,
                       const float* __restrict__ acc_s, const float* __restrict__ acc_sg,
                       const float* __restrict__ acc_vg, const float* __restrict__ acc_v,
                       float* __restrict__ out)
{
  __shared__ float smf[160*PF];
  const int tid  = threadIdx.x;
  const int lane = tid & 63;
  const int wv   = __builtin_amdgcn_readfirstlane(tid >> 6);
  const int n0   = blockIdx.x * 64;
  const int n    = n0 + lane;
  const int w0   = 16*wv;

  float agg[16][3], vnr[16], sva[16][3];
  #pragma unroll
  for (int t=0;t<16;++t){
    float inv = 1.f/(acc_vg[n*64 + w0 + t] + 1e-6f);
    agg[t][0] = acc_v[n*192 + (w0+t)*3 + 0]*inv;
    agg[t][1] = acc_v[n*192 + (w0+t)*3 + 1]*inv;
    agg[t][2] = acc_v[n*192 + (w0+t)*3 + 2]*inv;
    vnr[t] = sqrtf(agg[t][0]*agg[t][0]+agg[t][1]*agg[t][1]+agg[t][2]*agg[t][2]+1e-12f);
    smf[(96 + w0 + t)*PF + lane] = vnr[t];
    sva[t][0]=0.f; sva[t][1]=0.f; sva[t][2]=0.f;
  }

  float outs[32];
  #pragma unroll
  for (int j=0;j<32;++j) outs[j] = wf[OFF_SELF_BS + 32*wv + j];

  for (int cc=0; cc<2; ++cc){
    for (int lin=tid; lin<1024; lin+=256){
      int row = lin>>4, c4 = lin&15;
      float4 v = reinterpret_cast<const float4*>(h)[(n0+row)*80 + cc*16 + c4];
      smf[(c4*4+0)*PF + row] = v.x;
      smf[(c4*4+1)*PF + row] = v.y;
      smf[(c4*4+2)*PF + row] = v.z;
      smf[(c4*4+3)*PF + row] = v.w;
    }
    __syncthreads();
    #pragma unroll 2
    for (int k=0;k<64;++k){
      float a = smf[k*PF + lane];
      const float* wr = wf + OFF_SELF_WS + (cc*64+k)*128 + 32*wv;
      #pragma unroll
      for (int j=0;j<32;++j) outs[j] += a*wr[j];
    }
    __syncthreads();
  }
  for (int cc=0; cc<2; ++cc){
    for (int lin=tid; lin<1536; lin+=256){
      int row = lin/24, c6 = lin%24;
      float4 v = reinterpret_cast<const float4*>(h)[(n0+row)*80 + 32 + cc*24 + c6];
      smf[(c6*4+0)*PF + row] = v.x;
      smf[(c6*4+1)*PF + row] = v.y;
      smf[(c6*4+2)*PF + row] = v.z;
      smf[(c6*4+3)*PF + row] = v.w;
    }
    __syncthreads();
    #pragma unroll 2
    for (int ul=0; ul<32; ++ul){
      float x0 = smf[(3*ul+0)*PF + lane];
      float x1 = smf[(3*ul+1)*PF + lane];
      float x2 = smf[(3*ul+2)*PF + lane];
      const float* wr = wf + OFF_SELF_WV + (cc*32+ul)*64 + w0;
      #pragma unroll
      for (int t=0;t<16;++t){ float wt=wr[t]; sva[t][0]+=x0*wt; sva[t][1]+=x1*wt; sva[t][2]+=x2*wt; }
    }
    __syncthreads();
  }

  float rv[16];
  #pragma unroll
  for (int t=0;t<16;++t) rv[t] = wf[OFF_VR_B + w0 + t];
  #pragma unroll 2
  for (int k=0;k<64;++k){
    float a = smf[(96+k)*PF + lane];
    const float* wr = wf + OFF_VR_W + k*64 + w0;
    #pragma unroll
    for (int t=0;t<16;++t) rv[t] += a*wr[t];
  }

  { float inv = 1.f/(acc_sg[n] + 1e-6f);
    #pragma unroll
    for (int j=0;j<32;++j) outs[j] += acc_s[n*128 + 32*wv + j]*inv;
  }

  float* orow = out + (size_t)n*320;
  { float4* o4 = reinterpret_cast<float4*>(orow + 32*wv);
    #pragma unroll
    for (int j=0;j<8;++j){
      float4 v; v.x=outs[4*j]; v.y=outs[4*j+1]; v.z=outs[4*j+2]; v.w=outs[4*j+3];
      o4[j] = v;
    }
  }
  { float vbuf[48];
    #pragma unroll
    for (int t=0;t<16;++t){
      float sc = rv[t]/(vnr[t]+1e-6f);
      vbuf[t*3+0] = agg[t][0]*sc + sva[t][0];
      vbuf[t*3+1] = agg[t][1]*sc + sva[t][1];
      vbuf[t*3+2] = agg[t][2]*sc + sva[t][2];
    }
    float4* o4 = reinterpret_cast<float4*>(orow + 128 + 48*wv);
    #pragma unroll
    for (int j=0;j<12;++j){
      float4 v; v.x=vbuf[4*j]; v.y=vbuf[4*j+1]; v.z=vbuf[4*j+2]; v.w=vbuf[4*j+3];
      o4[j] = v;
    }
  }
}

// ---------------- launch ----------------
extern "C" void kernel_launch(void* const* d_in, const int* in_sizes, int n_in,
                              void* d_out, int out_size, void* d_ws, size_t ws_size,
                              hipStream_t stream) {
  const float* h     = (const float*)d_in[0];
  const float* evec  = (const float*)d_in[1];
  const float* es    = (const float*)d_in[2];
  const float* edist = (const float*)d_in[3];
  const int* srcI    = (const int*)d_in[4];
  const int* dstI    = (const int*)d_in[5];
  const int* etyp    = (const int*)d_in[6];

  float* wsf    = (float*)d_ws;
  float* acc_s  = wsf + ACC_S_OFF;
  float* acc_sg = wsf + ACC_SG_OFF;
  float* acc_vg = wsf + ACC_VG_OFF;
  float* acc_v  = wsf + ACC_V_OFF;

  WCopy wc;
  const int ns[24]  = {8192,128,24576,192,24576,192,16384,8192,4096,8192,4096,64,4096,64,
                       4096,64,4160,65,10,4096,64,16384,128,4096};
  const int offs[24]= {OFF_RT_W,OFF_RT_B,OFF_RIN_W,OFF_RIN_B,OFF_ROUT_W,OFF_ROUT_B,
                       OFF_TP00,OFF_TP01,OFF_TP10,OFF_TP11,OFF_ACT_W1,OFF_ACT_B1,
                       OFF_ACT_W2,OFF_ACT_B2,OFF_GATE_W1,OFF_GATE_B1,OFF_GATE_W2,OFF_GATE_B2,
                       OFF_LSIG,OFF_VR_W,OFF_VR_B,OFF_SELF_WS,OFF_SELF_BS,OFF_SELF_WV};
  for (int a=0;a<24;++a){ wc.src[a] = (const float*)d_in[8+a]; wc.n[a]=ns[a]; wc.off[a]=offs[a]; }
  hipLaunchKernelGGL(k_copy, dim3(533), dim3(256), 0, stream, wc, wsf);

  { int nz = ACC_END - ACC_S_OFF;
    hipLaunchKernelGGL(k_zero, dim3((nz+255)/256), dim3(256), 0, stream, acc_s, nz); }

  hipLaunchKernelGGL(k_edge, dim3(N_EDGES/64), dim3(512), 0, stream,
                     h, evec, es, edist, srcI, dstI, etyp, wsf,
                     acc_s, acc_sg, acc_vg, acc_v);
  hipLaunchKernelGGL(k_node, dim3(N_NODES/64), dim3(256), 0, stream,
                     h, wsf, acc_s, acc_sg, acc_vg, acc_v, (float*)d_out);
}

// Round 10
// 1465.533 us; speedup vs baseline: 1.8030x; 1.0049x over previous
//
#include <hip/hip_runtime.h>

typedef unsigned int u32;
typedef float f32x2 __attribute__((ext_vector_type(2)));

#define N_NODES 32768
#define N_EDGES 262144
#define PF 65   // LDS pitch (floats): 64 edges + 1 pad

// ---------- fp32 weight buffer layout (float offsets in d_ws) ----------
enum : int {
  OFF_RT_W   = 0,       // [64,128]
  OFF_RT_B   = 8192,    // [128]
  OFF_RIN_W  = 8320,    // [128,192]  (stored PERMUTED for 8-wave ownership:
                        //  scalar col c<128 -> (c>>4)*24 + (c&15)
                        //  vec u=c-128     -> (u>>3)*24 + 16 + (u&7))
  OFF_RIN_B  = 32896,   // [192] (unpermuted)
  OFF_ROUT_W = 33088,   // [128,192]
  OFF_ROUT_B = 57664,   // [192]
  OFF_TP00   = 57856,   // [128,128]
  OFF_TP01   = 74240,   // [128,64]
  OFF_TP10   = 82432,   // [64,64]
  OFF_TP11   = 86528,   // [64,128]
  OFF_ACT_W1 = 94720,   // [64,64]
  OFF_ACT_B1 = 98816,   // [64]
  OFF_ACT_W2 = 98880,   // [64,64]
  OFF_ACT_B2 = 102976,  // [64]
  OFF_GATE_W1= 103040,  // [64,64]
  OFF_GATE_B1= 107136,  // [64]
  OFF_GATE_W2= 107200,  // [64,65]
  OFF_GATE_B2= 111360,  // [65]
  OFF_LSIG   = 111428,  // [10]
  OFF_VR_W   = 111440,  // [64,64]
  OFF_VR_B   = 115536,  // [64]
  OFF_SELF_WS= 115600,  // [128,128]
  OFF_SELF_BS= 131984,  // [128]
  OFF_SELF_WV= 132112,  // [64,64]
  NWF        = 136208
};
enum : int {
  ACC_S_OFF  = NWF,
  ACC_SG_OFF = ACC_S_OFF + N_NODES*128,
  ACC_VG_OFF = ACC_SG_OFF + N_NODES,
  ACC_V_OFF  = ACC_VG_OFF + N_NODES*64,
  ACC_END    = ACC_V_OFF + N_NODES*192
};

__device__ __forceinline__ float fsilu(float x){ return x/(1.f+__expf(-x)); }
__device__ __forceinline__ float fsig (float x){ return 1.f/(1.f+__expf(-x)); }
__device__ __forceinline__ f32x2 ld2(const float* p){ return *reinterpret_cast<const f32x2*>(p); }

#define SQ3f     1.7320508075688772f
#define INV_SQ3f 0.5773502691896258f

__global__ void k_zero(float* __restrict__ p, int n){
  int t = blockIdx.x*256 + threadIdx.x;
  if (t < n) p[t] = 0.f;
}

// weight copy; tensor index 2 (rin_w) permuted so wave wv (of 8) owns a
// contiguous 24-slot slice [24wv,24wv+24):
//   scalar cols [16wv,16wv+16) -> slots [24wv, 24wv+16)
//   vec u's    [ 8wv, 8wv+ 8)  -> slots [24wv+16, 24wv+24)
struct WCopy { const float* src[24]; int n[24]; int off[24]; };

__global__ void k_copy(WCopy w, float* __restrict__ dst){
  int t = blockIdx.x*256 + threadIdx.x;
  for (int a=0;a<24;++a){
    int n = w.n[a];
    if (t < n){
      if (a == 2){
        int k = t/192, c = t%192;
        int dc = (c < 128) ? ((c>>4)*24 + (c&15))
                           : ((((c-128)>>3)*24) + 16 + ((c-128)&7));
        dst[w.off[a] + k*192 + dc] = w.src[a][t];
      } else {
        dst[w.off[a]+t] = w.src[a][t];
      }
      return;
    }
    t -= n;
  }
}

// ---------------- edge kernel ----------------
// R10 = R9 + packed dual-FMA (v_pk_fma_f32) in all streaming GEMM loops.
// f32x2 accumulators + dwordx2 weight loads halve VALU FMA instruction
// count (one VOP3P = 2 FMAs). All weight row offsets are even float
// indices -> 8B-aligned. gate2 stays scalar (stride-65 rows).
// R9 spill-free baseline: VGPR=52/128, FETCH 218MB / WRITE 401MB
// (compulsory). Abort signal: traffic growth = spill.
__launch_bounds__(512,4)
__global__ void k_edge(const float* __restrict__ h, const float* __restrict__ evec,
                       const float* __restrict__ es_g, const float* __restrict__ edist,
                       const int* __restrict__ src_idx, const int* __restrict__ dst_idx,
                       const int* __restrict__ etype, const float* __restrict__ wf,
                       float* __restrict__ acc_s, float* __restrict__ acc_sg,
                       float* __restrict__ acc_vg, float* __restrict__ acc_v)
{
  __shared__ float smf[192*PF];     // [0,64) staging/VN ; [64,192) trunk (resident)
  __shared__ float s_vg[8*512];     // vg stash: [t][tid]
  __shared__ float s_sgate[64];
  __shared__ int   s_dst[64];

  const int tid  = threadIdx.x;
  const int lane = tid & 63;
  const int wv   = __builtin_amdgcn_readfirstlane(tid >> 6);   // 0..7
  const int e0   = blockIdx.x * 64;
  const int e    = e0 + lane;

  if (tid >= 64 && tid < 128) s_dst[tid-64] = dst_idx[e0 + tid-64];

  const int srcn = src_idx[e];
  const float* hrow = h + (size_t)srcn*320;
  const float4* hrow4 = reinterpret_cast<const float4*>(hrow);

  float y0,y1,y2;
  { float vx=evec[e*3], vy=evec[e*3+1], vz=evec[e*3+2];
    float rn = SQ3f * rsqrtf(vx*vx+vy*vy+vz*vz+1e-12f);
    y0=vx*rn; y1=vy*rn; y2=vz*rn; }

  // P0: stage edge_scalars -> ES [0,64)
  for (int lin=tid; lin<1024; lin+=512){
    int row = lin>>4, c4 = lin&15;
    float4 v = reinterpret_cast<const float4*>(es_g)[(e0+row)*16 + c4];
    smf[(c4*4+0)*PF + row] = v.x;
    smf[(c4*4+1)*PF + row] = v.y;
    smf[(c4*4+2)*PF + row] = v.z;
    smf[(c4*4+3)*PF + row] = v.w;
  }
  __syncthreads();                                        // B1

  // GATE 1: ge = silu(es@gate_w1+b1) -> [64,128)   [packed]
  { f32x2 ge2[4];
    #pragma unroll
    for (int t2=0;t2<4;++t2) ge2[t2] = ld2(wf + OFF_GATE_B1 + 8*wv + 2*t2);
    #pragma unroll 2
    for (int k=0;k<64;++k){
      float a = smf[k*PF + lane];
      const float* wr = wf + OFF_GATE_W1 + k*64 + 8*wv;
      #pragma unroll
      for (int t2=0;t2<4;++t2) ge2[t2] += a*ld2(wr + 2*t2);
    }
    #pragma unroll
    for (int t=0;t<8;++t) smf[(64 + 8*wv + t)*PF + lane] = fsilu(ge2[t>>1][t&1]);
  }
  __syncthreads();                                        // B2

  // GATE 2: go = ge@gate_w2 + b2 -> vg stash (s_vg), sgate   [scalar: stride 65]
  { float vga[8];
    float g0 = wf[OFF_GATE_B2];
    #pragma unroll
    for (int t=0;t<8;++t) vga[t] = wf[OFF_GATE_B2 + 1 + 8*wv + t];
    #pragma unroll 2
    for (int k=0;k<64;++k){
      float a = smf[(64+k)*PF + lane];
      const float* wr = wf + OFF_GATE_W2 + k*65;
      g0 += a*wr[0];
      #pragma unroll
      for (int t=0;t<8;++t) vga[t] += a*wr[1 + 8*wv + t];
    }
    #pragma unroll
    for (int t=0;t<8;++t) s_vg[t*512 + tid] = fsig(vga[t]);
    if (wv == 0){
      float sigma = __expf(wf[OFF_LSIG + etype[e]]);
      s_sgate[lane] = fsig(g0) * __expf(-edist[e]/sigma);
    }
  }
  __syncthreads();                                        // B3 (GE dead)

  // P1: trunk = silu(es@rt_w+b), 16 cols/wave -> [64,192)  (RESIDENT) [packed]
  { f32x2 acc2[8];
    #pragma unroll
    for (int j2=0;j2<8;++j2) acc2[j2] = ld2(wf + OFF_RT_B + 16*wv + 2*j2);
    #pragma unroll 2
    for (int k=0;k<64;++k){
      float a = smf[k*PF + lane];
      const float* wr = wf + OFF_RT_W + k*128 + 16*wv;
      #pragma unroll
      for (int j2=0;j2<8;++j2) acc2[j2] += a*ld2(wr + 2*j2);
    }
    #pragma unroll
    for (int j=0;j<16;++j) smf[(64 + 16*wv + j)*PF + lane] = fsilu(acc2[j>>1][j&1]);
  }
  __syncthreads();                                        // B4 (ES dead)

  // P2: scale_in only over full trunk   [packed]
  f32x2 sregS2[8], sregV2[4];
  #pragma unroll
  for (int i2=0;i2<8;++i2) sregS2[i2] = 1.f + ld2(wf + OFF_RIN_B + 16*wv + 2*i2);
  #pragma unroll
  for (int t2=0;t2<4;++t2) sregV2[t2] = 1.f + ld2(wf + OFF_RIN_B + 128 + 8*wv + 2*t2);
  #pragma unroll 2
  for (int k=0;k<128;++k){
    float a = smf[(64+k)*PF + lane];
    const float* wi = wf + OFF_RIN_W + k*192 + 24*wv;
    #pragma unroll
    for (int i2=0;i2<8;++i2) sregS2[i2] += a*ld2(wi + 2*i2);
    #pragma unroll
    for (int t2=0;t2<4;++t2) sregV2[t2] += a*ld2(wi + 16 + 2*t2);
  }
  // (no barrier: next writes [0,64); all es readers passed B4)

  f32x2 msg2[8], svv2[4];
  #pragma unroll
  for (int j2=0;j2<8;++j2) msg2[j2] = 0.f;
  #pragma unroll
  for (int t2=0;t2<4;++t2) svv2[t2] = 0.f;

  // ---- TP scalar, chunk 0: cols [0,64) staged by waves 0..3 into [0,64) ----
  if (wv < 4){
    #pragma unroll
    for (int q=0;q<4;++q){
      float4 v = hrow4[4*wv + q];
      int s = 16*wv + 4*q;
      smf[(s+0)*PF + lane] = v.x*sregS2[2*q+0][0];
      smf[(s+1)*PF + lane] = v.y*sregS2[2*q+0][1];
      smf[(s+2)*PF + lane] = v.z*sregS2[2*q+1][0];
      smf[(s+3)*PF + lane] = v.w*sregS2[2*q+1][1];
    }
  }
  __syncthreads();                                        // B5
  #pragma unroll 2
  for (int k=0;k<64;++k){
    float a = smf[k*PF + lane];
    const float* w0p = wf + OFF_TP00 + k*128 + 16*wv;
    const float* w1p = wf + OFF_TP01 + k*64  + 8*wv;
    #pragma unroll
    for (int j2=0;j2<8;++j2) msg2[j2] += a*ld2(w0p + 2*j2);
    #pragma unroll
    for (int t2=0;t2<4;++t2) svv2[t2] += a*ld2(w1p + 2*t2);
  }
  __syncthreads();                                        // B6
  // ---- TP scalar, chunk 1: cols [64,128) staged by waves 4..7 ----
  if (wv >= 4){
    #pragma unroll
    for (int q=0;q<4;++q){
      float4 v = hrow4[4*wv + q];
      int s = 16*(wv-4) + 4*q;
      smf[(s+0)*PF + lane] = v.x*sregS2[2*q+0][0];
      smf[(s+1)*PF + lane] = v.y*sregS2[2*q+0][1];
      smf[(s+2)*PF + lane] = v.z*sregS2[2*q+1][0];
      smf[(s+3)*PF + lane] = v.w*sregS2[2*q+1][1];
    }
  }
  __syncthreads();                                        // B7
  #pragma unroll 2
  for (int k=0;k<64;++k){
    float a = smf[k*PF + lane];
    const float* w0p = wf + OFF_TP00 + (64+k)*128 + 16*wv;
    const float* w1p = wf + OFF_TP01 + (64+k)*64  + 8*wv;
    #pragma unroll
    for (int j2=0;j2<8;++j2) msg2[j2] += a*ld2(w0p + 2*j2);
    #pragma unroll
    for (int t2=0;t2<4;++t2) svv2[t2] += a*ld2(w1p + 2*t2);
  }
  __syncthreads();                                        // B8

  // rank-1 init: mv = svv*y (svv dies); mv packed over t: mv2[d][t2]
  f32x2 mv2[3][4];
  #pragma unroll
  for (int t2=0;t2<4;++t2){
    mv2[0][t2] = svv2[t2]*y0; mv2[1][t2] = svv2[t2]*y1; mv2[2][t2] = svv2[t2]*y2;
  }

  // ---- TP vector: 4 chunks of 16 u's; XB [0,48) + DOT [48,64) ----
  for (int vc=0; vc<4; ++vc){
    if ((wv>>1) == vc){
      const int half = wv & 1;
      float dreg[8];
      #pragma unroll
      for (int t=0;t<8;++t) dreg[t]=0.f;
      #pragma unroll
      for (int q=0;q<6;++q){
        float4 v = hrow4[32 + 6*wv + q];
        float vv[4] = {v.x, v.y, v.z, v.w};
        #pragma unroll
        for (int c=0;c<4;++c){
          int l = 4*q + c;             // 0..23
          int t = l/3, d = l - 3*t;    // compile-time
          float x = vv[c]*sregV2[t>>1][t&1];
          smf[(3*(8*half + t) + d)*PF + lane] = x;
          dreg[t] += x * (d==0 ? y0 : (d==1 ? y1 : y2));
        }
      }
      #pragma unroll
      for (int t=0;t<8;++t)
        smf[(48 + 8*half + t)*PF + lane] = dreg[t]*INV_SQ3f;
    }
    __syncthreads();                                      // stage done
    #pragma unroll 2
    for (int ul=0; ul<16; ++ul){
      float x0 = smf[(3*ul+0)*PF + lane];
      float x1 = smf[(3*ul+1)*PF + lane];
      float x2 = smf[(3*ul+2)*PF + lane];
      const float* wr = wf + OFF_TP10 + (16*vc + ul)*64 + 8*wv;
      #pragma unroll
      for (int t2=0;t2<4;++t2){
        f32x2 wt2 = ld2(wr + 2*t2);
        mv2[0][t2] += x0*wt2; mv2[1][t2] += x1*wt2; mv2[2][t2] += x2*wt2;
      }
    }
    #pragma unroll 2
    for (int k=0;k<16;++k){
      float a = smf[(48+k)*PF + lane];
      const float* wr = wf + OFF_TP11 + (16*vc + k)*128 + 16*wv;
      #pragma unroll
      for (int j2=0;j2<8;++j2) msg2[j2] += a*ld2(wr + 2*j2);
    }
    __syncthreads();                                      // compute done
  }

  // ---- rout pass (LATE): souts/soutv from resident trunk   [packed]
  f32x2 souts2[8], soutv2[4];
  #pragma unroll
  for (int j2=0;j2<8;++j2) souts2[j2] = 1.f + ld2(wf + OFF_ROUT_B + 16*wv + 2*j2);
  #pragma unroll
  for (int t2=0;t2<4;++t2) soutv2[t2] = 1.f + ld2(wf + OFF_ROUT_B + 128 + 8*wv + 2*t2);
  #pragma unroll 2
  for (int k=0;k<128;++k){
    float a = smf[(64+k)*PF + lane];
    const float* wo = wf + OFF_ROUT_W + k*192;
    #pragma unroll
    for (int j2=0;j2<8;++j2) souts2[j2] += a*ld2(wo + 16*wv + 2*j2);
    #pragma unroll
    for (int t2=0;t2<4;++t2) soutv2[t2] += a*ld2(wo + 128 + 8*wv + 2*t2);
  }

  // P6: apply scale_out + silu + vn -> VN [0,64)
  #pragma unroll
  for (int j2=0;j2<8;++j2){
    f32x2 m = msg2[j2]*souts2[j2];
    msg2[j2][0] = fsilu(m[0]); msg2[j2][1] = fsilu(m[1]);
  }
  #pragma unroll
  for (int t2=0;t2<4;++t2){
    mv2[0][t2] *= soutv2[t2]; mv2[1][t2] *= soutv2[t2]; mv2[2][t2] *= soutv2[t2];
  }
  #pragma unroll
  for (int t=0;t<8;++t){
    float m0 = mv2[0][t>>1][t&1], m1 = mv2[1][t>>1][t&1], m2 = mv2[2][t>>1][t&1];
    float vn = sqrtf(m0*m0 + m1*m1 + m2*m2 + 1e-12f);
    smf[(8*wv + t)*PF + lane] = vn;
  }
  __syncthreads();                                        // B17 (trunk reads done)

  // P7: t1 = silu(vn@act_w1+b1) -> T1 [64,128)   [packed]
  { f32x2 a12[4];
    #pragma unroll
    for (int t2=0;t2<4;++t2) a12[t2] = ld2(wf + OFF_ACT_B1 + 8*wv + 2*t2);
    #pragma unroll 2
    for (int k=0;k<64;++k){
      float a = smf[k*PF + lane];
      const float* wr = wf + OFF_ACT_W1 + k*64 + 8*wv;
      #pragma unroll
      for (int t2=0;t2<4;++t2) a12[t2] += a*ld2(wr + 2*t2);
    }
    #pragma unroll
    for (int t=0;t<8;++t) smf[(64 + 8*wv + t)*PF + lane] = fsilu(a12[t>>1][t&1]);
  }
  __syncthreads();                                        // B18

  // P8: g = sigmoid(t1@act_w2+b2); mv *= g   [packed]
  { f32x2 gq2[4];
    #pragma unroll
    for (int t2=0;t2<4;++t2) gq2[t2] = ld2(wf + OFF_ACT_B2 + 8*wv + 2*t2);
    #pragma unroll 2
    for (int k=0;k<64;++k){
      float a = smf[(64+k)*PF + lane];
      const float* wr = wf + OFF_ACT_W2 + k*64 + 8*wv;
      #pragma unroll
      for (int t2=0;t2<4;++t2) gq2[t2] += a*ld2(wr + 2*t2);
    }
    #pragma unroll
    for (int t=0;t<8;++t){
      float g = fsig(gq2[t>>1][t&1]);
      mv2[0][t>>1][t&1] *= g; mv2[1][t>>1][t&1] *= g; mv2[2][t>>1][t&1] *= g;
    }
  }
  __syncthreads();                                        // B19

  // ===== COALESCED scatter via LDS transpose =====
  // Phase A: sg*msg_s (128 ch)
  { float sg = s_sgate[lane];
    #pragma unroll
    for (int j=0;j<16;++j) smf[(16*wv + j)*PF + lane] = sg*msg2[j>>1][j&1];
  }
  __syncthreads();
  for (int lin=tid; lin<8192; lin+=512){
    int row = lin >> 7, ch = lin & 127;
    atomicAdd(acc_s + (size_t)s_dst[row]*128 + ch, smf[ch*PF + row]);
  }
  __syncthreads();
  // Phase B half 1: u in [0,32) (waves 0..3), 96 ch
  if (wv < 4){
    #pragma unroll
    for (int t=0;t<8;++t){
      int u = 8*wv + t;
      float vgt = s_vg[t*512 + tid];
      smf[(3*u+0)*PF + lane] = vgt*mv2[0][t>>1][t&1];
      smf[(3*u+1)*PF + lane] = vgt*mv2[1][t>>1][t&1];
      smf[(3*u+2)*PF + lane] = vgt*mv2[2][t>>1][t&1];
    }
  }
  __syncthreads();
  for (int lin=tid; lin<6144; lin+=512){
    int row = lin / 96, ch = lin % 96;
    atomicAdd(acc_v + (size_t)s_dst[row]*192 + ch, smf[ch*PF + row]);
  }
  __syncthreads();
  // Phase B half 2: u in [32,64) (waves 4..7), 96 ch
  if (wv >= 4){
    #pragma unroll
    for (int t=0;t<8;++t){
      int um = 8*(wv-4) + t;
      float vgt = s_vg[t*512 + tid];
      smf[(3*um+0)*PF + lane] = vgt*mv2[0][t>>1][t&1];
      smf[(3*um+1)*PF + lane] = vgt*mv2[1][t>>1][t&1];
      smf[(3*um+2)*PF + lane] = vgt*mv2[2][t>>1][t&1];
    }
  }
  __syncthreads();
  for (int lin=tid; lin<6144; lin+=512){
    int row = lin / 96, ch = lin % 96;
    atomicAdd(acc_v + (size_t)s_dst[row]*192 + 96 + ch, smf[ch*PF + row]);
  }
  __syncthreads();
  // Phase C: vg (64 ch) + sg
  #pragma unroll
  for (int t=0;t<8;++t) smf[(8*wv + t)*PF + lane] = s_vg[t*512 + tid];
  __syncthreads();
  for (int lin=tid; lin<4096; lin+=512){
    int row = lin >> 6, ch = lin & 63;
    atomicAdd(acc_vg + (size_t)s_dst[row]*64 + ch, smf[ch*PF + row]);
  }
  if (tid < 64) atomicAdd(acc_sg + s_dst[tid], s_sgate[tid]);
}

// ---------------- node kernel ----------------
__launch_bounds__(256,2)
__global__ void k_node(const float* __restrict__ h, const float* __restrict__ wf,
                       const float* __restrict__ acc_s, const float* __restrict__ acc_sg,
                       const float* __restrict__ acc_vg, const float* __restrict__ acc_v,
                       float* __restrict__ out)
{
  __shared__ float smf[160*PF];
  const int tid  = threadIdx.x;
  const int lane = tid & 63;
  const int wv   = __builtin_amdgcn_readfirstlane(tid >> 6);
  const int n0   = blockIdx.x * 64;
  const int n    = n0 + lane;
  const int w0   = 16*wv;

  float agg[16][3], vnr[16];
  f32x2 sva2[3][8];
  #pragma unroll
  for (int t=0;t<16;++t){
    float inv = 1.f/(acc_vg[n*64 + w0 + t] + 1e-6f);
    agg[t][0] = acc_v[n*192 + (w0+t)*3 + 0]*inv;
    agg[t][1] = acc_v[n*192 + (w0+t)*3 + 1]*inv;
    agg[t][2] = acc_v[n*192 + (w0+t)*3 + 2]*inv;
    vnr[t] = sqrtf(agg[t][0]*agg[t][0]+agg[t][1]*agg[t][1]+agg[t][2]*agg[t][2]+1e-12f);
    smf[(96 + w0 + t)*PF + lane] = vnr[t];
  }
  #pragma unroll
  for (int t2=0;t2<8;++t2){ sva2[0][t2]=0.f; sva2[1][t2]=0.f; sva2[2][t2]=0.f; }

  f32x2 outs2[16];
  #pragma unroll
  for (int j2=0;j2<16;++j2) outs2[j2] = ld2(wf + OFF_SELF_BS + 32*wv + 2*j2);

  for (int cc=0; cc<2; ++cc){
    for (int lin=tid; lin<1024; lin+=256){
      int row = lin>>4, c4 = lin&15;
      float4 v = reinterpret_cast<const float4*>(h)[(n0+row)*80 + cc*16 + c4];
      smf[(c4*4+0)*PF + row] = v.x;
      smf[(c4*4+1)*PF + row] = v.y;
      smf[(c4*4+2)*PF + row] = v.z;
      smf[(c4*4+3)*PF + row] = v.w;
    }
    __syncthreads();
    #pragma unroll 2
    for (int k=0;k<64;++k){
      float a = smf[k*PF + lane];
      const float* wr = wf + OFF_SELF_WS + (cc*64+k)*128 + 32*wv;
      #pragma unroll
      for (int j2=0;j2<16;++j2) outs2[j2] += a*ld2(wr + 2*j2);
    }
    __syncthreads();
  }
  for (int cc=0; cc<2; ++cc){
    for (int lin=tid; lin<1536; lin+=256){
      int row = lin/24, c6 = lin%24;
      float4 v = reinterpret_cast<const float4*>(h)[(n0+row)*80 + 32 + cc*24 + c6];
      smf[(c6*4+0)*PF + row] = v.x;
      smf[(c6*4+1)*PF + row] = v.y;
      smf[(c6*4+2)*PF + row] = v.z;
      smf[(c6*4+3)*PF + row] = v.w;
    }
    __syncthreads();
    #pragma unroll 2
    for (int ul=0; ul<32; ++ul){
      float x0 = smf[(3*ul+0)*PF + lane];
      float x1 = smf[(3*ul+1)*PF + lane];
      float x2 = smf[(3*ul+2)*PF + lane];
      const float* wr = wf + OFF_SELF_WV + (cc*32+ul)*64 + w0;
      #pragma unroll
      for (int t2=0;t2<8;++t2){
        f32x2 wt2 = ld2(wr + 2*t2);
        sva2[0][t2] += x0*wt2; sva2[1][t2] += x1*wt2; sva2[2][t2] += x2*wt2;
      }
    }
    __syncthreads();
  }

  f32x2 rv2[8];
  #pragma unroll
  for (int t2=0;t2<8;++t2) rv2[t2] = ld2(wf + OFF_VR_B + w0 + 2*t2);
  #pragma unroll 2
  for (int k=0;k<64;++k){
    float a = smf[(96+k)*PF + lane];
    const float* wr = wf + OFF_VR_W + k*64 + w0;
    #pragma unroll
    for (int t2=0;t2<8;++t2) rv2[t2] += a*ld2(wr + 2*t2);
  }

  { float inv = 1.f/(acc_sg[n] + 1e-6f);
    const float* ap = acc_s + (size_t)n*128 + 32*wv;
    #pragma unroll
    for (int j2=0;j2<16;++j2) outs2[j2] += ld2(ap + 2*j2)*inv;
  }

  float* orow = out + (size_t)n*320;
  { float4* o4 = reinterpret_cast<float4*>(orow + 32*wv);
    #pragma unroll
    for (int j=0;j<8;++j){
      float4 v;
      v.x=outs2[2*j+0][0]; v.y=outs2[2*j+0][1];
      v.z=outs2[2*j+1][0]; v.w=outs2[2*j+1][1];
      o4[j] = v;
    }
  }
  { float vbuf[48];
    #pragma unroll
    for (int t=0;t<16;++t){
      float sc = rv2[t>>1][t&1]/(vnr[t]+1e-6f);
      vbuf[t*3+0] = agg[t][0]*sc + sva2[0][t>>1][t&1];
      vbuf[t*3+1] = agg[t][1]*sc + sva2[1][t>>1][t&1];
      vbuf[t*3+2] = agg[t][2]*sc + sva2[2][t>>1][t&1];
    }
    float4* o4 = reinterpret_cast<float4*>(orow + 128 + 48*wv);
    #pragma unroll
    for (int j=0;j<12;++j){
      float4 v; v.x=vbuf[4*j]; v.y=vbuf[4*j+1]; v.z=vbuf[4*j+2]; v.w=vbuf[4*j+3];
      o4[j] = v;
    }
  }
}

// ---------------- launch ----------------
extern "C" void kernel_launch(void* const* d_in, const int* in_sizes, int n_in,
                              void* d_out, int out_size, void* d_ws, size_t ws_size,
                              hipStream_t stream) {
  const float* h     = (const float*)d_in[0];
  const float* evec  = (const float*)d_in[1];
  const float* es    = (const float*)d_in[2];
  const float* edist = (const float*)d_in[3];
  const int* srcI    = (const int*)d_in[4];
  const int* dstI    = (const int*)d_in[5];
  const int* etyp    = (const int*)d_in[6];

  float* wsf    = (float*)d_ws;
  float* acc_s  = wsf + ACC_S_OFF;
  float* acc_sg = wsf + ACC_SG_OFF;
  float* acc_vg = wsf + ACC_VG_OFF;
  float* acc_v  = wsf + ACC_V_OFF;

  WCopy wc;
  const int ns[24]  = {8192,128,24576,192,24576,192,16384,8192,4096,8192,4096,64,4096,64,
                       4096,64,4160,65,10,4096,64,16384,128,4096};
  const int offs[24]= {OFF_RT_W,OFF_RT_B,OFF_RIN_W,OFF_RIN_B,OFF_ROUT_W,OFF_ROUT_B,
                       OFF_TP00,OFF_TP01,OFF_TP10,OFF_TP11,OFF_ACT_W1,OFF_ACT_B1,
                       OFF_ACT_W2,OFF_ACT_B2,OFF_GATE_W1,OFF_GATE_B1,OFF_GATE_W2,OFF_GATE_B2,
                       OFF_LSIG,OFF_VR_W,OFF_VR_B,OFF_SELF_WS,OFF_SELF_BS,OFF_SELF_WV};
  for (int a=0;a<24;++a){ wc.src[a] = (const float*)d_in[8+a]; wc.n[a]=ns[a]; wc.off[a]=offs[a]; }
  hipLaunchKernelGGL(k_copy, dim3(533), dim3(256), 0, stream, wc, wsf);

  { int nz = ACC_END - ACC_S_OFF;
    hipLaunchKernelGGL(k_zero, dim3((nz+255)/256), dim3(256), 0, stream, acc_s, nz); }

  hipLaunchKernelGGL(k_edge, dim3(N_EDGES/64), dim3(512), 0, stream,
                     h, evec, es, edist, srcI, dstI, etyp, wsf,
                     acc_s, acc_sg, acc_vg, acc_v);
  hipLaunchKernelGGL(k_node, dim3(N_NODES/64), dim3(256), 0, stream,
                     h, wsf, acc_s, acc_sg, acc_vg, acc_v, (float*)d_out);
}

// Round 13
// 1336.133 us; speedup vs baseline: 1.9776x; 1.0968x over previous
//
#include <hip/hip_runtime.h>

typedef unsigned int u32;
typedef float f32x2 __attribute__((ext_vector_type(2)));
typedef float f32x4 __attribute__((ext_vector_type(4)));
typedef short s16x8 __attribute__((ext_vector_type(8)));

#define N_NODES 32768
#define N_EDGES 262144
#define PF 65   // LDS pitch (floats): 64 edges + 1 pad

// ---------- fp32 weight buffer layout (float offsets in d_ws) ----------
enum : int {
  OFF_RT_W   = 0,       // [64,128]
  OFF_RT_B   = 8192,    // [128]
  OFF_RIN_W  = 8320,    // [128,192]  (stored PERMUTED for 8-wave ownership:
                        //  scalar col c<128 -> (c>>4)*24 + (c&15)
                        //  vec u=c-128     -> (u>>3)*24 + 16 + (u&7))
  OFF_RIN_B  = 32896,   // [192]
  OFF_ROUT_W = 33088,   // [128,192]
  OFF_ROUT_B = 57664,   // [192]
  OFF_TP00   = 57856,   // [128,128]
  OFF_TP01   = 74240,   // [128,64]
  OFF_TP10   = 82432,   // [64,64]
  OFF_TP11   = 86528,   // [64,128]
  OFF_ACT_W1 = 94720,   // [64,64]
  OFF_ACT_B1 = 98816,   // [64]
  OFF_ACT_W2 = 98880,   // [64,64]
  OFF_ACT_B2 = 102976,  // [64]
  OFF_GATE_W1= 103040,  // [64,64]
  OFF_GATE_B1= 107136,  // [64]
  OFF_GATE_W2= 107200,  // [64,65]
  OFF_GATE_B2= 111360,  // [65]
  OFF_LSIG   = 111428,  // [10]
  OFF_VR_W   = 111440,  // [64,64]
  OFF_VR_B   = 115536,  // [64]
  OFF_SELF_WS= 115600,  // [128,128]
  OFF_SELF_BS= 131984,  // [128]
  OFF_SELF_WV= 132112,  // [64,64]
  // bf16 B-fragment pack of [tp00;tp11] stacked (K=192):
  // [8 ctile][6 kstep][64 lane][8 j] u16 = 24576 u16 = 12288 float slots
  OFF_MSBF   = 136208,
  NWF        = 148496
};
enum : int {
  ACC_S_OFF  = NWF,
  ACC_SG_OFF = ACC_S_OFF + N_NODES*128,
  ACC_VG_OFF = ACC_SG_OFF + N_NODES,
  ACC_V_OFF  = ACC_VG_OFF + N_NODES*64,
  ACC_END    = ACC_V_OFF + N_NODES*192
};

__device__ __forceinline__ float fsilu(float x){ return x/(1.f+__expf(-x)); }
__device__ __forceinline__ float fsig (float x){ return 1.f/(1.f+__expf(-x)); }
__device__ __forceinline__ f32x2 ld2(const float* p){ return *reinterpret_cast<const f32x2*>(p); }
__device__ __forceinline__ unsigned short f2bf(float f){
  u32 x = __builtin_bit_cast(u32, f);
  u32 r = x + 0x7FFFu + ((x>>16)&1u);
  return (unsigned short)(r>>16);
}

#define SQ3f     1.7320508075688772f
#define INV_SQ3f 0.5773502691896258f

__global__ void k_zero(float* __restrict__ p, int n){
  int t = blockIdx.x*256 + threadIdx.x;
  if (t < n) p[t] = 0.f;
}

// weight copy; rin_w (a=2) permuted for 8-wave ownership (as R8-R10);
// tp00 (a=6) and tp11 (a=9) additionally packed as stacked bf16 B-frags.
struct WCopy { const float* src[24]; int n[24]; int off[24]; };

__global__ void k_copy(WCopy w, float* __restrict__ dst){
  int t = blockIdx.x*256 + threadIdx.x;
  unsigned short* ms = reinterpret_cast<unsigned short*>(dst + OFF_MSBF);
  for (int a=0;a<24;++a){
    int n = w.n[a];
    if (t < n){
      float v = w.src[a][t];
      if (a == 2){
        int k = t/192, c = t%192;
        int dc = (c < 128) ? ((c>>4)*24 + (c&15))
                           : ((((c-128)>>3)*24) + 16 + ((c-128)&7));
        dst[w.off[a] + k*192 + dc] = v;
      } else {
        dst[w.off[a]+t] = v;
      }
      if (a == 6 || a == 9){
        // B-frag for mfma_f32_16x16x32_bf16: lane ln holds
        // B[k = ks*32 + ((ln>>4)&3)*8 + j][c = ct*16 + (ln&15)]
        int k = t/128, c = t%128;
        int kg = (a==9) ? 128+k : k;       // tp11 stacked at K rows 128..191
        int ct = c>>4;
        int ks = kg>>5;                     // 0..5
        int ln = (c&15) | (((kg>>3)&3)<<4);
        int j  = kg&7;
        ms[((ct*6+ks)*64 + ln)*8 + j] = f2bf(v);
      }
      return;
    }
    t -= n;
  }
}

// ---------------- edge kernel ----------------
// R12 = R10 + bf16 MFMA for msg_s ONLY (out_s path, amplification ~1).
// R11 lesson: any bf16 rounding reaching mv is amplified ~150x by the
// agg_v normalization (absmax 0.38 > 0.26). msg_s path (silu + weighted
// mean) tolerates bf16. So: x and dot staged bf16 in A-frag layout
// x_bf[64][200] (K=192 = x(128) || dot(64)); [tp00;tp11] pre-packed bf16
// B-frags; 24 MFMAs/wave after the rout pass; D written fp32 over the
// dead trunk region and read back. Everything feeding mv (sreg, tp01,
// tp10, soutv, gate, act) stays fp32 scalar. vg back in REGISTERS
// (s_vg LDS dropped; 128-reg budget has room at VGPR=52).
__launch_bounds__(512,4)
__global__ void k_edge(const float* __restrict__ h, const float* __restrict__ evec,
                       const float* __restrict__ es_g, const float* __restrict__ edist,
                       const int* __restrict__ src_idx, const int* __restrict__ dst_idx,
                       const int* __restrict__ etype, const float* __restrict__ wf,
                       float* __restrict__ acc_s, float* __restrict__ acc_sg,
                       float* __restrict__ acc_vg, float* __restrict__ acc_v)
{
  __shared__ float smf[192*PF];       // [0,64) staging/VN ; [64,192) trunk -> msgT -> T1/scatter
  __shared__ unsigned short x_bf[64*200];  // bf16 A-frags: [edge][k], k<128 = x, 128+u = dot
  __shared__ float s_sgate[64];
  __shared__ int   s_dst[64];

  const int tid  = threadIdx.x;
  const int lane = tid & 63;
  const int wv   = __builtin_amdgcn_readfirstlane(tid >> 6);   // 0..7
  const int e0   = blockIdx.x * 64;
  const int e    = e0 + lane;

  if (tid >= 64 && tid < 128) s_dst[tid-64] = dst_idx[e0 + tid-64];

  const int srcn = src_idx[e];
  const float* hrow = h + (size_t)srcn*320;
  const float4* hrow4 = reinterpret_cast<const float4*>(hrow);

  float y0,y1,y2;
  { float vx=evec[e*3], vy=evec[e*3+1], vz=evec[e*3+2];
    float rn = SQ3f * rsqrtf(vx*vx+vy*vy+vz*vz+1e-12f);
    y0=vx*rn; y1=vy*rn; y2=vz*rn; }

  // P0: stage edge_scalars -> smf [0,64)
  for (int lin=tid; lin<1024; lin+=512){
    int row = lin>>4, c4 = lin&15;
    float4 v = reinterpret_cast<const float4*>(es_g)[(e0+row)*16 + c4];
    smf[(c4*4+0)*PF + row] = v.x;
    smf[(c4*4+1)*PF + row] = v.y;
    smf[(c4*4+2)*PF + row] = v.z;
    smf[(c4*4+3)*PF + row] = v.w;
  }
  __syncthreads();                                        // B1

  // GATE 1: ge = silu(es@gate_w1+b1) -> [64,128)
  { f32x2 ge2[4];
    #pragma unroll
    for (int t2=0;t2<4;++t2) ge2[t2] = ld2(wf + OFF_GATE_B1 + 8*wv + 2*t2);
    #pragma unroll 2
    for (int k=0;k<64;++k){
      float a = smf[k*PF + lane];
      const float* wr = wf + OFF_GATE_W1 + k*64 + 8*wv;
      #pragma unroll
      for (int t2=0;t2<4;++t2) ge2[t2] += a*ld2(wr + 2*t2);
    }
    #pragma unroll
    for (int t=0;t<8;++t) smf[(64 + 8*wv + t)*PF + lane] = fsilu(ge2[t>>1][t&1]);
  }
  __syncthreads();                                        // B2

  // GATE 2: go = ge@gate_w2 + b2 -> vg (REGISTERS), sgate
  float vga[8];
  { float g0 = wf[OFF_GATE_B2];
    #pragma unroll
    for (int t=0;t<8;++t) vga[t] = wf[OFF_GATE_B2 + 1 + 8*wv + t];
    #pragma unroll 2
    for (int k=0;k<64;++k){
      float a = smf[(64+k)*PF + lane];
      const float* wr = wf + OFF_GATE_W2 + k*65;
      g0 += a*wr[0];
      #pragma unroll
      for (int t=0;t<8;++t) vga[t] += a*wr[1 + 8*wv + t];
    }
    #pragma unroll
    for (int t=0;t<8;++t) vga[t] = fsig(vga[t]);
    if (wv == 0){
      float sigma = __expf(wf[OFF_LSIG + etype[e]]);
      s_sgate[lane] = fsig(g0) * __expf(-edist[e]/sigma);
    }
  }
  __syncthreads();                                        // B3 (GE dead)

  // P1: trunk = silu(es@rt_w+b), 16 cols/wave -> [64,192) (RESIDENT, fp32)
  { f32x2 acc2[8];
    #pragma unroll
    for (int j2=0;j2<8;++j2) acc2[j2] = ld2(wf + OFF_RT_B + 16*wv + 2*j2);
    #pragma unroll 2
    for (int k=0;k<64;++k){
      float a = smf[k*PF + lane];
      const float* wr = wf + OFF_RT_W + k*128 + 16*wv;
      #pragma unroll
      for (int j2=0;j2<8;++j2) acc2[j2] += a*ld2(wr + 2*j2);
    }
    #pragma unroll
    for (int j=0;j<16;++j) smf[(64 + 16*wv + j)*PF + lane] = fsilu(acc2[j>>1][j&1]);
  }
  __syncthreads();                                        // B4 (ES dead)

  // P2: scale_in (fp32 registers) over full trunk
  f32x2 sregS2[8], sregV2[4];
  #pragma unroll
  for (int i2=0;i2<8;++i2) sregS2[i2] = 1.f + ld2(wf + OFF_RIN_B + 16*wv + 2*i2);
  #pragma unroll
  for (int t2=0;t2<4;++t2) sregV2[t2] = 1.f + ld2(wf + OFF_RIN_B + 128 + 8*wv + 2*t2);
  #pragma unroll 2
  for (int k=0;k<128;++k){
    float a = smf[(64+k)*PF + lane];
    const float* wi = wf + OFF_RIN_W + k*192 + 24*wv;
    #pragma unroll
    for (int i2=0;i2<8;++i2) sregS2[i2] += a*ld2(wi + 2*i2);
    #pragma unroll
    for (int t2=0;t2<4;++t2) sregV2[t2] += a*ld2(wi + 16 + 2*t2);
  }
  // (no barrier: next writes [0,64); all es readers passed B4)

  f32x2 svv2[4];
  #pragma unroll
  for (int t2=0;t2<4;++t2) svv2[t2] = 0.f;

  u32* xb32 = reinterpret_cast<u32*>(x_bf);

  // ---- TP scalar, chunk 0: cols [0,64) staged by waves 0..3 (fp32 + bf16) ----
  if (wv < 4){
    #pragma unroll
    for (int q=0;q<4;++q){
      float4 v = hrow4[4*wv + q];
      int s = 16*wv + 4*q;
      float x0 = v.x*sregS2[2*q+0][0];
      float x1 = v.y*sregS2[2*q+0][1];
      float x2 = v.z*sregS2[2*q+1][0];
      float x3 = v.w*sregS2[2*q+1][1];
      smf[(s+0)*PF + lane] = x0;
      smf[(s+1)*PF + lane] = x1;
      smf[(s+2)*PF + lane] = x2;
      smf[(s+3)*PF + lane] = x3;
      xb32[lane*100 + (s>>1)    ] = (u32)f2bf(x0) | ((u32)f2bf(x1)<<16);
      xb32[lane*100 + (s>>1) + 1] = (u32)f2bf(x2) | ((u32)f2bf(x3)<<16);
    }
  }
  __syncthreads();                                        // B5
  #pragma unroll 2
  for (int k=0;k<64;++k){
    float a = smf[k*PF + lane];
    const float* w1p = wf + OFF_TP01 + k*64 + 8*wv;
    #pragma unroll
    for (int t2=0;t2<4;++t2) svv2[t2] += a*ld2(w1p + 2*t2);
  }
  __syncthreads();                                        // B6
  // ---- TP scalar, chunk 1: cols [64,128) staged by waves 4..7 ----
  if (wv >= 4){
    #pragma unroll
    for (int q=0;q<4;++q){
      float4 v = hrow4[4*wv + q];
      int gcol = 16*wv + 4*q;     // [64,128)
      int s = gcol - 64;
      float x0 = v.x*sregS2[2*q+0][0];
      float x1 = v.y*sregS2[2*q+0][1];
      float x2 = v.z*sregS2[2*q+1][0];
      float x3 = v.w*sregS2[2*q+1][1];
      smf[(s+0)*PF + lane] = x0;
      smf[(s+1)*PF + lane] = x1;
      smf[(s+2)*PF + lane] = x2;
      smf[(s+3)*PF + lane] = x3;
      xb32[lane*100 + (gcol>>1)    ] = (u32)f2bf(x0) | ((u32)f2bf(x1)<<16);
      xb32[lane*100 + (gcol>>1) + 1] = (u32)f2bf(x2) | ((u32)f2bf(x3)<<16);
    }
  }
  __syncthreads();                                        // B7
  #pragma unroll 2
  for (int k=0;k<64;++k){
    float a = smf[k*PF + lane];
    const float* w1p = wf + OFF_TP01 + (64+k)*64 + 8*wv;
    #pragma unroll
    for (int t2=0;t2<4;++t2) svv2[t2] += a*ld2(w1p + 2*t2);
  }
  __syncthreads();                                        // B8

  // rank-1 init: mv = svv*y (fp32)
  f32x2 mv2[3][4];
  #pragma unroll
  for (int t2=0;t2<4;++t2){
    mv2[0][t2] = svv2[t2]*y0; mv2[1][t2] = svv2[t2]*y1; mv2[2][t2] = svv2[t2]*y2;
  }

  // ---- TP vector: 4 chunks of 16 u's; XB [0,48) fp32; dot -> x_bf bf16 ----
  for (int vc=0; vc<4; ++vc){
    if ((wv>>1) == vc){
      const int half = wv & 1;
      float dreg[8];
      #pragma unroll
      for (int t=0;t<8;++t) dreg[t]=0.f;
      #pragma unroll
      for (int q=0;q<6;++q){
        float4 v = hrow4[32 + 6*wv + q];
        float vv[4] = {v.x, v.y, v.z, v.w};
        #pragma unroll
        for (int c=0;c<4;++c){
          int l = 4*q + c;             // 0..23
          int t = l/3, d = l - 3*t;    // compile-time
          float x = vv[c]*sregV2[t>>1][t&1];
          smf[(3*(8*half + t) + d)*PF + lane] = x;
          dreg[t] += x * (d==0 ? y0 : (d==1 ? y1 : y2));
        }
      }
      #pragma unroll
      for (int t=0;t<8;++t)
        x_bf[lane*200 + 128 + 16*vc + 8*half + t] = f2bf(dreg[t]*INV_SQ3f);
    }
    __syncthreads();                                      // stage done
    #pragma unroll 2
    for (int ul=0; ul<16; ++ul){
      float x0 = smf[(3*ul+0)*PF + lane];
      float x1 = smf[(3*ul+1)*PF + lane];
      float x2 = smf[(3*ul+2)*PF + lane];
      const float* wr = wf + OFF_TP10 + (16*vc + ul)*64 + 8*wv;
      #pragma unroll
      for (int t2=0;t2<4;++t2){
        f32x2 wt2 = ld2(wr + 2*t2);
        mv2[0][t2] += x0*wt2; mv2[1][t2] += x1*wt2; mv2[2][t2] += x2*wt2;
      }
    }
    __syncthreads();                                      // compute done
  }

  // ---- rout pass (LATE, fp32): souts/soutv from resident trunk ----
  f32x2 souts2[8], soutv2[4];
  #pragma unroll
  for (int j2=0;j2<8;++j2) souts2[j2] = 1.f + ld2(wf + OFF_ROUT_B + 16*wv + 2*j2);
  #pragma unroll
  for (int t2=0;t2<4;++t2) soutv2[t2] = 1.f + ld2(wf + OFF_ROUT_B + 128 + 8*wv + 2*t2);
  #pragma unroll 2
  for (int k=0;k<128;++k){
    float a = smf[(64+k)*PF + lane];
    const float* wo = wf + OFF_ROUT_W + k*192;
    #pragma unroll
    for (int j2=0;j2<8;++j2) souts2[j2] += a*ld2(wo + 16*wv + 2*j2);
    #pragma unroll
    for (int t2=0;t2<4;++t2) soutv2[t2] += a*ld2(wo + 128 + 8*wv + 2*t2);
  }
  __syncthreads();                                        // B-rout (trunk reads done)

  // ===== MFMA: msg_s = [x|dot] @ [tp00;tp11], K=192, 24 MFMAs/wave =====
  { const int etile = wv & 3, g = wv >> 2;
    const int erow = (etile<<4) + (lane&15);
    const int kgrp = (lane>>4)<<3;
    const s16x8* ms8 = reinterpret_cast<const s16x8*>(wf + OFF_MSBF);
    f32x4 dacc[4];
    #pragma unroll
    for (int i=0;i<4;++i) dacc[i] = f32x4{0.f,0.f,0.f,0.f};
    #pragma unroll
    for (int ks=0;ks<6;++ks){
      s16x8 af = *reinterpret_cast<const s16x8*>(x_bf + erow*200 + ks*32 + kgrp);
      #pragma unroll
      for (int i=0;i<4;++i){
        int ct = 4*g + i;
        dacc[i] = __builtin_amdgcn_mfma_f32_16x16x32_bf16(af, ms8[(ct*6+ks)*64 + lane], dacc[i], 0,0,0);
      }
    }
    // D layout (m89): col = lane&15, row = (lane>>4)*4 + r
    #pragma unroll
    for (int i=0;i<4;++i){
      int c = (4*g+i)*16 + (lane&15);
      #pragma unroll
      for (int r=0;r<4;++r){
        int ee = (etile<<4) + ((lane>>4)<<2) + r;
        smf[(64 + c)*PF + ee] = dacc[i][r];
      }
    }
  }
  __syncthreads();                                        // msgT ready

  // readback msg_s (16 cols/thread)
  f32x2 msg2[8];
  #pragma unroll
  for (int j2=0;j2<8;++j2){
    msg2[j2][0] = smf[(64 + 16*wv + 2*j2+0)*PF + lane];
    msg2[j2][1] = smf[(64 + 16*wv + 2*j2+1)*PF + lane];
  }

  // P6: apply scale_out + silu + vn -> VN [0,64)
  #pragma unroll
  for (int j2=0;j2<8;++j2){
    f32x2 m = msg2[j2]*souts2[j2];
    msg2[j2][0] = fsilu(m[0]); msg2[j2][1] = fsilu(m[1]);
  }
  #pragma unroll
  for (int t2=0;t2<4;++t2){
    mv2[0][t2] *= soutv2[t2]; mv2[1][t2] *= soutv2[t2]; mv2[2][t2] *= soutv2[t2];
  }
  #pragma unroll
  for (int t=0;t<8;++t){
    float m0 = mv2[0][t>>1][t&1], m1 = mv2[1][t>>1][t&1], m2 = mv2[2][t>>1][t&1];
    float vn = sqrtf(m0*m0 + m1*m1 + m2*m2 + 1e-12f);
    smf[(8*wv + t)*PF + lane] = vn;
  }
  __syncthreads();                                        // B19 (msgT reads done)

  // P7: t1 = silu(vn@act_w1+b1) -> [64,128)
  { f32x2 a12[4];
    #pragma unroll
    for (int t2=0;t2<4;++t2) a12[t2] = ld2(wf + OFF_ACT_B1 + 8*wv + 2*t2);
    #pragma unroll 2
    for (int k=0;k<64;++k){
      float a = smf[k*PF + lane];
      const float* wr = wf + OFF_ACT_W1 + k*64 + 8*wv;
      #pragma unroll
      for (int t2=0;t2<4;++t2) a12[t2] += a*ld2(wr + 2*t2);
    }
    #pragma unroll
    for (int t=0;t<8;++t) smf[(64 + 8*wv + t)*PF + lane] = fsilu(a12[t>>1][t&1]);
  }
  __syncthreads();                                        // B20

  // P8: g = sigmoid(t1@act_w2+b2); mv *= g
  { f32x2 gq2[4];
    #pragma unroll
    for (int t2=0;t2<4;++t2) gq2[t2] = ld2(wf + OFF_ACT_B2 + 8*wv + 2*t2);
    #pragma unroll 2
    for (int k=0;k<64;++k){
      float a = smf[(64+k)*PF + lane];
      const float* wr = wf + OFF_ACT_W2 + k*64 + 8*wv;
      #pragma unroll
      for (int t2=0;t2<4;++t2) gq2[t2] += a*ld2(wr + 2*t2);
    }
    #pragma unroll
    for (int t=0;t<8;++t){
      float g = fsig(gq2[t>>1][t&1]);
      mv2[0][t>>1][t&1] *= g; mv2[1][t>>1][t&1] *= g; mv2[2][t>>1][t&1] *= g;
    }
  }
  __syncthreads();                                        // B21

  // ===== COALESCED scatter via LDS transpose (channels over smf[0,128)) =====
  // Phase A: sg*msg_s (128 ch)
  { float sg = s_sgate[lane];
    #pragma unroll
    for (int j=0;j<16;++j) smf[(16*wv + j)*PF + lane] = sg*msg2[j>>1][j&1];
  }
  __syncthreads();
  for (int lin=tid; lin<8192; lin+=512){
    int row = lin >> 7, ch = lin & 127;
    atomicAdd(acc_s + (size_t)s_dst[row]*128 + ch, smf[ch*PF + row]);
  }
  __syncthreads();
  // Phase B half 1: u in [0,32) (waves 0..3), 96 ch
  if (wv < 4){
    #pragma unroll
    for (int t=0;t<8;++t){
      int u = 8*wv + t;
      float vgt = vga[t];
      smf[(3*u+0)*PF + lane] = vgt*mv2[0][t>>1][t&1];
      smf[(3*u+1)*PF + lane] = vgt*mv2[1][t>>1][t&1];
      smf[(3*u+2)*PF + lane] = vgt*mv2[2][t>>1][t&1];
    }
  }
  __syncthreads();
  for (int lin=tid; lin<6144; lin+=512){
    int row = lin / 96, ch = lin % 96;
    atomicAdd(acc_v + (size_t)s_dst[row]*192 + ch, smf[ch*PF + row]);
  }
  __syncthreads();
  // Phase B half 2: u in [32,64) (waves 4..7), 96 ch
  if (wv >= 4){
    #pragma unroll
    for (int t=0;t<8;++t){
      int um = 8*(wv-4) + t;
      float vgt = vga[t];
      smf[(3*um+0)*PF + lane] = vgt*mv2[0][t>>1][t&1];
      smf[(3*um+1)*PF + lane] = vgt*mv2[1][t>>1][t&1];
      smf[(3*um+2)*PF + lane] = vgt*mv2[2][t>>1][t&1];
    }
  }
  __syncthreads();
  for (int lin=tid; lin<6144; lin+=512){
    int row = lin / 96, ch = lin % 96;
    atomicAdd(acc_v + (size_t)s_dst[row]*192 + 96 + ch, smf[ch*PF + row]);
  }
  __syncthreads();
  // Phase C: vg (64 ch) + sg
  #pragma unroll
  for (int t=0;t<8;++t) smf[(8*wv + t)*PF + lane] = vga[t];
  __syncthreads();
  for (int lin=tid; lin<4096; lin+=512){
    int row = lin >> 6, ch = lin & 63;
    atomicAdd(acc_vg + (size_t)s_dst[row]*64 + ch, smf[ch*PF + row]);
  }
  if (tid < 64) atomicAdd(acc_sg + s_dst[tid], s_sgate[tid]);
}

// ---------------- node kernel ----------------
__launch_bounds__(256,2)
__global__ void k_node(const float* __restrict__ h, const float* __restrict__ wf,
                       const float* __restrict__ acc_s, const float* __restrict__ acc_sg,
                       const float* __restrict__ acc_vg, const float* __restrict__ acc_v,
                       float* __restrict__ out)
{
  __shared__ float smf[160*PF];
  const int tid  = threadIdx.x;
  const int lane = tid & 63;
  const int wv   = __builtin_amdgcn_readfirstlane(tid >> 6);
  const int n0   = blockIdx.x * 64;
  const int n    = n0 + lane;
  const int w0   = 16*wv;

  float agg[16][3], vnr[16];
  f32x2 sva2[3][8];
  #pragma unroll
  for (int t=0;t<16;++t){
    float inv = 1.f/(acc_vg[n*64 + w0 + t] + 1e-6f);
    agg[t][0] = acc_v[n*192 + (w0+t)*3 + 0]*inv;
    agg[t][1] = acc_v[n*192 + (w0+t)*3 + 1]*inv;
    agg[t][2] = acc_v[n*192 + (w0+t)*3 + 2]*inv;
    vnr[t] = sqrtf(agg[t][0]*agg[t][0]+agg[t][1]*agg[t][1]+agg[t][2]*agg[t][2]+1e-12f);
    smf[(96 + w0 + t)*PF + lane] = vnr[t];
  }
  #pragma unroll
  for (int t2=0;t2<8;++t2){ sva2[0][t2]=0.f; sva2[1][t2]=0.f; sva2[2][t2]=0.f; }

  f32x2 outs2[16];
  #pragma unroll
  for (int j2=0;j2<16;++j2) outs2[j2] = ld2(wf + OFF_SELF_BS + 32*wv + 2*j2);

  for (int cc=0; cc<2; ++cc){
    for (int lin=tid; lin<1024; lin+=256){
      int row = lin>>4, c4 = lin&15;
      float4 v = reinterpret_cast<const float4*>(h)[(n0+row)*80 + cc*16 + c4];
      smf[(c4*4+0)*PF + row] = v.x;
      smf[(c4*4+1)*PF + row] = v.y;
      smf[(c4*4+2)*PF + row] = v.z;
      smf[(c4*4+3)*PF + row] = v.w;
    }
    __syncthreads();
    #pragma unroll 2
    for (int k=0;k<64;++k){
      float a = smf[k*PF + lane];
      const float* wr = wf + OFF_SELF_WS + (cc*64+k)*128 + 32*wv;
      #pragma unroll
      for (int j2=0;j2<16;++j2) outs2[j2] += a*ld2(wr + 2*j2);
    }
    __syncthreads();
  }
  for (int cc=0; cc<2; ++cc){
    for (int lin=tid; lin<1536; lin+=256){
      int row = lin/24, c6 = lin%24;
      float4 v = reinterpret_cast<const float4*>(h)[(n0+row)*80 + 32 + cc*24 + c6];
      smf[(c6*4+0)*PF + row] = v.x;
      smf[(c6*4+1)*PF + row] = v.y;
      smf[(c6*4+2)*PF + row] = v.z;
      smf[(c6*4+3)*PF + row] = v.w;
    }
    __syncthreads();
    #pragma unroll 2
    for (int ul=0; ul<32; ++ul){
      float x0 = smf[(3*ul+0)*PF + lane];
      float x1 = smf[(3*ul+1)*PF + lane];
      float x2 = smf[(3*ul+2)*PF + lane];
      const float* wr = wf + OFF_SELF_WV + (cc*32+ul)*64 + w0;
      #pragma unroll
      for (int t2=0;t2<8;++t2){
        f32x2 wt2 = ld2(wr + 2*t2);
        sva2[0][t2] += x0*wt2; sva2[1][t2] += x1*wt2; sva2[2][t2] += x2*wt2;
      }
    }
    __syncthreads();
  }

  f32x2 rv2[8];
  #pragma unroll
  for (int t2=0;t2<8;++t2) rv2[t2] = ld2(wf + OFF_VR_B + w0 + 2*t2);
  #pragma unroll 2
  for (int k=0;k<64;++k){
    float a = smf[(96+k)*PF + lane];
    const float* wr = wf + OFF_VR_W + k*64 + w0;
    #pragma unroll
    for (int t2=0;t2<8;++t2) rv2[t2] += a*ld2(wr + 2*t2);
  }

  { float inv = 1.f/(acc_sg[n] + 1e-6f);
    const float* ap = acc_s + (size_t)n*128 + 32*wv;
    #pragma unroll
    for (int j2=0;j2<16;++j2) outs2[j2] += ld2(ap + 2*j2)*inv;
  }

  float* orow = out + (size_t)n*320;
  { float4* o4 = reinterpret_cast<float4*>(orow + 32*wv);
    #pragma unroll
    for (int j=0;j<8;++j){
      float4 v;
      v.x=outs2[2*j+0][0]; v.y=outs2[2*j+0][1];
      v.z=outs2[2*j+1][0]; v.w=outs2[2*j+1][1];
      o4[j] = v;
    }
  }
  { float vbuf[48];
    #pragma unroll
    for (int t=0;t<16;++t){
      float sc = rv2[t>>1][t&1]/(vnr[t]+1e-6f);
      vbuf[t*3+0] = agg[t][0]*sc + sva2[0][t>>1][t&1];
      vbuf[t*3+1] = agg[t][1]*sc + sva2[1][t>>1][t&1];
      vbuf[t*3+2] = agg[t][2]*sc + sva2[2][t>>1][t&1];
    }
    float4* o4 = reinterpret_cast<float4*>(orow + 128 + 48*wv);
    #pragma unroll
    for (int j=0;j<12;++j){
      float4 v; v.x=vbuf[4*j]; v.y=vbuf[4*j+1]; v.z=vbuf[4*j+2]; v.w=vbuf[4*j+3];
      o4[j] = v;
    }
  }
}

// ---------------- launch ----------------
extern "C" void kernel_launch(void* const* d_in, const int* in_sizes, int n_in,
                              void* d_out, int out_size, void* d_ws, size_t ws_size,
                              hipStream_t stream) {
  const float* h     = (const float*)d_in[0];
  const float* evec  = (const float*)d_in[1];
  const float* es    = (const float*)d_in[2];
  const float* edist = (const float*)d_in[3];
  const int* srcI    = (const int*)d_in[4];
  const int* dstI    = (const int*)d_in[5];
  const int* etyp    = (const int*)d_in[6];

  float* wsf    = (float*)d_ws;
  float* acc_s  = wsf + ACC_S_OFF;
  float* acc_sg = wsf + ACC_SG_OFF;
  float* acc_vg = wsf + ACC_VG_OFF;
  float* acc_v  = wsf + ACC_V_OFF;

  WCopy wc;
  const int ns[24]  = {8192,128,24576,192,24576,192,16384,8192,4096,8192,4096,64,4096,64,
                       4096,64,4160,65,10,4096,64,16384,128,4096};
  const int offs[24]= {OFF_RT_W,OFF_RT_B,OFF_RIN_W,OFF_RIN_B,OFF_ROUT_W,OFF_ROUT_B,
                       OFF_TP00,OFF_TP01,OFF_TP10,OFF_TP11,OFF_ACT_W1,OFF_ACT_B1,
                       OFF_ACT_W2,OFF_ACT_B2,OFF_GATE_W1,OFF_GATE_B1,OFF_GATE_W2,OFF_GATE_B2,
                       OFF_LSIG,OFF_VR_W,OFF_VR_B,OFF_SELF_WS,OFF_SELF_BS,OFF_SELF_WV};
  for (int a=0;a<24;++a){ wc.src[a] = (const float*)d_in[8+a]; wc.n[a]=ns[a]; wc.off[a]=offs[a]; }
  hipLaunchKernelGGL(k_copy, dim3(533), dim3(256), 0, stream, wc, wsf);

  { int nz = ACC_END - ACC_S_OFF;
    hipLaunchKernelGGL(k_zero, dim3((nz+255)/256), dim3(256), 0, stream, acc_s, nz); }

  hipLaunchKernelGGL(k_edge, dim3(N_EDGES/64), dim3(512), 0, stream,
                     h, evec, es, edist, srcI, dstI, etyp, wsf,
                     acc_s, acc_sg, acc_vg, acc_v);
  hipLaunchKernelGGL(k_node, dim3(N_NODES/64), dim3(256), 0, stream,
                     h, wsf, acc_s, acc_sg, acc_vg, acc_v, (float*)d_out);
}

// Round 14
// 1278.940 us; speedup vs baseline: 2.0660x; 1.0447x over previous
//
#include <hip/hip_runtime.h>

typedef unsigned int u32;
typedef float f32x2 __attribute__((ext_vector_type(2)));
typedef float f32x4 __attribute__((ext_vector_type(4)));
typedef short s16x8 __attribute__((ext_vector_type(8)));

#define N_NODES 32768
#define N_EDGES 262144
#define PF 65   // LDS pitch (floats): 64 edges + 1 pad

// ---------- fp32 weight buffer layout (float offsets in d_ws) ----------
enum : int {
  OFF_RT_W   = 0,       // [64,128]
  OFF_RT_B   = 8192,    // [128]
  OFF_RIN_W  = 8320,    // [128,192] (plain fp32, natural order; MFMA uses packs)
  OFF_RIN_B  = 32896,   // [192]
  OFF_ROUT_W = 33088,   // [128,192]
  OFF_ROUT_B = 57664,   // [192]
  OFF_TP00   = 57856,   // [128,128]
  OFF_TP01   = 74240,   // [128,64]
  OFF_TP10   = 82432,   // [64,64]
  OFF_TP11   = 86528,   // [64,128]
  OFF_ACT_W1 = 94720,   // [64,64]
  OFF_ACT_B1 = 98816,   // [64]
  OFF_ACT_W2 = 98880,   // [64,64]
  OFF_ACT_B2 = 102976,  // [64]
  OFF_GATE_W1= 103040,  // [64,64]
  OFF_GATE_B1= 107136,  // [64]
  OFF_GATE_W2= 107200,  // [64,65]
  OFF_GATE_B2= 111360,  // [65]
  OFF_LSIG   = 111428,  // [10]
  OFF_VR_W   = 111440,  // [64,64]
  OFF_VR_B   = 115536,  // [64]
  OFF_SELF_WS= 115600,  // [128,128]
  OFF_SELF_BS= 131984,  // [128]
  OFF_SELF_WV= 132112,  // [64,64]
  // bf16 B-frag pack of [tp00;tp11] stacked (K=192): [8ct][6ks][64][8]
  OFF_MSBF   = 136208,  // 12288 float slots
  // bf16 hi/lo B-frag packs for rin/rout: each [12ct][4ks][64][8] u16
  OFF_RINHI  = 148496,  // 12288
  OFF_RINLO  = 160784,  // 12288
  OFF_ROUTHI = 173072,  // 12288
  OFF_ROUTLO = 185360,  // 12288
  NWF        = 197648
};
enum : int {
  ACC_S_OFF  = NWF,
  ACC_SG_OFF = ACC_S_OFF + N_NODES*128,
  ACC_VG_OFF = ACC_SG_OFF + N_NODES,
  ACC_V_OFF  = ACC_VG_OFF + N_NODES*64,
  ACC_END    = ACC_V_OFF + N_NODES*192
};

__device__ __forceinline__ float fsilu(float x){ return x/(1.f+__expf(-x)); }
__device__ __forceinline__ float fsig (float x){ return 1.f/(1.f+__expf(-x)); }
__device__ __forceinline__ f32x2 ld2(const float* p){ return *reinterpret_cast<const f32x2*>(p); }
__device__ __forceinline__ unsigned short f2bf(float f){
  u32 x = __builtin_bit_cast(u32, f);
  u32 r = x + 0x7FFFu + ((x>>16)&1u);
  return (unsigned short)(r>>16);
}
__device__ __forceinline__ float bf2f(unsigned short h){
  u32 x = ((u32)h)<<16; return __builtin_bit_cast(float, x);
}

#define SQ3f     1.7320508075688772f
#define INV_SQ3f 0.5773502691896258f

__global__ void k_zero(float* __restrict__ p, int n){
  int t = blockIdx.x*256 + threadIdx.x;
  if (t < n) p[t] = 0.f;
}

// weight copy:
//  a=2 (rin_w) / a=4 (rout_w): plain fp32 + SPLIT hi/lo bf16 B-frag packs
//  a=6 (tp00) / a=9 (tp11): plain fp32 + stacked bf16 B-frag pack (msg_s MFMA)
struct WCopy { const float* src[24]; int n[24]; int off[24]; };

__global__ void k_copy(WCopy w, float* __restrict__ dst){
  int t = blockIdx.x*256 + threadIdx.x;
  unsigned short* ms = reinterpret_cast<unsigned short*>(dst + OFF_MSBF);
  for (int a=0;a<24;++a){
    int n = w.n[a];
    if (t < n){
      float v = w.src[a][t];
      dst[w.off[a]+t] = v;
      if (a == 2 || a == 4){
        // B-frag (16x16x32): lane ln holds B[k=ks*32+((ln>>4)&3)*8+j][c=ct*16+(ln&15)]
        int k = t/192, c = t%192;
        int ct = c>>4;                      // 0..11
        int ks = k>>5;                      // 0..3
        int ln = (c&15) | (((k>>3)&3)<<4);
        int j  = k&7;
        int idx = ((ct*4+ks)*64 + ln)*8 + j;
        unsigned short hi = f2bf(v);
        unsigned short lo = f2bf(v - bf2f(hi));
        if (a == 2){
          reinterpret_cast<unsigned short*>(dst + OFF_RINHI)[idx] = hi;
          reinterpret_cast<unsigned short*>(dst + OFF_RINLO)[idx] = lo;
        } else {
          reinterpret_cast<unsigned short*>(dst + OFF_ROUTHI)[idx] = hi;
          reinterpret_cast<unsigned short*>(dst + OFF_ROUTLO)[idx] = lo;
        }
      }
      if (a == 6 || a == 9){
        int k = t/128, c = t%128;
        int kg = (a==9) ? 128+k : k;        // tp11 stacked at K rows 128..191
        int ct = c>>4;
        int ks = kg>>5;                     // 0..5
        int ln = (c&15) | (((kg>>3)&3)<<4);
        int j  = kg&7;
        ms[((ct*6+ks)*64 + ln)*8 + j] = f2bf(v);
      }
      return;
    }
    t -= n;
  }
}

// ---------------- edge kernel ----------------
// R14 = R13 + SPLIT-bf16 (hi+lo) MFMA for rin AND rout GEMMs.
//   D = Ahi@Bhi + Ahi@Blo + Alo@Bhi  (~16 mantissa bits ~ fp32-grade;
//   residual ~1e-4 -> v-path amplification 150x -> ~0.015, safe).
// Scales redistributed through a TRANSIENT fp32 LDS buffer (2 passes of
// 96 cols through smf[0,96)) then live in registers -> v-path numerics
// preserved (R11 lesson: bf16 STORAGE of scales was the failure).
// trunk lives in dedicated hi/lo bf16 buffers (34.8KB), which after rout
// are overlaid by x_bf (msg_s A-frags). smf shrinks 192->128 ch.
// LDS total 68.6KB -> 2 blocks/CU kept. Removes 6144 scalar FMAs/thread.
__launch_bounds__(512,4)
__global__ void k_edge(const float* __restrict__ h, const float* __restrict__ evec,
                       const float* __restrict__ es_g, const float* __restrict__ edist,
                       const int* __restrict__ src_idx, const int* __restrict__ dst_idx,
                       const int* __restrict__ etype, const float* __restrict__ wf,
                       float* __restrict__ acc_s, float* __restrict__ acc_sg,
                       float* __restrict__ acc_vg, float* __restrict__ acc_v)
{
  __shared__ float smf[128*PF];              // es|ge -> scalebuf -> TP staging -> msgT -> scatter
  __shared__ unsigned short tkbuf[2*64*136]; // trunk hi|lo bf16 A-frags; later x_bf overlay
  __shared__ float s_sgate[64];
  __shared__ int   s_dst[64];

  unsigned short* trunk_hi = tkbuf;
  unsigned short* trunk_lo = tkbuf + 64*136;
  unsigned short* x_bf     = tkbuf;          // overlay (trunk dead before TP)

  const int tid  = threadIdx.x;
  const int lane = tid & 63;
  const int wv   = __builtin_amdgcn_readfirstlane(tid >> 6);   // 0..7
  const int e0   = blockIdx.x * 64;
  const int e    = e0 + lane;

  if (tid >= 64 && tid < 128) s_dst[tid-64] = dst_idx[e0 + tid-64];

  const int srcn = src_idx[e];
  const float* hrow = h + (size_t)srcn*320;
  const float4* hrow4 = reinterpret_cast<const float4*>(hrow);

  float y0,y1,y2;
  { float vx=evec[e*3], vy=evec[e*3+1], vz=evec[e*3+2];
    float rn = SQ3f * rsqrtf(vx*vx+vy*vy+vz*vz+1e-12f);
    y0=vx*rn; y1=vy*rn; y2=vz*rn; }

  // P0: stage edge_scalars -> smf [0,64)
  for (int lin=tid; lin<1024; lin+=512){
    int row = lin>>4, c4 = lin&15;
    float4 v = reinterpret_cast<const float4*>(es_g)[(e0+row)*16 + c4];
    smf[(c4*4+0)*PF + row] = v.x;
    smf[(c4*4+1)*PF + row] = v.y;
    smf[(c4*4+2)*PF + row] = v.z;
    smf[(c4*4+3)*PF + row] = v.w;
  }
  __syncthreads();                                        // B1

  // GATE 1: ge = silu(es@gate_w1+b1) -> smf[64,128)
  { f32x2 ge2[4];
    #pragma unroll
    for (int t2=0;t2<4;++t2) ge2[t2] = ld2(wf + OFF_GATE_B1 + 8*wv + 2*t2);
    #pragma unroll 2
    for (int k=0;k<64;++k){
      float a = smf[k*PF + lane];
      const float* wr = wf + OFF_GATE_W1 + k*64 + 8*wv;
      #pragma unroll
      for (int t2=0;t2<4;++t2) ge2[t2] += a*ld2(wr + 2*t2);
    }
    #pragma unroll
    for (int t=0;t<8;++t) smf[(64 + 8*wv + t)*PF + lane] = fsilu(ge2[t>>1][t&1]);
  }
  __syncthreads();                                        // B2

  // GATE 2: go = ge@gate_w2 + b2 -> vg (registers), sgate
  float vga[8];
  { float g0 = wf[OFF_GATE_B2];
    #pragma unroll
    for (int t=0;t<8;++t) vga[t] = wf[OFF_GATE_B2 + 1 + 8*wv + t];
    #pragma unroll 2
    for (int k=0;k<64;++k){
      float a = smf[(64+k)*PF + lane];
      const float* wr = wf + OFF_GATE_W2 + k*65;
      g0 += a*wr[0];
      #pragma unroll
      for (int t=0;t<8;++t) vga[t] += a*wr[1 + 8*wv + t];
    }
    #pragma unroll
    for (int t=0;t<8;++t) vga[t] = fsig(vga[t]);
    if (wv == 0){
      float sigma = __expf(wf[OFF_LSIG + etype[e]]);
      s_sgate[lane] = fsig(g0) * __expf(-edist[e]/sigma);
    }
  }
  __syncthreads();                                        // B3 (GE dead)

  // P1: trunk = silu(es@rt_w+b), 16 cols/wave -> hi/lo bf16 A-frag buffers
  { f32x2 acc2[8];
    #pragma unroll
    for (int j2=0;j2<8;++j2) acc2[j2] = ld2(wf + OFF_RT_B + 16*wv + 2*j2);
    #pragma unroll 2
    for (int k=0;k<64;++k){
      float a = smf[k*PF + lane];
      const float* wr = wf + OFF_RT_W + k*128 + 16*wv;
      #pragma unroll
      for (int j2=0;j2<8;++j2) acc2[j2] += a*ld2(wr + 2*j2);
    }
    u32* th32 = reinterpret_cast<u32*>(trunk_hi);
    u32* tl32 = reinterpret_cast<u32*>(trunk_lo);
    #pragma unroll
    for (int j2=0;j2<8;++j2){
      float t0 = fsilu(acc2[j2][0]), t1 = fsilu(acc2[j2][1]);
      unsigned short h0 = f2bf(t0), h1 = f2bf(t1);
      unsigned short l0 = f2bf(t0 - bf2f(h0)), l1 = f2bf(t1 - bf2f(h1));
      th32[(lane*136 + 16*wv)/2 + j2] = (u32)h0 | ((u32)h1<<16);
      tl32[(lane*136 + 16*wv)/2 + j2] = (u32)l0 | ((u32)l1<<16);
    }
  }
  __syncthreads();                                        // B4 (es dead)

  // ===== A-fragments (K=128, 4 ksteps) from trunk hi/lo =====
  const int etile = wv & 3, g = wv >> 2;
  const int erow  = etile*16 + (lane&15);
  const int kg    = (lane>>4)<<3;
  s16x8 ahi[4], alo[4];
  #pragma unroll
  for (int ks=0;ks<4;++ks){
    ahi[ks] = *reinterpret_cast<const s16x8*>(trunk_hi + erow*136 + ks*32 + kg);
    alo[ks] = *reinterpret_cast<const s16x8*>(trunk_lo + erow*136 + ks*32 + kg);
  }

  float sregS[16], sregV[8], souts[16], soutv[8];
  const s16x8* rinhi8  = reinterpret_cast<const s16x8*>(wf + OFF_RINHI);
  const s16x8* rinlo8  = reinterpret_cast<const s16x8*>(wf + OFF_RINLO);
  const s16x8* routhi8 = reinterpret_cast<const s16x8*>(wf + OFF_ROUTHI);
  const s16x8* routlo8 = reinterpret_cast<const s16x8*>(wf + OFF_ROUTLO);

  // ===== RIN split-MFMA, pass 0: ctiles 0..5 (cols 0..95) =====
  #pragma unroll
  for (int i=0;i<3;++i){
    int ct = 3*g + i;
    float bias = 1.f + wf[OFF_RIN_B + ct*16 + (lane&15)];
    f32x4 d = {bias,bias,bias,bias};
    #pragma unroll
    for (int ks=0;ks<4;++ks){
      s16x8 bh = rinhi8[(ct*4+ks)*64 + lane];
      d = __builtin_amdgcn_mfma_f32_16x16x32_bf16(ahi[ks], bh, d, 0,0,0);
      d = __builtin_amdgcn_mfma_f32_16x16x32_bf16(ahi[ks], rinlo8[(ct*4+ks)*64 + lane], d, 0,0,0);
      d = __builtin_amdgcn_mfma_f32_16x16x32_bf16(alo[ks], bh, d, 0,0,0);
    }
    int cl = ct*16 + (lane&15);
    #pragma unroll
    for (int r=0;r<4;++r) smf[cl*PF + etile*16 + ((lane>>4)<<2) + r] = d[r];
  }
  __syncthreads();
  if (wv < 6){
    #pragma unroll
    for (int i=0;i<16;++i) sregS[i] = smf[(16*wv+i)*PF + lane];
  }
  __syncthreads();
  // ===== RIN pass 1: ctiles 6..11 (cols 96..191) =====
  #pragma unroll
  for (int i=0;i<3;++i){
    int ct = 6 + 3*g + i;
    float bias = 1.f + wf[OFF_RIN_B + ct*16 + (lane&15)];
    f32x4 d = {bias,bias,bias,bias};
    #pragma unroll
    for (int ks=0;ks<4;++ks){
      s16x8 bh = rinhi8[(ct*4+ks)*64 + lane];
      d = __builtin_amdgcn_mfma_f32_16x16x32_bf16(ahi[ks], bh, d, 0,0,0);
      d = __builtin_amdgcn_mfma_f32_16x16x32_bf16(ahi[ks], rinlo8[(ct*4+ks)*64 + lane], d, 0,0,0);
      d = __builtin_amdgcn_mfma_f32_16x16x32_bf16(alo[ks], bh, d, 0,0,0);
    }
    int cl = ct*16 + (lane&15) - 96;
    #pragma unroll
    for (int r=0;r<4;++r) smf[cl*PF + etile*16 + ((lane>>4)<<2) + r] = d[r];
  }
  __syncthreads();
  if (wv >= 6){
    #pragma unroll
    for (int i=0;i<16;++i) sregS[i] = smf[(16*wv+i-96)*PF + lane];
  }
  #pragma unroll
  for (int t=0;t<8;++t) sregV[t] = smf[(32 + 8*wv + t)*PF + lane];
  __syncthreads();

  // ===== ROUT split-MFMA, pass 0: ctiles 0..5 =====
  #pragma unroll
  for (int i=0;i<3;++i){
    int ct = 3*g + i;
    float bias = 1.f + wf[OFF_ROUT_B + ct*16 + (lane&15)];
    f32x4 d = {bias,bias,bias,bias};
    #pragma unroll
    for (int ks=0;ks<4;++ks){
      s16x8 bh = routhi8[(ct*4+ks)*64 + lane];
      d = __builtin_amdgcn_mfma_f32_16x16x32_bf16(ahi[ks], bh, d, 0,0,0);
      d = __builtin_amdgcn_mfma_f32_16x16x32_bf16(ahi[ks], routlo8[(ct*4+ks)*64 + lane], d, 0,0,0);
      d = __builtin_amdgcn_mfma_f32_16x16x32_bf16(alo[ks], bh, d, 0,0,0);
    }
    int cl = ct*16 + (lane&15);
    #pragma unroll
    for (int r=0;r<4;++r) smf[cl*PF + etile*16 + ((lane>>4)<<2) + r] = d[r];
  }
  __syncthreads();
  if (wv < 6){
    #pragma unroll
    for (int i=0;i<16;++i) souts[i] = smf[(16*wv+i)*PF + lane];
  }
  __syncthreads();
  // ===== ROUT pass 1: ctiles 6..11 =====
  #pragma unroll
  for (int i=0;i<3;++i){
    int ct = 6 + 3*g + i;
    float bias = 1.f + wf[OFF_ROUT_B + ct*16 + (lane&15)];
    f32x4 d = {bias,bias,bias,bias};
    #pragma unroll
    for (int ks=0;ks<4;++ks){
      s16x8 bh = routhi8[(ct*4+ks)*64 + lane];
      d = __builtin_amdgcn_mfma_f32_16x16x32_bf16(ahi[ks], bh, d, 0,0,0);
      d = __builtin_amdgcn_mfma_f32_16x16x32_bf16(ahi[ks], routlo8[(ct*4+ks)*64 + lane], d, 0,0,0);
      d = __builtin_amdgcn_mfma_f32_16x16x32_bf16(alo[ks], bh, d, 0,0,0);
    }
    int cl = ct*16 + (lane&15) - 96;
    #pragma unroll
    for (int r=0;r<4;++r) smf[cl*PF + etile*16 + ((lane>>4)<<2) + r] = d[r];
  }
  __syncthreads();
  if (wv >= 6){
    #pragma unroll
    for (int i=0;i<16;++i) souts[i] = smf[(16*wv+i-96)*PF + lane];
  }
  #pragma unroll
  for (int t=0;t<8;++t) soutv[t] = smf[(32 + 8*wv + t)*PF + lane];
  __syncthreads();                                        // trunk + scalebuf dead

  f32x2 svv2[4];
  #pragma unroll
  for (int t2=0;t2<4;++t2) svv2[t2] = 0.f;

  u32* xb32 = reinterpret_cast<u32*>(x_bf);

  // ---- TP scalar, chunk 0: cols [0,64) staged by waves 0..3 (fp32 + bf16) ----
  if (wv < 4){
    #pragma unroll
    for (int q=0;q<4;++q){
      float4 v = hrow4[4*wv + q];
      int s = 16*wv + 4*q;
      float x0 = v.x*sregS[4*q+0];
      float x1 = v.y*sregS[4*q+1];
      float x2 = v.z*sregS[4*q+2];
      float x3 = v.w*sregS[4*q+3];
      smf[(s+0)*PF + lane] = x0;
      smf[(s+1)*PF + lane] = x1;
      smf[(s+2)*PF + lane] = x2;
      smf[(s+3)*PF + lane] = x3;
      xb32[lane*100 + (s>>1)    ] = (u32)f2bf(x0) | ((u32)f2bf(x1)<<16);
      xb32[lane*100 + (s>>1) + 1] = (u32)f2bf(x2) | ((u32)f2bf(x3)<<16);
    }
  }
  __syncthreads();                                        // B5
  #pragma unroll 2
  for (int k=0;k<64;++k){
    float a = smf[k*PF + lane];
    const float* w1p = wf + OFF_TP01 + k*64 + 8*wv;
    #pragma unroll
    for (int t2=0;t2<4;++t2) svv2[t2] += a*ld2(w1p + 2*t2);
  }
  __syncthreads();                                        // B6
  // ---- TP scalar, chunk 1: cols [64,128) staged by waves 4..7 ----
  if (wv >= 4){
    #pragma unroll
    for (int q=0;q<4;++q){
      float4 v = hrow4[4*wv + q];
      int gcol = 16*wv + 4*q;     // [64,128)
      int s = gcol - 64;
      float x0 = v.x*sregS[4*q+0];
      float x1 = v.y*sregS[4*q+1];
      float x2 = v.z*sregS[4*q+2];
      float x3 = v.w*sregS[4*q+3];
      smf[(s+0)*PF + lane] = x0;
      smf[(s+1)*PF + lane] = x1;
      smf[(s+2)*PF + lane] = x2;
      smf[(s+3)*PF + lane] = x3;
      xb32[lane*100 + (gcol>>1)    ] = (u32)f2bf(x0) | ((u32)f2bf(x1)<<16);
      xb32[lane*100 + (gcol>>1) + 1] = (u32)f2bf(x2) | ((u32)f2bf(x3)<<16);
    }
  }
  __syncthreads();                                        // B7
  #pragma unroll 2
  for (int k=0;k<64;++k){
    float a = smf[k*PF + lane];
    const float* w1p = wf + OFF_TP01 + (64+k)*64 + 8*wv;
    #pragma unroll
    for (int t2=0;t2<4;++t2) svv2[t2] += a*ld2(w1p + 2*t2);
  }
  __syncthreads();                                        // B8

  // rank-1 init: mv = svv*y (fp32)
  f32x2 mv2[3][4];
  #pragma unroll
  for (int t2=0;t2<4;++t2){
    mv2[0][t2] = svv2[t2]*y0; mv2[1][t2] = svv2[t2]*y1; mv2[2][t2] = svv2[t2]*y2;
  }

  // ---- TP vector: 4 chunks of 16 u's; XB [0,48) fp32; dot -> x_bf bf16 ----
  for (int vc=0; vc<4; ++vc){
    if ((wv>>1) == vc){
      const int half = wv & 1;
      float dreg[8];
      #pragma unroll
      for (int t=0;t<8;++t) dreg[t]=0.f;
      #pragma unroll
      for (int q=0;q<6;++q){
        float4 v = hrow4[32 + 6*wv + q];
        float vv[4] = {v.x, v.y, v.z, v.w};
        #pragma unroll
        for (int c=0;c<4;++c){
          int l = 4*q + c;             // 0..23
          int t = l/3, d = l - 3*t;    // compile-time
          float x = vv[c]*sregV[t];
          smf[(3*(8*half + t) + d)*PF + lane] = x;
          dreg[t] += x * (d==0 ? y0 : (d==1 ? y1 : y2));
        }
      }
      #pragma unroll
      for (int t=0;t<8;++t)
        x_bf[lane*200 + 128 + 16*vc + 8*half + t] = f2bf(dreg[t]*INV_SQ3f);
    }
    __syncthreads();                                      // stage done
    #pragma unroll 2
    for (int ul=0; ul<16; ++ul){
      float x0 = smf[(3*ul+0)*PF + lane];
      float x1 = smf[(3*ul+1)*PF + lane];
      float x2 = smf[(3*ul+2)*PF + lane];
      const float* wr = wf + OFF_TP10 + (16*vc + ul)*64 + 8*wv;
      #pragma unroll
      for (int t2=0;t2<4;++t2){
        f32x2 wt2 = ld2(wr + 2*t2);
        mv2[0][t2] += x0*wt2; mv2[1][t2] += x1*wt2; mv2[2][t2] += x2*wt2;
      }
    }
    __syncthreads();                                      // compute done
  }

  // ===== MFMA: msg_s = [x|dot] @ [tp00;tp11], K=192, 24 MFMAs/wave =====
  { const s16x8* ms8 = reinterpret_cast<const s16x8*>(wf + OFF_MSBF);
    f32x4 dacc[4];
    #pragma unroll
    for (int i=0;i<4;++i) dacc[i] = f32x4{0.f,0.f,0.f,0.f};
    #pragma unroll
    for (int ks=0;ks<6;++ks){
      s16x8 af = *reinterpret_cast<const s16x8*>(x_bf + erow*200 + ks*32 + kg);
      #pragma unroll
      for (int i=0;i<4;++i){
        int ct = 4*g + i;
        dacc[i] = __builtin_amdgcn_mfma_f32_16x16x32_bf16(af, ms8[(ct*6+ks)*64 + lane], dacc[i], 0,0,0);
      }
    }
    // D layout (m89): col = lane&15, row = (lane>>4)*4 + r
    #pragma unroll
    for (int i=0;i<4;++i){
      int c = (4*g+i)*16 + (lane&15);
      #pragma unroll
      for (int r=0;r<4;++r)
        smf[c*PF + etile*16 + ((lane>>4)<<2) + r] = dacc[i][r];
    }
  }
  __syncthreads();                                        // msgT ready

  // readback msg_s (16 cols/thread)
  f32x2 msg2[8];
  #pragma unroll
  for (int j2=0;j2<8;++j2){
    msg2[j2][0] = smf[(16*wv + 2*j2+0)*PF + lane];
    msg2[j2][1] = smf[(16*wv + 2*j2+1)*PF + lane];
  }
  __syncthreads();                                        // msgT dead

  // P6: apply scale_out + silu + vn -> VN smf[0,64)
  #pragma unroll
  for (int j=0;j<16;++j){
    float m = msg2[j>>1][j&1]*souts[j];
    msg2[j>>1][j&1] = fsilu(m);
  }
  #pragma unroll
  for (int t=0;t<8;++t){
    mv2[0][t>>1][t&1] *= soutv[t]; mv2[1][t>>1][t&1] *= soutv[t]; mv2[2][t>>1][t&1] *= soutv[t];
  }
  #pragma unroll
  for (int t=0;t<8;++t){
    float m0 = mv2[0][t>>1][t&1], m1 = mv2[1][t>>1][t&1], m2 = mv2[2][t>>1][t&1];
    float vn = sqrtf(m0*m0 + m1*m1 + m2*m2 + 1e-12f);
    smf[(8*wv + t)*PF + lane] = vn;
  }
  __syncthreads();                                        // B19

  // P7: t1 = silu(vn@act_w1+b1) -> smf[64,128)
  { f32x2 a12[4];
    #pragma unroll
    for (int t2=0;t2<4;++t2) a12[t2] = ld2(wf + OFF_ACT_B1 + 8*wv + 2*t2);
    #pragma unroll 2
    for (int k=0;k<64;++k){
      float a = smf[k*PF + lane];
      const float* wr = wf + OFF_ACT_W1 + k*64 + 8*wv;
      #pragma unroll
      for (int t2=0;t2<4;++t2) a12[t2] += a*ld2(wr + 2*t2);
    }
    #pragma unroll
    for (int t=0;t<8;++t) smf[(64 + 8*wv + t)*PF + lane] = fsilu(a12[t>>1][t&1]);
  }
  __syncthreads();                                        // B20

  // P8: g = sigmoid(t1@act_w2+b2); mv *= g
  { f32x2 gq2[4];
    #pragma unroll
    for (int t2=0;t2<4;++t2) gq2[t2] = ld2(wf + OFF_ACT_B2 + 8*wv + 2*t2);
    #pragma unroll 2
    for (int k=0;k<64;++k){
      float a = smf[(64+k)*PF + lane];
      const float* wr = wf + OFF_ACT_W2 + k*64 + 8*wv;
      #pragma unroll
      for (int t2=0;t2<4;++t2) gq2[t2] += a*ld2(wr + 2*t2);
    }
    #pragma unroll
    for (int t=0;t<8;++t){
      float gg = fsig(gq2[t>>1][t&1]);
      mv2[0][t>>1][t&1] *= gg; mv2[1][t>>1][t&1] *= gg; mv2[2][t>>1][t&1] *= gg;
    }
  }
  __syncthreads();                                        // B21

  // ===== COALESCED scatter via LDS transpose (smf[0,128)) =====
  // Phase A: sg*msg_s (128 ch)
  { float sg = s_sgate[lane];
    #pragma unroll
    for (int j=0;j<16;++j) smf[(16*wv + j)*PF + lane] = sg*msg2[j>>1][j&1];
  }
  __syncthreads();
  for (int lin=tid; lin<8192; lin+=512){
    int row = lin >> 7, ch = lin & 127;
    atomicAdd(acc_s + (size_t)s_dst[row]*128 + ch, smf[ch*PF + row]);
  }
  __syncthreads();
  // Phase B half 1: u in [0,32) (waves 0..3), 96 ch
  if (wv < 4){
    #pragma unroll
    for (int t=0;t<8;++t){
      int u = 8*wv + t;
      float vgt = vga[t];
      smf[(3*u+0)*PF + lane] = vgt*mv2[0][t>>1][t&1];
      smf[(3*u+1)*PF + lane] = vgt*mv2[1][t>>1][t&1];
      smf[(3*u+2)*PF + lane] = vgt*mv2[2][t>>1][t&1];
    }
  }
  __syncthreads();
  for (int lin=tid; lin<6144; lin+=512){
    int row = lin / 96, ch = lin % 96;
    atomicAdd(acc_v + (size_t)s_dst[row]*192 + ch, smf[ch*PF + row]);
  }
  __syncthreads();
  // Phase B half 2: u in [32,64) (waves 4..7), 96 ch
  if (wv >= 4){
    #pragma unroll
    for (int t=0;t<8;++t){
      int um = 8*(wv-4) + t;
      float vgt = vga[t];
      smf[(3*um+0)*PF + lane] = vgt*mv2[0][t>>1][t&1];
      smf[(3*um+1)*PF + lane] = vgt*mv2[1][t>>1][t&1];
      smf[(3*um+2)*PF + lane] = vgt*mv2[2][t>>1][t&1];
    }
  }
  __syncthreads();
  for (int lin=tid; lin<6144; lin+=512){
    int row = lin / 96, ch = lin % 96;
    atomicAdd(acc_v + (size_t)s_dst[row]*192 + 96 + ch, smf[ch*PF + row]);
  }
  __syncthreads();
  // Phase C: vg (64 ch) + sg
  #pragma unroll
  for (int t=0;t<8;++t) smf[(8*wv + t)*PF + lane] = vga[t];
  __syncthreads();
  for (int lin=tid; lin<4096; lin+=512){
    int row = lin >> 6, ch = lin & 63;
    atomicAdd(acc_vg + (size_t)s_dst[row]*64 + ch, smf[ch*PF + row]);
  }
  if (tid < 64) atomicAdd(acc_sg + s_dst[tid], s_sgate[tid]);
}

// ---------------- node kernel ----------------
__launch_bounds__(256,2)
__global__ void k_node(const float* __restrict__ h, const float* __restrict__ wf,
                       const float* __restrict__ acc_s, const float* __restrict__ acc_sg,
                       const float* __restrict__ acc_vg, const float* __restrict__ acc_v,
                       float* __restrict__ out)
{
  __shared__ float smf[160*PF];
  const int tid  = threadIdx.x;
  const int lane = tid & 63;
  const int wv   = __builtin_amdgcn_readfirstlane(tid >> 6);
  const int n0   = blockIdx.x * 64;
  const int n    = n0 + lane;
  const int w0   = 16*wv;

  float agg[16][3], vnr[16];
  f32x2 sva2[3][8];
  #pragma unroll
  for (int t=0;t<16;++t){
    float inv = 1.f/(acc_vg[n*64 + w0 + t] + 1e-6f);
    agg[t][0] = acc_v[n*192 + (w0+t)*3 + 0]*inv;
    agg[t][1] = acc_v[n*192 + (w0+t)*3 + 1]*inv;
    agg[t][2] = acc_v[n*192 + (w0+t)*3 + 2]*inv;
    vnr[t] = sqrtf(agg[t][0]*agg[t][0]+agg[t][1]*agg[t][1]+agg[t][2]*agg[t][2]+1e-12f);
    smf[(96 + w0 + t)*PF + lane] = vnr[t];
  }
  #pragma unroll
  for (int t2=0;t2<8;++t2){ sva2[0][t2]=0.f; sva2[1][t2]=0.f; sva2[2][t2]=0.f; }

  f32x2 outs2[16];
  #pragma unroll
  for (int j2=0;j2<16;++j2) outs2[j2] = ld2(wf + OFF_SELF_BS + 32*wv + 2*j2);

  for (int cc=0; cc<2; ++cc){
    for (int lin=tid; lin<1024; lin+=256){
      int row = lin>>4, c4 = lin&15;
      float4 v = reinterpret_cast<const float4*>(h)[(n0+row)*80 + cc*16 + c4];
      smf[(c4*4+0)*PF + row] = v.x;
      smf[(c4*4+1)*PF + row] = v.y;
      smf[(c4*4+2)*PF + row] = v.z;
      smf[(c4*4+3)*PF + row] = v.w;
    }
    __syncthreads();
    #pragma unroll 2
    for (int k=0;k<64;++k){
      float a = smf[k*PF + lane];
      const float* wr = wf + OFF_SELF_WS + (cc*64+k)*128 + 32*wv;
      #pragma unroll
      for (int j2=0;j2<16;++j2) outs2[j2] += a*ld2(wr + 2*j2);
    }
    __syncthreads();
  }
  for (int cc=0; cc<2; ++cc){
    for (int lin=tid; lin<1536; lin+=256){
      int row = lin/24, c6 = lin%24;
      float4 v = reinterpret_cast<const float4*>(h)[(n0+row)*80 + 32 + cc*24 + c6];
      smf[(c6*4+0)*PF + row] = v.x;
      smf[(c6*4+1)*PF + row] = v.y;
      smf[(c6*4+2)*PF + row] = v.z;
      smf[(c6*4+3)*PF + row] = v.w;
    }
    __syncthreads();
    #pragma unroll 2
    for (int ul=0; ul<32; ++ul){
      float x0 = smf[(3*ul+0)*PF + lane];
      float x1 = smf[(3*ul+1)*PF + lane];
      float x2 = smf[(3*ul+2)*PF + lane];
      const float* wr = wf + OFF_SELF_WV + (cc*32+ul)*64 + w0;
      #pragma unroll
      for (int t2=0;t2<8;++t2){
        f32x2 wt2 = ld2(wr + 2*t2);
        sva2[0][t2] += x0*wt2; sva2[1][t2] += x1*wt2; sva2[2][t2] += x2*wt2;
      }
    }
    __syncthreads();
  }

  f32x2 rv2[8];
  #pragma unroll
  for (int t2=0;t2<8;++t2) rv2[t2] = ld2(wf + OFF_VR_B + w0 + 2*t2);
  #pragma unroll 2
  for (int k=0;k<64;++k){
    float a = smf[(96+k)*PF + lane];
    const float* wr = wf + OFF_VR_W + k*64 + w0;
    #pragma unroll
    for (int t2=0;t2<8;++t2) rv2[t2] += a*ld2(wr + 2*t2);
  }

  { float inv = 1.f/(acc_sg[n] + 1e-6f);
    const float* ap = acc_s + (size_t)n*128 + 32*wv;
    #pragma unroll
    for (int j2=0;j2<16;++j2) outs2[j2] += ld2(ap + 2*j2)*inv;
  }

  float* orow = out + (size_t)n*320;
  { float4* o4 = reinterpret_cast<float4*>(orow + 32*wv);
    #pragma unroll
    for (int j=0;j<8;++j){
      float4 v;
      v.x=outs2[2*j+0][0]; v.y=outs2[2*j+0][1];
      v.z=outs2[2*j+1][0]; v.w=outs2[2*j+1][1];
      o4[j] = v;
    }
  }
  { float vbuf[48];
    #pragma unroll
    for (int t=0;t<16;++t){
      float sc = rv2[t>>1][t&1]/(vnr[t]+1e-6f);
      vbuf[t*3+0] = agg[t][0]*sc + sva2[0][t>>1][t&1];
      vbuf[t*3+1] = agg[t][1]*sc + sva2[1][t>>1][t&1];
      vbuf[t*3+2] = agg[t][2]*sc + sva2[2][t>>1][t&1];
    }
    float4* o4 = reinterpret_cast<float4*>(orow + 128 + 48*wv);
    #pragma unroll
    for (int j=0;j<12;++j){
      float4 v; v.x=vbuf[4*j]; v.y=vbuf[4*j+1]; v.z=vbuf[4*j+2]; v.w=vbuf[4*j+3];
      o4[j] = v;
    }
  }
}

// ---------------- launch ----------------
extern "C" void kernel_launch(void* const* d_in, const int* in_sizes, int n_in,
                              void* d_out, int out_size, void* d_ws, size_t ws_size,
                              hipStream_t stream) {
  const float* h     = (const float*)d_in[0];
  const float* evec  = (const float*)d_in[1];
  const float* es    = (const float*)d_in[2];
  const float* edist = (const float*)d_in[3];
  const int* srcI    = (const int*)d_in[4];
  const int* dstI    = (const int*)d_in[5];
  const int* etyp    = (const int*)d_in[6];

  float* wsf    = (float*)d_ws;
  float* acc_s  = wsf + ACC_S_OFF;
  float* acc_sg = wsf + ACC_SG_OFF;
  float* acc_vg = wsf + ACC_VG_OFF;
  float* acc_v  = wsf + ACC_V_OFF;

  WCopy wc;
  const int ns[24]  = {8192,128,24576,192,24576,192,16384,8192,4096,8192,4096,64,4096,64,
                       4096,64,4160,65,10,4096,64,16384,128,4096};
  const int offs[24]= {OFF_RT_W,OFF_RT_B,OFF_RIN_W,OFF_RIN_B,OFF_ROUT_W,OFF_ROUT_B,
                       OFF_TP00,OFF_TP01,OFF_TP10,OFF_TP11,OFF_ACT_W1,OFF_ACT_B1,
                       OFF_ACT_W2,OFF_ACT_B2,OFF_GATE_W1,OFF_GATE_B1,OFF_GATE_W2,OFF_GATE_B2,
                       OFF_LSIG,OFF_VR_W,OFF_VR_B,OFF_SELF_WS,OFF_SELF_BS,OFF_SELF_WV};
  for (int a=0;a<24;++a){ wc.src[a] = (const float*)d_in[8+a]; wc.n[a]=ns[a]; wc.off[a]=offs[a]; }
  hipLaunchKernelGGL(k_copy, dim3(533), dim3(256), 0, stream, wc, wsf);

  { int nz = ACC_END - ACC_S_OFF;
    hipLaunchKernelGGL(k_zero, dim3((nz+255)/256), dim3(256), 0, stream, acc_s, nz); }

  hipLaunchKernelGGL(k_edge, dim3(N_EDGES/64), dim3(512), 0, stream,
                     h, evec, es, edist, srcI, dstI, etyp, wsf,
                     acc_s, acc_sg, acc_vg, acc_v);
  hipLaunchKernelGGL(k_node, dim3(N_NODES/64), dim3(256), 0, stream,
                     h, wsf, acc_s, acc_sg, acc_vg, acc_v, (float*)d_out);
}

// Round 15
// 1149.494 us; speedup vs baseline: 2.2987x; 1.1126x over previous
//
#include <hip/hip_runtime.h>

typedef unsigned int u32;
typedef float f32x2 __attribute__((ext_vector_type(2)));
typedef float f32x4 __attribute__((ext_vector_type(4)));
typedef short s16x8 __attribute__((ext_vector_type(8)));

#define N_NODES 32768
#define N_EDGES 262144
#define PF 65   // LDS pitch (floats): 64 edges + 1 pad

// ---------- fp32 weight buffer layout (float offsets in d_ws) ----------
enum : int {
  OFF_RT_W   = 0,       // [64,128]
  OFF_RT_B   = 8192,    // [128]
  OFF_RIN_W  = 8320,    // [128,192]
  OFF_RIN_B  = 32896,   // [192]
  OFF_ROUT_W = 33088,   // [128,192]
  OFF_ROUT_B = 57664,   // [192]
  OFF_TP00   = 57856,   // [128,128]
  OFF_TP01   = 74240,   // [128,64]
  OFF_TP10   = 82432,   // [64,64]
  OFF_TP11   = 86528,   // [64,128]
  OFF_ACT_W1 = 94720,   // [64,64]
  OFF_ACT_B1 = 98816,   // [64]
  OFF_ACT_W2 = 98880,   // [64,64]
  OFF_ACT_B2 = 102976,  // [64]
  OFF_GATE_W1= 103040,  // [64,64]
  OFF_GATE_B1= 107136,  // [64]
  OFF_GATE_W2= 107200,  // [64,65]
  OFF_GATE_B2= 111360,  // [65]
  OFF_LSIG   = 111428,  // [10]
  OFF_VR_W   = 111440,  // [64,64]
  OFF_VR_B   = 115536,  // [64]
  OFF_SELF_WS= 115600,  // [128,128]
  OFF_SELF_BS= 131984,  // [128]
  OFF_SELF_WV= 132112,  // [64,64]
  // bf16 B-frag pack of [tp00;tp11] stacked (K=192): [8ct][6ks][64][8]
  OFF_MSBF   = 136208,  // 12288 float slots
  // bf16 hi/lo B-frag packs for rin/rout: each [12ct][4ks][64][8] u16
  OFF_RINHI  = 148496,  // 12288
  OFF_RINLO  = 160784,  // 12288
  OFF_ROUTHI = 173072,  // 12288
  OFF_ROUTLO = 185360,  // 12288
  // bf16 hi/lo B-frag packs for rt_w (K=64): each [8ct][2ks][64][8] u16
  OFF_RTHI   = 197648,  // 4096
  OFF_RTLO   = 201744,  // 4096
  // bf16 hi/lo B-frag packs for gate_w1 (K=64): each [4ct][2ks][64][8] u16
  OFF_GW1HI  = 205840,  // 2048
  OFF_GW1LO  = 207888,  // 2048
  NWF        = 209936
};
enum : int {
  ACC_S_OFF  = NWF,
  ACC_SG_OFF = ACC_S_OFF + N_NODES*128,
  ACC_VG_OFF = ACC_SG_OFF + N_NODES,
  ACC_V_OFF  = ACC_VG_OFF + N_NODES*64,
  ACC_END    = ACC_V_OFF + N_NODES*192
};

__device__ __forceinline__ float fsilu(float x){ return x/(1.f+__expf(-x)); }
__device__ __forceinline__ float fsig (float x){ return 1.f/(1.f+__expf(-x)); }
__device__ __forceinline__ f32x2 ld2(const float* p){ return *reinterpret_cast<const f32x2*>(p); }
__device__ __forceinline__ unsigned short f2bf(float f){
  u32 x = __builtin_bit_cast(u32, f);
  u32 r = x + 0x7FFFu + ((x>>16)&1u);
  return (unsigned short)(r>>16);
}
__device__ __forceinline__ float bf2f(unsigned short h){
  u32 x = ((u32)h)<<16; return __builtin_bit_cast(float, x);
}

#define SQ3f     1.7320508075688772f
#define INV_SQ3f 0.5773502691896258f

__global__ void k_zero(float* __restrict__ p, int n){
  int t = blockIdx.x*256 + threadIdx.x;
  if (t < n) p[t] = 0.f;
}

// weight copy + bf16 fragment packs:
//  a=0  rt_w    -> RTHI/RTLO   ([8ct][2ks], K=64)
//  a=2  rin_w   -> RINHI/RINLO ([12ct][4ks], K=128)
//  a=4  rout_w  -> ROUTHI/ROUTLO
//  a=6  tp00 / a=9 tp11 -> MSBF stacked ([8ct][6ks], K=192)
//  a=14 gate_w1 -> GW1HI/GW1LO ([4ct][2ks], K=64)
struct WCopy { const float* src[24]; int n[24]; int off[24]; };

__global__ void k_copy(WCopy w, float* __restrict__ dst){
  int t = blockIdx.x*256 + threadIdx.x;
  unsigned short* ms = reinterpret_cast<unsigned short*>(dst + OFF_MSBF);
  for (int a=0;a<24;++a){
    int n = w.n[a];
    if (t < n){
      float v = w.src[a][t];
      dst[w.off[a]+t] = v;
      if (a == 2 || a == 4){
        int k = t/192, c = t%192;
        int ct = c>>4, ks = k>>5;
        int ln = (c&15) | (((k>>3)&3)<<4);
        int j  = k&7;
        int idx = ((ct*4+ks)*64 + ln)*8 + j;
        unsigned short hi = f2bf(v);
        unsigned short lo = f2bf(v - bf2f(hi));
        if (a == 2){
          reinterpret_cast<unsigned short*>(dst + OFF_RINHI)[idx] = hi;
          reinterpret_cast<unsigned short*>(dst + OFF_RINLO)[idx] = lo;
        } else {
          reinterpret_cast<unsigned short*>(dst + OFF_ROUTHI)[idx] = hi;
          reinterpret_cast<unsigned short*>(dst + OFF_ROUTLO)[idx] = lo;
        }
      }
      if (a == 0){
        int k = t/128, c = t%128;
        int ct = c>>4, ks = k>>5;               // ct 0..7, ks 0..1
        int ln = (c&15) | (((k>>3)&3)<<4);
        int j  = k&7;
        int idx = ((ct*2+ks)*64 + ln)*8 + j;
        unsigned short hi = f2bf(v);
        unsigned short lo = f2bf(v - bf2f(hi));
        reinterpret_cast<unsigned short*>(dst + OFF_RTHI)[idx] = hi;
        reinterpret_cast<unsigned short*>(dst + OFF_RTLO)[idx] = lo;
      }
      if (a == 14){
        int k = t/64, c = t%64;
        int ct = c>>4, ks = k>>5;               // ct 0..3, ks 0..1
        int ln = (c&15) | (((k>>3)&3)<<4);
        int j  = k&7;
        int idx = ((ct*2+ks)*64 + ln)*8 + j;
        unsigned short hi = f2bf(v);
        unsigned short lo = f2bf(v - bf2f(hi));
        reinterpret_cast<unsigned short*>(dst + OFF_GW1HI)[idx] = hi;
        reinterpret_cast<unsigned short*>(dst + OFF_GW1LO)[idx] = lo;
      }
      if (a == 6 || a == 9){
        int k = t/128, c = t%128;
        int kg = (a==9) ? 128+k : k;
        int ct = c>>4, ks = kg>>5;
        int ln = (c&15) | (((kg>>3)&3)<<4);
        int j  = kg&7;
        ms[((ct*6+ks)*64 + ln)*8 + j] = f2bf(v);
      }
      return;
    }
    t -= n;
  }
}

// ---------------- edge kernel ----------------
// R15 = R14 + front-end split-MFMA (trunk + gate1) + ahi/alo pass-scoping.
// es staged DIRECTLY as hi/lo bf16 A-frags (es's only consumers were trunk
// & gate1, both MFMA now; no fp32 es copy). Per wave: trunk 4 tiles
// (24 MFMA) + gate1 2 tiles (12 MFMA) replace 768 pk-FMA issues/thread.
// Trunk D -> silu -> hi/lo split -> trunk_hi/lo (R14-verified layout);
// ge D -> smf[64,128) for the unchanged scalar gate2. ahi/alo reloaded
// inside each rin/rout pass to cut 32 long-lived regs (R14 spill signal:
// FETCH/WRITE +80/+174 MB).
__launch_bounds__(512,4)
__global__ void k_edge(const float* __restrict__ h, const float* __restrict__ evec,
                       const float* __restrict__ es_g, const float* __restrict__ edist,
                       const int* __restrict__ src_idx, const int* __restrict__ dst_idx,
                       const int* __restrict__ etype, const float* __restrict__ wf,
                       float* __restrict__ acc_s, float* __restrict__ acc_sg,
                       float* __restrict__ acc_vg, float* __restrict__ acc_v)
{
  __shared__ float smf[128*PF];              // ge -> scalebuf -> TP staging -> msgT -> scatter
  __shared__ unsigned short tkbuf[2*64*136]; // es hi/lo frags -> trunk hi/lo -> x_bf overlay
  __shared__ float s_sgate[64];
  __shared__ int   s_dst[64];

  unsigned short* es_hi    = tkbuf;              // [64][64] u16
  unsigned short* es_lo    = tkbuf + 64*64;      // [64][64] u16
  unsigned short* trunk_hi = tkbuf;              // [64][136] u16 (after es consumed)
  unsigned short* trunk_lo = tkbuf + 64*136;
  unsigned short* x_bf     = tkbuf;              // [64][200] u16 (after trunk dead)

  const int tid  = threadIdx.x;
  const int lane = tid & 63;
  const int wv   = __builtin_amdgcn_readfirstlane(tid >> 6);   // 0..7
  const int e0   = blockIdx.x * 64;
  const int e    = e0 + lane;

  if (tid >= 64 && tid < 128) s_dst[tid-64] = dst_idx[e0 + tid-64];

  const int srcn = src_idx[e];
  const float* hrow = h + (size_t)srcn*320;
  const float4* hrow4 = reinterpret_cast<const float4*>(hrow);

  float y0,y1,y2;
  { float vx=evec[e*3], vy=evec[e*3+1], vz=evec[e*3+2];
    float rn = SQ3f * rsqrtf(vx*vx+vy*vy+vz*vz+1e-12f);
    y0=vx*rn; y1=vy*rn; y2=vz*rn; }

  // P0: stage edge_scalars DIRECTLY as hi/lo bf16 A-frag layout
  for (int lin=tid; lin<1024; lin+=512){
    int row = lin>>4, c4 = lin&15;
    float4 v = reinterpret_cast<const float4*>(es_g)[(e0+row)*16 + c4];
    float xv[4] = {v.x, v.y, v.z, v.w};
    #pragma unroll
    for (int i=0;i<4;++i){
      unsigned short hh = f2bf(xv[i]);
      unsigned short ll = f2bf(xv[i] - bf2f(hh));
      es_hi[row*64 + c4*4 + i] = hh;
      es_lo[row*64 + c4*4 + i] = ll;
    }
  }
  __syncthreads();                                        // B1

  const int etile = wv & 3, g = wv >> 2;
  const int erow  = etile*16 + (lane&15);
  const int kg    = (lane>>4)<<3;

  // load es A-frags (2 ksteps, hi+lo) into registers
  s16x8 esh[2], esl[2];
  #pragma unroll
  for (int ks=0;ks<2;++ks){
    esh[ks] = *reinterpret_cast<const s16x8*>(es_hi + erow*64 + ks*32 + kg);
    esl[ks] = *reinterpret_cast<const s16x8*>(es_lo + erow*64 + ks*32 + kg);
  }
  __syncthreads();                                        // B2 (all es reads done)

  // ===== FRONT-END MFMA =====
  // trunk: ctiles 4g..4g+3 (cols), etile fixed -> writes trunk hi/lo
  { const s16x8* rthi8 = reinterpret_cast<const s16x8*>(wf + OFF_RTHI);
    const s16x8* rtlo8 = reinterpret_cast<const s16x8*>(wf + OFF_RTLO);
    #pragma unroll
    for (int i=0;i<4;++i){
      int ct = 4*g + i;                    // 0..7
      float bias = wf[OFF_RT_B + ct*16 + (lane&15)];
      f32x4 d = {bias,bias,bias,bias};
      #pragma unroll
      for (int ks=0;ks<2;++ks){
        s16x8 bh = rthi8[(ct*2+ks)*64 + lane];
        d = __builtin_amdgcn_mfma_f32_16x16x32_bf16(esh[ks], bh, d, 0,0,0);
        d = __builtin_amdgcn_mfma_f32_16x16x32_bf16(esh[ks], rtlo8[(ct*2+ks)*64 + lane], d, 0,0,0);
        d = __builtin_amdgcn_mfma_f32_16x16x32_bf16(esl[ks], bh, d, 0,0,0);
      }
      int col = ct*16 + (lane&15);
      #pragma unroll
      for (int r=0;r<4;++r){
        int ee = etile*16 + ((lane>>4)<<2) + r;
        float tv = fsilu(d[r]);
        unsigned short hh = f2bf(tv);
        trunk_hi[ee*136 + col] = hh;
        trunk_lo[ee*136 + col] = f2bf(tv - bf2f(hh));
      }
    }
  }
  // gate1: ctiles 2g, 2g+1 -> ge = silu(.) -> smf[64,128)
  { const s16x8* g1hi8 = reinterpret_cast<const s16x8*>(wf + OFF_GW1HI);
    const s16x8* g1lo8 = reinterpret_cast<const s16x8*>(wf + OFF_GW1LO);
    #pragma unroll
    for (int i=0;i<2;++i){
      int ct = 2*g + i;                    // 0..3
      float bias = wf[OFF_GATE_B1 + ct*16 + (lane&15)];
      f32x4 d = {bias,bias,bias,bias};
      #pragma unroll
      for (int ks=0;ks<2;++ks){
        s16x8 bh = g1hi8[(ct*2+ks)*64 + lane];
        d = __builtin_amdgcn_mfma_f32_16x16x32_bf16(esh[ks], bh, d, 0,0,0);
        d = __builtin_amdgcn_mfma_f32_16x16x32_bf16(esh[ks], g1lo8[(ct*2+ks)*64 + lane], d, 0,0,0);
        d = __builtin_amdgcn_mfma_f32_16x16x32_bf16(esl[ks], bh, d, 0,0,0);
      }
      int ch = ct*16 + (lane&15);
      #pragma unroll
      for (int r=0;r<4;++r){
        int ee = etile*16 + ((lane>>4)<<2) + r;
        smf[(64 + ch)*PF + ee] = fsilu(d[r]);
      }
    }
  }
  __syncthreads();                                        // B3 (trunk+ge ready)

  // GATE 2: go = ge@gate_w2 + b2 -> vg (registers), sgate
  float vga[8];
  { float g0 = wf[OFF_GATE_B2];
    #pragma unroll
    for (int t=0;t<8;++t) vga[t] = wf[OFF_GATE_B2 + 1 + 8*wv + t];
    #pragma unroll 2
    for (int k=0;k<64;++k){
      float a = smf[(64+k)*PF + lane];
      const float* wr = wf + OFF_GATE_W2 + k*65;
      g0 += a*wr[0];
      #pragma unroll
      for (int t=0;t<8;++t) vga[t] += a*wr[1 + 8*wv + t];
    }
    #pragma unroll
    for (int t=0;t<8;++t) vga[t] = fsig(vga[t]);
    if (wv == 0){
      float sigma = __expf(wf[OFF_LSIG + etype[e]]);
      s_sgate[lane] = fsig(g0) * __expf(-edist[e]/sigma);
    }
  }
  __syncthreads();                                        // B4 (ge dead)

  float sregS[16], sregV[8], souts[16], soutv[8];
  const s16x8* rinhi8  = reinterpret_cast<const s16x8*>(wf + OFF_RINHI);
  const s16x8* rinlo8  = reinterpret_cast<const s16x8*>(wf + OFF_RINLO);
  const s16x8* routhi8 = reinterpret_cast<const s16x8*>(wf + OFF_ROUTHI);
  const s16x8* routlo8 = reinterpret_cast<const s16x8*>(wf + OFF_ROUTLO);

  // ===== RIN split-MFMA, pass 0: ctiles 0..5 (cols 0..95) =====
  { s16x8 ahi[4], alo[4];
    #pragma unroll
    for (int ks=0;ks<4;++ks){
      ahi[ks] = *reinterpret_cast<const s16x8*>(trunk_hi + erow*136 + ks*32 + kg);
      alo[ks] = *reinterpret_cast<const s16x8*>(trunk_lo + erow*136 + ks*32 + kg);
    }
    #pragma unroll
    for (int i=0;i<3;++i){
      int ct = 3*g + i;
      float bias = 1.f + wf[OFF_RIN_B + ct*16 + (lane&15)];
      f32x4 d = {bias,bias,bias,bias};
      #pragma unroll
      for (int ks=0;ks<4;++ks){
        s16x8 bh = rinhi8[(ct*4+ks)*64 + lane];
        d = __builtin_amdgcn_mfma_f32_16x16x32_bf16(ahi[ks], bh, d, 0,0,0);
        d = __builtin_amdgcn_mfma_f32_16x16x32_bf16(ahi[ks], rinlo8[(ct*4+ks)*64 + lane], d, 0,0,0);
        d = __builtin_amdgcn_mfma_f32_16x16x32_bf16(alo[ks], bh, d, 0,0,0);
      }
      int cl = ct*16 + (lane&15);
      #pragma unroll
      for (int r=0;r<4;++r) smf[cl*PF + etile*16 + ((lane>>4)<<2) + r] = d[r];
    }
  }
  __syncthreads();
  if (wv < 6){
    #pragma unroll
    for (int i=0;i<16;++i) sregS[i] = smf[(16*wv+i)*PF + lane];
  }
  __syncthreads();
  // ===== RIN pass 1: ctiles 6..11 (cols 96..191) =====
  { s16x8 ahi[4], alo[4];
    #pragma unroll
    for (int ks=0;ks<4;++ks){
      ahi[ks] = *reinterpret_cast<const s16x8*>(trunk_hi + erow*136 + ks*32 + kg);
      alo[ks] = *reinterpret_cast<const s16x8*>(trunk_lo + erow*136 + ks*32 + kg);
    }
    #pragma unroll
    for (int i=0;i<3;++i){
      int ct = 6 + 3*g + i;
      float bias = 1.f + wf[OFF_RIN_B + ct*16 + (lane&15)];
      f32x4 d = {bias,bias,bias,bias};
      #pragma unroll
      for (int ks=0;ks<4;++ks){
        s16x8 bh = rinhi8[(ct*4+ks)*64 + lane];
        d = __builtin_amdgcn_mfma_f32_16x16x32_bf16(ahi[ks], bh, d, 0,0,0);
        d = __builtin_amdgcn_mfma_f32_16x16x32_bf16(ahi[ks], rinlo8[(ct*4+ks)*64 + lane], d, 0,0,0);
        d = __builtin_amdgcn_mfma_f32_16x16x32_bf16(alo[ks], bh, d, 0,0,0);
      }
      int cl = ct*16 + (lane&15) - 96;
      #pragma unroll
      for (int r=0;r<4;++r) smf[cl*PF + etile*16 + ((lane>>4)<<2) + r] = d[r];
    }
  }
  __syncthreads();
  if (wv >= 6){
    #pragma unroll
    for (int i=0;i<16;++i) sregS[i] = smf[(16*wv+i-96)*PF + lane];
  }
  #pragma unroll
  for (int t=0;t<8;++t) sregV[t] = smf[(32 + 8*wv + t)*PF + lane];
  __syncthreads();

  // ===== ROUT split-MFMA, pass 0: ctiles 0..5 =====
  { s16x8 ahi[4], alo[4];
    #pragma unroll
    for (int ks=0;ks<4;++ks){
      ahi[ks] = *reinterpret_cast<const s16x8*>(trunk_hi + erow*136 + ks*32 + kg);
      alo[ks] = *reinterpret_cast<const s16x8*>(trunk_lo + erow*136 + ks*32 + kg);
    }
    #pragma unroll
    for (int i=0;i<3;++i){
      int ct = 3*g + i;
      float bias = 1.f + wf[OFF_ROUT_B + ct*16 + (lane&15)];
      f32x4 d = {bias,bias,bias,bias};
      #pragma unroll
      for (int ks=0;ks<4;++ks){
        s16x8 bh = routhi8[(ct*4+ks)*64 + lane];
        d = __builtin_amdgcn_mfma_f32_16x16x32_bf16(ahi[ks], bh, d, 0,0,0);
        d = __builtin_amdgcn_mfma_f32_16x16x32_bf16(ahi[ks], routlo8[(ct*4+ks)*64 + lane], d, 0,0,0);
        d = __builtin_amdgcn_mfma_f32_16x16x32_bf16(alo[ks], bh, d, 0,0,0);
      }
      int cl = ct*16 + (lane&15);
      #pragma unroll
      for (int r=0;r<4;++r) smf[cl*PF + etile*16 + ((lane>>4)<<2) + r] = d[r];
    }
  }
  __syncthreads();
  if (wv < 6){
    #pragma unroll
    for (int i=0;i<16;++i) souts[i] = smf[(16*wv+i)*PF + lane];
  }
  __syncthreads();
  // ===== ROUT pass 1: ctiles 6..11 =====
  { s16x8 ahi[4], alo[4];
    #pragma unroll
    for (int ks=0;ks<4;++ks){
      ahi[ks] = *reinterpret_cast<const s16x8*>(trunk_hi + erow*136 + ks*32 + kg);
      alo[ks] = *reinterpret_cast<const s16x8*>(trunk_lo + erow*136 + ks*32 + kg);
    }
    #pragma unroll
    for (int i=0;i<3;++i){
      int ct = 6 + 3*g + i;
      float bias = 1.f + wf[OFF_ROUT_B + ct*16 + (lane&15)];
      f32x4 d = {bias,bias,bias,bias};
      #pragma unroll
      for (int ks=0;ks<4;++ks){
        s16x8 bh = routhi8[(ct*4+ks)*64 + lane];
        d = __builtin_amdgcn_mfma_f32_16x16x32_bf16(ahi[ks], bh, d, 0,0,0);
        d = __builtin_amdgcn_mfma_f32_16x16x32_bf16(ahi[ks], routlo8[(ct*4+ks)*64 + lane], d, 0,0,0);
        d = __builtin_amdgcn_mfma_f32_16x16x32_bf16(alo[ks], bh, d, 0,0,0);
      }
      int cl = ct*16 + (lane&15) - 96;
      #pragma unroll
      for (int r=0;r<4;++r) smf[cl*PF + etile*16 + ((lane>>4)<<2) + r] = d[r];
    }
  }
  __syncthreads();
  if (wv >= 6){
    #pragma unroll
    for (int i=0;i<16;++i) souts[i] = smf[(16*wv+i-96)*PF + lane];
  }
  #pragma unroll
  for (int t=0;t<8;++t) soutv[t] = smf[(32 + 8*wv + t)*PF + lane];
  __syncthreads();                                        // trunk + scalebuf dead

  f32x2 svv2[4];
  #pragma unroll
  for (int t2=0;t2<4;++t2) svv2[t2] = 0.f;

  u32* xb32 = reinterpret_cast<u32*>(x_bf);

  // ---- TP scalar, chunk 0: cols [0,64) staged by waves 0..3 (fp32 + bf16) ----
  if (wv < 4){
    #pragma unroll
    for (int q=0;q<4;++q){
      float4 v = hrow4[4*wv + q];
      int s = 16*wv + 4*q;
      float x0 = v.x*sregS[4*q+0];
      float x1 = v.y*sregS[4*q+1];
      float x2 = v.z*sregS[4*q+2];
      float x3 = v.w*sregS[4*q+3];
      smf[(s+0)*PF + lane] = x0;
      smf[(s+1)*PF + lane] = x1;
      smf[(s+2)*PF + lane] = x2;
      smf[(s+3)*PF + lane] = x3;
      xb32[lane*100 + (s>>1)    ] = (u32)f2bf(x0) | ((u32)f2bf(x1)<<16);
      xb32[lane*100 + (s>>1) + 1] = (u32)f2bf(x2) | ((u32)f2bf(x3)<<16);
    }
  }
  __syncthreads();                                        // B5
  #pragma unroll 2
  for (int k=0;k<64;++k){
    float a = smf[k*PF + lane];
    const float* w1p = wf + OFF_TP01 + k*64 + 8*wv;
    #pragma unroll
    for (int t2=0;t2<4;++t2) svv2[t2] += a*ld2(w1p + 2*t2);
  }
  __syncthreads();                                        // B6
  // ---- TP scalar, chunk 1: cols [64,128) staged by waves 4..7 ----
  if (wv >= 4){
    #pragma unroll
    for (int q=0;q<4;++q){
      float4 v = hrow4[4*wv + q];
      int gcol = 16*wv + 4*q;     // [64,128)
      int s = gcol - 64;
      float x0 = v.x*sregS[4*q+0];
      float x1 = v.y*sregS[4*q+1];
      float x2 = v.z*sregS[4*q+2];
      float x3 = v.w*sregS[4*q+3];
      smf[(s+0)*PF + lane] = x0;
      smf[(s+1)*PF + lane] = x1;
      smf[(s+2)*PF + lane] = x2;
      smf[(s+3)*PF + lane] = x3;
      xb32[lane*100 + (gcol>>1)    ] = (u32)f2bf(x0) | ((u32)f2bf(x1)<<16);
      xb32[lane*100 + (gcol>>1) + 1] = (u32)f2bf(x2) | ((u32)f2bf(x3)<<16);
    }
  }
  __syncthreads();                                        // B7
  #pragma unroll 2
  for (int k=0;k<64;++k){
    float a = smf[k*PF + lane];
    const float* w1p = wf + OFF_TP01 + (64+k)*64 + 8*wv;
    #pragma unroll
    for (int t2=0;t2<4;++t2) svv2[t2] += a*ld2(w1p + 2*t2);
  }
  __syncthreads();                                        // B8

  // rank-1 init: mv = svv*y (fp32)
  f32x2 mv2[3][4];
  #pragma unroll
  for (int t2=0;t2<4;++t2){
    mv2[0][t2] = svv2[t2]*y0; mv2[1][t2] = svv2[t2]*y1; mv2[2][t2] = svv2[t2]*y2;
  }

  // ---- TP vector: 4 chunks of 16 u's; XB [0,48) fp32; dot -> x_bf bf16 ----
  for (int vc=0; vc<4; ++vc){
    if ((wv>>1) == vc){
      const int half = wv & 1;
      float dreg[8];
      #pragma unroll
      for (int t=0;t<8;++t) dreg[t]=0.f;
      #pragma unroll
      for (int q=0;q<6;++q){
        float4 v = hrow4[32 + 6*wv + q];
        float vv[4] = {v.x, v.y, v.z, v.w};
        #pragma unroll
        for (int c=0;c<4;++c){
          int l = 4*q + c;             // 0..23
          int t = l/3, d = l - 3*t;    // compile-time
          float x = vv[c]*sregV[t];
          smf[(3*(8*half + t) + d)*PF + lane] = x;
          dreg[t] += x * (d==0 ? y0 : (d==1 ? y1 : y2));
        }
      }
      #pragma unroll
      for (int t=0;t<8;++t)
        x_bf[lane*200 + 128 + 16*vc + 8*half + t] = f2bf(dreg[t]*INV_SQ3f);
    }
    __syncthreads();                                      // stage done
    #pragma unroll 2
    for (int ul=0; ul<16; ++ul){
      float x0 = smf[(3*ul+0)*PF + lane];
      float x1 = smf[(3*ul+1)*PF + lane];
      float x2 = smf[(3*ul+2)*PF + lane];
      const float* wr = wf + OFF_TP10 + (16*vc + ul)*64 + 8*wv;
      #pragma unroll
      for (int t2=0;t2<4;++t2){
        f32x2 wt2 = ld2(wr + 2*t2);
        mv2[0][t2] += x0*wt2; mv2[1][t2] += x1*wt2; mv2[2][t2] += x2*wt2;
      }
    }
    __syncthreads();                                      // compute done
  }

  // ===== MFMA: msg_s = [x|dot] @ [tp00;tp11], K=192, 24 MFMAs/wave =====
  { const s16x8* ms8 = reinterpret_cast<const s16x8*>(wf + OFF_MSBF);
    f32x4 dacc[4];
    #pragma unroll
    for (int i=0;i<4;++i) dacc[i] = f32x4{0.f,0.f,0.f,0.f};
    #pragma unroll
    for (int ks=0;ks<6;++ks){
      s16x8 af = *reinterpret_cast<const s16x8*>(x_bf + erow*200 + ks*32 + kg);
      #pragma unroll
      for (int i=0;i<4;++i){
        int ct = 4*g + i;
        dacc[i] = __builtin_amdgcn_mfma_f32_16x16x32_bf16(af, ms8[(ct*6+ks)*64 + lane], dacc[i], 0,0,0);
      }
    }
    // D layout (m89): col = lane&15, row = (lane>>4)*4 + r
    #pragma unroll
    for (int i=0;i<4;++i){
      int c = (4*g+i)*16 + (lane&15);
      #pragma unroll
      for (int r=0;r<4;++r)
        smf[c*PF + etile*16 + ((lane>>4)<<2) + r] = dacc[i][r];
    }
  }
  __syncthreads();                                        // msgT ready

  // readback msg_s (16 cols/thread)
  f32x2 msg2[8];
  #pragma unroll
  for (int j2=0;j2<8;++j2){
    msg2[j2][0] = smf[(16*wv + 2*j2+0)*PF + lane];
    msg2[j2][1] = smf[(16*wv + 2*j2+1)*PF + lane];
  }
  __syncthreads();                                        // msgT dead

  // P6: apply scale_out + silu + vn -> VN smf[0,64)
  #pragma unroll
  for (int j=0;j<16;++j){
    float m = msg2[j>>1][j&1]*souts[j];
    msg2[j>>1][j&1] = fsilu(m);
  }
  #pragma unroll
  for (int t=0;t<8;++t){
    mv2[0][t>>1][t&1] *= soutv[t]; mv2[1][t>>1][t&1] *= soutv[t]; mv2[2][t>>1][t&1] *= soutv[t];
  }
  #pragma unroll
  for (int t=0;t<8;++t){
    float m0 = mv2[0][t>>1][t&1], m1 = mv2[1][t>>1][t&1], m2 = mv2[2][t>>1][t&1];
    float vn = sqrtf(m0*m0 + m1*m1 + m2*m2 + 1e-12f);
    smf[(8*wv + t)*PF + lane] = vn;
  }
  __syncthreads();                                        // B19

  // P7: t1 = silu(vn@act_w1+b1) -> smf[64,128)
  { f32x2 a12[4];
    #pragma unroll
    for (int t2=0;t2<4;++t2) a12[t2] = ld2(wf + OFF_ACT_B1 + 8*wv + 2*t2);
    #pragma unroll 2
    for (int k=0;k<64;++k){
      float a = smf[k*PF + lane];
      const float* wr = wf + OFF_ACT_W1 + k*64 + 8*wv;
      #pragma unroll
      for (int t2=0;t2<4;++t2) a12[t2] += a*ld2(wr + 2*t2);
    }
    #pragma unroll
    for (int t=0;t<8;++t) smf[(64 + 8*wv + t)*PF + lane] = fsilu(a12[t>>1][t&1]);
  }
  __syncthreads();                                        // B20

  // P8: g = sigmoid(t1@act_w2+b2); mv *= g
  { f32x2 gq2[4];
    #pragma unroll
    for (int t2=0;t2<4;++t2) gq2[t2] = ld2(wf + OFF_ACT_B2 + 8*wv + 2*t2);
    #pragma unroll 2
    for (int k=0;k<64;++k){
      float a = smf[(64+k)*PF + lane];
      const float* wr = wf + OFF_ACT_W2 + k*64 + 8*wv;
      #pragma unroll
      for (int t2=0;t2<4;++t2) gq2[t2] += a*ld2(wr + 2*t2);
    }
    #pragma unroll
    for (int t=0;t<8;++t){
      float gg = fsig(gq2[t>>1][t&1]);
      mv2[0][t>>1][t&1] *= gg; mv2[1][t>>1][t&1] *= gg; mv2[2][t>>1][t&1] *= gg;
    }
  }
  __syncthreads();                                        // B21

  // ===== COALESCED scatter via LDS transpose (smf[0,128)) =====
  // Phase A: sg*msg_s (128 ch)
  { float sg = s_sgate[lane];
    #pragma unroll
    for (int j=0;j<16;++j) smf[(16*wv + j)*PF + lane] = sg*msg2[j>>1][j&1];
  }
  __syncthreads();
  for (int lin=tid; lin<8192; lin+=512){
    int row = lin >> 7, ch = lin & 127;
    atomicAdd(acc_s + (size_t)s_dst[row]*128 + ch, smf[ch*PF + row]);
  }
  __syncthreads();
  // Phase B half 1: u in [0,32) (waves 0..3), 96 ch
  if (wv < 4){
    #pragma unroll
    for (int t=0;t<8;++t){
      int u = 8*wv + t;
      float vgt = vga[t];
      smf[(3*u+0)*PF + lane] = vgt*mv2[0][t>>1][t&1];
      smf[(3*u+1)*PF + lane] = vgt*mv2[1][t>>1][t&1];
      smf[(3*u+2)*PF + lane] = vgt*mv2[2][t>>1][t&1];
    }
  }
  __syncthreads();
  for (int lin=tid; lin<6144; lin+=512){
    int row = lin / 96, ch = lin % 96;
    atomicAdd(acc_v + (size_t)s_dst[row]*192 + ch, smf[ch*PF + row]);
  }
  __syncthreads();
  // Phase B half 2: u in [32,64) (waves 4..7), 96 ch
  if (wv >= 4){
    #pragma unroll
    for (int t=0;t<8;++t){
      int um = 8*(wv-4) + t;
      float vgt = vga[t];
      smf[(3*um+0)*PF + lane] = vgt*mv2[0][t>>1][t&1];
      smf[(3*um+1)*PF + lane] = vgt*mv2[1][t>>1][t&1];
      smf[(3*um+2)*PF + lane] = vgt*mv2[2][t>>1][t&1];
    }
  }
  __syncthreads();
  for (int lin=tid; lin<6144; lin+=512){
    int row = lin / 96, ch = lin % 96;
    atomicAdd(acc_v + (size_t)s_dst[row]*192 + 96 + ch, smf[ch*PF + row]);
  }
  __syncthreads();
  // Phase C: vg (64 ch) + sg
  #pragma unroll
  for (int t=0;t<8;++t) smf[(8*wv + t)*PF + lane] = vga[t];
  __syncthreads();
  for (int lin=tid; lin<4096; lin+=512){
    int row = lin >> 6, ch = lin & 63;
    atomicAdd(acc_vg + (size_t)s_dst[row]*64 + ch, smf[ch*PF + row]);
  }
  if (tid < 64) atomicAdd(acc_sg + s_dst[tid], s_sgate[tid]);
}

// ---------------- node kernel ----------------
__launch_bounds__(256,2)
__global__ void k_node(const float* __restrict__ h, const float* __restrict__ wf,
                       const float* __restrict__ acc_s, const float* __restrict__ acc_sg,
                       const float* __restrict__ acc_vg, const float* __restrict__ acc_v,
                       float* __restrict__ out)
{
  __shared__ float smf[160*PF];
  const int tid  = threadIdx.x;
  const int lane = tid & 63;
  const int wv   = __builtin_amdgcn_readfirstlane(tid >> 6);
  const int n0   = blockIdx.x * 64;
  const int n    = n0 + lane;
  const int w0   = 16*wv;

  float agg[16][3], vnr[16];
  f32x2 sva2[3][8];
  #pragma unroll
  for (int t=0;t<16;++t){
    float inv = 1.f/(acc_vg[n*64 + w0 + t] + 1e-6f);
    agg[t][0] = acc_v[n*192 + (w0+t)*3 + 0]*inv;
    agg[t][1] = acc_v[n*192 + (w0+t)*3 + 1]*inv;
    agg[t][2] = acc_v[n*192 + (w0+t)*3 + 2]*inv;
    vnr[t] = sqrtf(agg[t][0]*agg[t][0]+agg[t][1]*agg[t][1]+agg[t][2]*agg[t][2]+1e-12f);
    smf[(96 + w0 + t)*PF + lane] = vnr[t];
  }
  #pragma unroll
  for (int t2=0;t2<8;++t2){ sva2[0][t2]=0.f; sva2[1][t2]=0.f; sva2[2][t2]=0.f; }

  f32x2 outs2[16];
  #pragma unroll
  for (int j2=0;j2<16;++j2) outs2[j2] = ld2(wf + OFF_SELF_BS + 32*wv + 2*j2);

  for (int cc=0; cc<2; ++cc){
    for (int lin=tid; lin<1024; lin+=256){
      int row = lin>>4, c4 = lin&15;
      float4 v = reinterpret_cast<const float4*>(h)[(n0+row)*80 + cc*16 + c4];
      smf[(c4*4+0)*PF + row] = v.x;
      smf[(c4*4+1)*PF + row] = v.y;
      smf[(c4*4+2)*PF + row] = v.z;
      smf[(c4*4+3)*PF + row] = v.w;
    }
    __syncthreads();
    #pragma unroll 2
    for (int k=0;k<64;++k){
      float a = smf[k*PF + lane];
      const float* wr = wf + OFF_SELF_WS + (cc*64+k)*128 + 32*wv;
      #pragma unroll
      for (int j2=0;j2<16;++j2) outs2[j2] += a*ld2(wr + 2*j2);
    }
    __syncthreads();
  }
  for (int cc=0; cc<2; ++cc){
    for (int lin=tid; lin<1536; lin+=256){
      int row = lin/24, c6 = lin%24;
      float4 v = reinterpret_cast<const float4*>(h)[(n0+row)*80 + 32 + cc*24 + c6];
      smf[(c6*4+0)*PF + row] = v.x;
      smf[(c6*4+1)*PF + row] = v.y;
      smf[(c6*4+2)*PF + row] = v.z;
      smf[(c6*4+3)*PF + row] = v.w;
    }
    __syncthreads();
    #pragma unroll 2
    for (int ul=0; ul<32; ++ul){
      float x0 = smf[(3*ul+0)*PF + lane];
      float x1 = smf[(3*ul+1)*PF + lane];
      float x2 = smf[(3*ul+2)*PF + lane];
      const float* wr = wf + OFF_SELF_WV + (cc*32+ul)*64 + w0;
      #pragma unroll
      for (int t2=0;t2<8;++t2){
        f32x2 wt2 = ld2(wr + 2*t2);
        sva2[0][t2] += x0*wt2; sva2[1][t2] += x1*wt2; sva2[2][t2] += x2*wt2;
      }
    }
    __syncthreads();
  }

  f32x2 rv2[8];
  #pragma unroll
  for (int t2=0;t2<8;++t2) rv2[t2] = ld2(wf + OFF_VR_B + w0 + 2*t2);
  #pragma unroll 2
  for (int k=0;k<64;++k){
    float a = smf[(96+k)*PF + lane];
    const float* wr = wf + OFF_VR_W + k*64 + w0;
    #pragma unroll
    for (int t2=0;t2<8;++t2) rv2[t2] += a*ld2(wr + 2*t2);
  }

  { float inv = 1.f/(acc_sg[n] + 1e-6f);
    const float* ap = acc_s + (size_t)n*128 + 32*wv;
    #pragma unroll
    for (int j2=0;j2<16;++j2) outs2[j2] += ld2(ap + 2*j2)*inv;
  }

  float* orow = out + (size_t)n*320;
  { float4* o4 = reinterpret_cast<float4*>(orow + 32*wv);
    #pragma unroll
    for (int j=0;j<8;++j){
      float4 v;
      v.x=outs2[2*j+0][0]; v.y=outs2[2*j+0][1];
      v.z=outs2[2*j+1][0]; v.w=outs2[2*j+1][1];
      o4[j] = v;
    }
  }
  { float vbuf[48];
    #pragma unroll
    for (int t=0;t<16;++t){
      float sc = rv2[t>>1][t&1]/(vnr[t]+1e-6f);
      vbuf[t*3+0] = agg[t][0]*sc + sva2[0][t>>1][t&1];
      vbuf[t*3+1] = agg[t][1]*sc + sva2[1][t>>1][t&1];
      vbuf[t*3+2] = agg[t][2]*sc + sva2[2][t>>1][t&1];
    }
    float4* o4 = reinterpret_cast<float4*>(orow + 128 + 48*wv);
    #pragma unroll
    for (int j=0;j<12;++j){
      float4 v; v.x=vbuf[4*j]; v.y=vbuf[4*j+1]; v.z=vbuf[4*j+2]; v.w=vbuf[4*j+3];
      o4[j] = v;
    }
  }
}

// ---------------- launch ----------------
extern "C" void kernel_launch(void* const* d_in, const int* in_sizes, int n_in,
                              void* d_out, int out_size, void* d_ws, size_t ws_size,
                              hipStream_t stream) {
  const float* h     = (const float*)d_in[0];
  const float* evec  = (const float*)d_in[1];
  const float* es    = (const float*)d_in[2];
  const float* edist = (const float*)d_in[3];
  const int* srcI    = (const int*)d_in[4];
  const int* dstI    = (const int*)d_in[5];
  const int* etyp    = (const int*)d_in[6];

  float* wsf    = (float*)d_ws;
  float* acc_s  = wsf + ACC_S_OFF;
  float* acc_sg = wsf + ACC_SG_OFF;
  float* acc_vg = wsf + ACC_VG_OFF;
  float* acc_v  = wsf + ACC_V_OFF;

  WCopy wc;
  const int ns[24]  = {8192,128,24576,192,24576,192,16384,8192,4096,8192,4096,64,4096,64,
                       4096,64,4160,65,10,4096,64,16384,128,4096};
  const int offs[24]= {OFF_RT_W,OFF_RT_B,OFF_RIN_W,OFF_RIN_B,OFF_ROUT_W,OFF_ROUT_B,
                       OFF_TP00,OFF_TP01,OFF_TP10,OFF_TP11,OFF_ACT_W1,OFF_ACT_B1,
                       OFF_ACT_W2,OFF_ACT_B2,OFF_GATE_W1,OFF_GATE_B1,OFF_GATE_W2,OFF_GATE_B2,
                       OFF_LSIG,OFF_VR_W,OFF_VR_B,OFF_SELF_WS,OFF_SELF_BS,OFF_SELF_WV};
  for (int a=0;a<24;++a){ wc.src[a] = (const float*)d_in[8+a]; wc.n[a]=ns[a]; wc.off[a]=offs[a]; }
  hipLaunchKernelGGL(k_copy, dim3(533), dim3(256), 0, stream, wc, wsf);

  { int nz = ACC_END - ACC_S_OFF;
    hipLaunchKernelGGL(k_zero, dim3((nz+255)/256), dim3(256), 0, stream, acc_s, nz); }

  hipLaunchKernelGGL(k_edge, dim3(N_EDGES/64), dim3(512), 0, stream,
                     h, evec, es, edist, srcI, dstI, etyp, wsf,
                     acc_s, acc_sg, acc_vg, acc_v);
  hipLaunchKernelGGL(k_node, dim3(N_NODES/64), dim3(256), 0, stream,
                     h, wsf, acc_s, acc_sg, acc_vg, acc_v, (float*)d_out);
}